// Round 14
// baseline (412.739 us; speedup 1.0000x reference)
//
#include <hip/hip_runtime.h>
#include <hip/hip_bf16.h>

#define DDIM 1024
#define SLEN 2048
#define NTOK 8192
#define MLPD 4096

typedef float f32x4 __attribute__((ext_vector_type(4)));
typedef __bf16 bf16x8 __attribute__((ext_vector_type(8)));

__device__ __forceinline__ void async16(void* lds, const void* g) {
  __builtin_amdgcn_global_load_lds(
      (__attribute__((address_space(1))) void*)g,
      (__attribute__((address_space(3))) void*)lds, 16, 0, 0);
}

template <int N> struct VMC { static constexpr int v = N; };

// ---------------------------------------------------------------------------
// prep: router logits + mask + probs, causal depthwise conv (k=3), x -> bf16
// ---------------------------------------------------------------------------
__global__ __launch_bounds__(256) void prep_kernel(
    const float* __restrict__ x, const float* __restrict__ gate_w,
    const float* __restrict__ gate_b, const float* __restrict__ conv_w,
    const float* __restrict__ conv_b, __bf16* __restrict__ xb,
    __bf16* __restrict__ xcb, float* __restrict__ maskp,
    float* __restrict__ probsp) {
  const int tok = blockIdx.x, t = threadIdx.x;
  const int s = tok & (SLEN - 1);
  const float* xr = x + (size_t)tok * DDIM;
  float4 v = ((const float4*)xr)[t];
  float4 g = ((const float4*)gate_w)[t];
  float part = v.x * g.x + v.y * g.y + v.z * g.z + v.w * g.w;
#pragma unroll
  for (int d = 32; d; d >>= 1) part += __shfl_down(part, d);
  __shared__ float ws4[4];
  const int lane = t & 63, w = t >> 6;
  if (lane == 0) ws4[w] = part;
  __syncthreads();
  if (t == 0) {
    float logit = ws4[0] + ws4[1] + ws4[2] + ws4[3] + gate_b[0];
    float prob = 1.f / (1.f + __expf(-logit));
    probsp[tok] = prob;
    maskp[tok] = prob > 0.5f ? 1.f : 0.f;
  }
  union { ushort4 u; __bf16 b[4]; } xo;
  xo.b[0] = (__bf16)v.x; xo.b[1] = (__bf16)v.y;
  xo.b[2] = (__bf16)v.z; xo.b[3] = (__bf16)v.w;
  ((ushort4*)(xb + (size_t)tok * DDIM))[t] = xo.u;
  float4 zero4 = {0.f, 0.f, 0.f, 0.f};
  float4 m1 = (s >= 1) ? ((const float4*)(xr - DDIM))[t] : zero4;
  float4 m2 = (s >= 2) ? ((const float4*)(xr - 2 * DDIM))[t] : zero4;
  int d0 = t * 4;
  float vv[4] = {v.x, v.y, v.z, v.w};
  float a1[4] = {m1.x, m1.y, m1.z, m1.w};
  float a2[4] = {m2.x, m2.y, m2.z, m2.w};
  union { ushort4 u; __bf16 b[4]; } co;
#pragma unroll
  for (int i = 0; i < 4; ++i) {
    float c0 = conv_w[(d0 + i) * 3 + 0];
    float c1 = conv_w[(d0 + i) * 3 + 1];
    float c2 = conv_w[(d0 + i) * 3 + 2];
    float r = a2[i] * c0 + a1[i] * c1 + vv[i] * c2 + conv_b[d0 + i];
    co.b[i] = (__bf16)r;
  }
  ((ushort4*)(xcb + (size_t)tok * DDIM))[t] = co.u;
}

// ---------------------------------------------------------------------------
// compact: per batch, prefix-scan of mask -> act[b][j] (sorted original
// positions of active queries), nact[b]. One block per batch.
// ---------------------------------------------------------------------------
__global__ __launch_bounds__(256) void compact_kernel(
    const float* __restrict__ maskp, int* __restrict__ act,
    int* __restrict__ nact) {
  const int b = blockIdx.x, t = threadIdx.x;
  __shared__ int sc[256];
  __shared__ int base;
  if (t == 0) base = 0;
  __syncthreads();
  for (int ch = 0; ch < 8; ++ch) {
    int tok = ch * 256 + t;
    int m = maskp[b * 2048 + tok] > 0.5f ? 1 : 0;
    sc[t] = m;
    __syncthreads();
#pragma unroll
    for (int off = 1; off < 256; off <<= 1) {
      int v = t >= off ? sc[t - off] : 0;
      __syncthreads();
      sc[t] += v;
      __syncthreads();
    }
    if (m) act[b * 2048 + base + sc[t] - 1] = tok;
    int tot = sc[255];
    __syncthreads();
    if (t == 0) base += tot;
    __syncthreads();
  }
  if (t == 0) nact[b] = base;
}

// ---------------------------------------------------------------------------
// RoPE trig table: tab[s][i] = (cos(s*invf(i)), sin(s*invf(i))), s<2048, i<32
// ---------------------------------------------------------------------------
__global__ __launch_bounds__(256) void tabgen_kernel(float2* __restrict__ tab) {
  const int idx = blockIdx.x * 256 + threadIdx.x;  // 65536 total
  const int s = idx >> 5, i = idx & 31;
  float invf = __builtin_amdgcn_exp2f(-(float)i * (13.28771238f / 32.f));
  float fr = (float)s * invf;
  tab[idx] = make_float2(cosf(fr), sinf(fr));
}

// ---------------------------------------------------------------------------
// transposed cast: src [K][N] f32 -> dst [N][K] bf16
// ---------------------------------------------------------------------------
__global__ __launch_bounds__(256) void tcast_kernel(const float* __restrict__ src,
                                                    __bf16* __restrict__ dst,
                                                    int K, int N) {
  __shared__ __bf16 tile[64][65];
  const int n0 = blockIdx.x * 64, k0 = blockIdx.y * 64;
  const int t = threadIdx.x;
  const int cr = (t & 15) * 4;
#pragma unroll
  for (int i = 0; i < 4; ++i) {
    int rr = (t >> 4) + i * 16;
    float4 v = *(const float4*)(src + (size_t)(k0 + rr) * N + n0 + cr);
    tile[rr][cr + 0] = (__bf16)v.x; tile[rr][cr + 1] = (__bf16)v.y;
    tile[rr][cr + 2] = (__bf16)v.z; tile[rr][cr + 3] = (__bf16)v.w;
  }
  __syncthreads();
#pragma unroll
  for (int i = 0; i < 2; ++i) {
    int c = t + i * 256;
    int nl = c >> 3, koff = (c & 7) * 8;
    union { uint4 u; __bf16 b[8]; } o;
#pragma unroll
    for (int j = 0; j < 8; ++j) o.b[j] = tile[koff + j][nl];
    *(uint4*)(dst + (size_t)(n0 + nl) * K + k0 + koff) = o.u;
  }
}

// ---------------------------------------------------------------------------
// 256x256 pipelined GEMM (ring-4, counted vmcnt), optional fused RoPE.
// EPI: 0 = bf16 store; 1 = bf16 relu(v+bias).
// ---------------------------------------------------------------------------
template <int EPI, bool ROPE>
__global__ __launch_bounds__(512, 2) void gemm256p(
    const __bf16* __restrict__ A, const __bf16* __restrict__ Bt,
    const float* __restrict__ bias, const float2* __restrict__ tab,
    __bf16* __restrict__ Cb, int M, int N, int K) {
  extern __shared__ char sm[];
  const int t = threadIdx.x, lane = t & 63, w = t >> 6;
  const int c = lane & 15, g = lane >> 4;
  const int nwg = gridDim.x * gridDim.y;
  const int wgid = blockIdx.y * gridDim.x + blockIdx.x;
  const int swz = (wgid & 7) * (nwg >> 3) + (wgid >> 3);
  const int m0 = (swz / gridDim.x) * 256, n0 = (swz % gridDim.x) * 256;
  const int wm = (w >> 2) * 128, wn = (w & 3) * 64;

  f32x4 acc[8][4] = {};
  const int nk = K >> 5;

  auto stage = [&](int buf, int kt) {
    const int k0 = kt << 5;
    char* base = sm + buf * 32768;
#pragma unroll
    for (int r = 0; r < 2; ++r) {
      int o = ((r * 8 + w) << 10) + (lane << 4);
      int rp = o >> 7;
      int u = (o >> 4) & 7;
      int l = u ^ (rp & 7);
      int mr = rp * 2 + (l >> 2);
      int kk = (l & 3) * 8;
      async16(base + o, A + (size_t)(m0 + mr) * K + k0 + kk);
      async16(base + 16384 + o, Bt + (size_t)(n0 + mr) * K + k0 + kk);
    }
  };

  auto body = [&](auto vmc, int tt, bool dostage) {
    if (dostage) stage((tt + 3) & 3, tt + 3);
    asm volatile("s_waitcnt vmcnt(%0)" ::"n"(decltype(vmc)::v) : "memory");
    __builtin_amdgcn_s_barrier();
    asm volatile("" ::: "memory");
    const char* Ab = sm + (tt & 3) * 32768;
    const char* Bb = Ab + 16384;
    bf16x8 aq[8], bq[4];
#pragma unroll
    for (int nt = 0; nt < 4; ++nt) {
      int row = wn + nt * 16 + c;
      int rp = row >> 1;
      int u = ((row & 1) * 4 + g) ^ (rp & 7);
      bq[nt] = *(const bf16x8*)(Bb + rp * 128 + u * 16);
    }
#pragma unroll
    for (int i = 0; i < 8; ++i) {
      int row = wm + i * 16 + c;
      int rp = row >> 1;
      int u = ((row & 1) * 4 + g) ^ (rp & 7);
      aq[i] = *(const bf16x8*)(Ab + rp * 128 + u * 16);
    }
    __builtin_amdgcn_s_setprio(1);
#pragma unroll
    for (int i = 0; i < 8; ++i)
#pragma unroll
      for (int nt = 0; nt < 4; ++nt)
        acc[i][nt] = __builtin_amdgcn_mfma_f32_16x16x32_bf16(
            aq[i], bq[nt], acc[i][nt], 0, 0, 0);
    __builtin_amdgcn_s_setprio(0);
    __builtin_amdgcn_s_barrier();
    asm volatile("" ::: "memory");
  };

  stage(0, 0);
  stage(1, 1);
  stage(2, 2);
  int tt = 0;
  for (; tt < nk - 3; ++tt) body(VMC<12>{}, tt, true);
  body(VMC<8>{}, tt, false); ++tt;
  body(VMC<4>{}, tt, false); ++tt;
  body(VMC<0>{}, tt, false);

  if (ROPE && n0 < 2048) {
#pragma unroll
    for (int i = 0; i < 8; ++i)
#pragma unroll
      for (int r = 0; r < 4; ++r) {
        int s = (m0 + wm + i * 16 + g * 4 + r) & (SLEN - 1);
        float2 t0 = tab[s * 32 + c];
        float2 t1 = tab[s * 32 + 16 + c];
        float q0 = acc[i][0][r], q2 = acc[i][2][r];
        acc[i][0][r] = q0 * t0.x - q2 * t0.y;
        acc[i][2][r] = q2 * t0.x + q0 * t0.y;
        float q1 = acc[i][1][r], q3 = acc[i][3][r];
        acc[i][1][r] = q1 * t1.x - q3 * t1.y;
        acc[i][3][r] = q3 * t1.x + q1 * t1.y;
      }
  }

#pragma unroll
  for (int i = 0; i < 8; ++i)
#pragma unroll
    for (int nt = 0; nt < 4; ++nt)
#pragma unroll
      for (int r = 0; r < 4; ++r) {
        int row = m0 + wm + i * 16 + g * 4 + r;
        int col = n0 + wn + nt * 16 + c;
        float v = acc[i][nt][r];
        size_t idx = (size_t)row * N + col;
        if constexpr (EPI == 0) {
          Cb[idx] = (__bf16)v;
        } else {
          v += bias[col];
          Cb[idx] = (__bf16)fmaxf(v, 0.f);
        }
      }
}

// ---------------------------------------------------------------------------
// GEMM 128x128 (MLP2): f32 out = xres + v + bias
// ---------------------------------------------------------------------------
__global__ __launch_bounds__(256, 3) void gemm_bt2(
    const __bf16* __restrict__ A, const __bf16* __restrict__ Bt,
    const float* __restrict__ bias, const float* __restrict__ xres,
    float* __restrict__ Cf, int M, int N, int K) {
  __shared__ char smem[32768];
  char* As = smem;
  char* Bs = smem + 16384;
  const int t = threadIdx.x, lane = t & 63, w = t >> 6;
  const int nwg = gridDim.x * gridDim.y;
  const int wgid = blockIdx.y * gridDim.x + blockIdx.x;
  const int swz = (wgid & 7) * (nwg >> 3) + (wgid >> 3);
  const int m0 = (swz / gridDim.x) * 128, n0 = (swz % gridDim.x) * 128;
  const int wm = (w >> 1) * 64, wn = (w & 1) * 64;
  f32x4 acc[4][4] = {};
  const int nk = K >> 6;
  for (int kt = 0; kt < nk; ++kt) {
    const int k0 = kt << 6;
#pragma unroll
    for (int rd = 0; rd < 4; ++rd) {
      int o = ((rd * 4 + w) << 10) + (lane << 4);
      int row = o >> 7;
      int us = ((o >> 4) & 7) ^ (row & 7);
      async16(As + o, A + (size_t)(m0 + row) * K + k0 + us * 8);
      async16(Bs + o, Bt + (size_t)(n0 + row) * K + k0 + us * 8);
    }
    __syncthreads();
#pragma unroll
    for (int ks = 0; ks < 2; ++ks) {
      bf16x8 af[4], bfr[4];
#pragma unroll
      for (int mt = 0; mt < 4; ++mt) {
        int row = wm + mt * 16 + (lane & 15);
        int u = (ks * 4 + (lane >> 4)) ^ (row & 7);
        af[mt] = *(const bf16x8*)(As + row * 128 + u * 16);
      }
#pragma unroll
      for (int nt = 0; nt < 4; ++nt) {
        int row = wn + nt * 16 + (lane & 15);
        int u = (ks * 4 + (lane >> 4)) ^ (row & 7);
        bfr[nt] = *(const bf16x8*)(Bs + row * 128 + u * 16);
      }
#pragma unroll
      for (int mt = 0; mt < 4; ++mt)
#pragma unroll
        for (int nt = 0; nt < 4; ++nt)
          acc[mt][nt] = __builtin_amdgcn_mfma_f32_16x16x32_bf16(
              af[mt], bfr[nt], acc[mt][nt], 0, 0, 0);
    }
    __syncthreads();
  }
#pragma unroll
  for (int mt = 0; mt < 4; ++mt)
#pragma unroll
    for (int nt = 0; nt < 4; ++nt)
#pragma unroll
      for (int r = 0; r < 4; ++r) {
        int row = m0 + wm + mt * 16 + ((lane >> 4) << 2) + r;
        int col = n0 + wn + nt * 16 + (lane & 15);
        size_t idx = (size_t)row * N + col;
        Cf[idx] = xres[idx] + acc[mt][nt][r] + bias[col];
      }
}

// ---------------------------------------------------------------------------
// WO GEMM on COMPACTED ctx rows: out[act[j]] += (ctxc @ wo)[j]. Tiles whose
// 128-row span is fully inactive exit; partial tiles skip invalid stores.
// ---------------------------------------------------------------------------
__global__ __launch_bounds__(256, 3) void gemm_wo(
    const __bf16* __restrict__ A, const __bf16* __restrict__ Bt,
    const int* __restrict__ act, const int* __restrict__ nact,
    float* __restrict__ Cf, int M, int N, int K) {
  __shared__ char smem[32768];
  char* As = smem;
  char* Bs = smem + 16384;
  const int t = threadIdx.x, lane = t & 63, w = t >> 6;
  const int nwg = gridDim.x * gridDim.y;
  const int wgid = blockIdx.y * gridDim.x + blockIdx.x;
  const int swz = (wgid & 7) * (nwg >> 3) + (wgid >> 3);
  const int m0 = (swz / gridDim.x) * 128, n0 = (swz % gridDim.x) * 128;
  const int b = m0 >> 11;
  const int na = nact[b];
  if ((m0 & 2047) >= na) return;  // fully inactive tile (uniform)
  const int wm = (w >> 1) * 64, wn = (w & 1) * 64;
  f32x4 acc[4][4] = {};
  const int nk = K >> 6;
  for (int kt = 0; kt < nk; ++kt) {
    const int k0 = kt << 6;
#pragma unroll
    for (int rd = 0; rd < 4; ++rd) {
      int o = ((rd * 4 + w) << 10) + (lane << 4);
      int row = o >> 7;
      int us = ((o >> 4) & 7) ^ (row & 7);
      async16(As + o, A + (size_t)(m0 + row) * K + k0 + us * 8);
      async16(Bs + o, Bt + (size_t)(n0 + row) * K + k0 + us * 8);
    }
    __syncthreads();
#pragma unroll
    for (int ks = 0; ks < 2; ++ks) {
      bf16x8 af[4], bfr[4];
#pragma unroll
      for (int mt = 0; mt < 4; ++mt) {
        int row = wm + mt * 16 + (lane & 15);
        int u = (ks * 4 + (lane >> 4)) ^ (row & 7);
        af[mt] = *(const bf16x8*)(As + row * 128 + u * 16);
      }
#pragma unroll
      for (int nt = 0; nt < 4; ++nt) {
        int row = wn + nt * 16 + (lane & 15);
        int u = (ks * 4 + (lane >> 4)) ^ (row & 7);
        bfr[nt] = *(const bf16x8*)(Bs + row * 128 + u * 16);
      }
#pragma unroll
      for (int mt = 0; mt < 4; ++mt)
#pragma unroll
        for (int nt = 0; nt < 4; ++nt)
          acc[mt][nt] = __builtin_amdgcn_mfma_f32_16x16x32_bf16(
              af[mt], bfr[nt], acc[mt][nt], 0, 0, 0);
    }
    __syncthreads();
  }
#pragma unroll
  for (int mt = 0; mt < 4; ++mt)
#pragma unroll
    for (int nt = 0; nt < 4; ++nt)
#pragma unroll
      for (int r = 0; r < 4; ++r) {
        int row = m0 + wm + mt * 16 + ((lane >> 4) << 2) + r;
        int col = n0 + wn + nt * 16 + (lane & 15);
        int jj = row & 2047;
        if (jj < na) {
          int tok = act[b * 2048 + jj];
          Cf[((size_t)b * 2048 + tok) * N + col] += acc[mt][nt][r];
        }
      }
}

// ---------------------------------------------------------------------------
// V scatter: regs -> swizzled Vt[d][kj] LDS
// ---------------------------------------------------------------------------
__device__ __forceinline__ void scatterV(char* Vdst, int w, int lane,
                                         float4 va, float4 vb) {
  union { float4 f; __bf16 bv[8]; } u0, u1;
  u0.f = va; u1.f = vb;
#pragma unroll
  for (int j = 0; j < 8; ++j) {
    int d = w * 8 + j;
    int by = d * 128 + (((lane >> 3) ^ (d & 7)) << 4) + ((lane & 7) << 1);
    *(__bf16*)(Vdst + by) = u0.bv[j];
    int d2 = d + 32;
    int by2 = d2 * 128 + (((lane >> 3) ^ (d2 & 7)) << 4) + ((lane & 7) << 1);
    *(__bf16*)(Vdst + by2) = u1.bv[j];
  }
}

// ---------------------------------------------------------------------------
// Flash attention over COMPACTED (router-active) queries, causal by ORIGINAL
// position. Grid (64 bh, 16 j): j = 15-blockIdx.y (longest-first; j >= ntile
// exits). Q gather-staged; per-row causal pos from act[]; k-range from the
// tile's max original position. K/V stay in original token space (all
// tokens are keys). bh = blockIdx.x keeps same-bh blocks on one XCD (L2).
// Dead rows in later tiles: m_run finite after tile 0 => p = exp2(-1e30-m)=0.
// ---------------------------------------------------------------------------
__global__ __launch_bounds__(256, 3) void attn_kernel(
    const __bf16* __restrict__ qkv, __bf16* __restrict__ ctx,
    const int* __restrict__ act, const int* __restrict__ nact) {
  __shared__ char sm[32768];
  const int t = threadIdx.x, lane = t & 63, w = t >> 6;
  const int c = lane & 15, g = lane >> 4, g4 = g * 4;
  const int bh = (int)blockIdx.x;
  const int h = bh & 15, b = bh >> 4;
  const int na = nact[b];
  const int ntile = (na + 127) >> 7;
  const int j = 15 - (int)blockIdx.y;
  if (j >= ntile) return;
  const int* actb = act + b * 2048;
  const size_t tokbase = (size_t)b * SLEN;
  const __bf16* qg = qkv + tokbase * 3072 + h * 64;
  const __bf16* kg = qg + 1024;
  const __bf16* vg = qg + 2048;
  const float SCL = 0.125f * 1.44269504f;  // 1/sqrt(64) * log2(e)
  char* Ps = sm + (w << 12);
  char* Ks = sm + 16384;
  char* Vs = sm + 24576;

  const int q0 = j * 128;
  // gather-stage Q (per-lane global source; LDS dest linear per wave)
#pragma unroll
  for (int rd = 0; rd < 4; ++rd) {
    int o = ((rd * 4 + w) << 10) + (lane << 4);
    int row = o >> 7;
    int us = ((o >> 4) & 7) ^ (row & 7);
    int cr = q0 + row; if (cr > na - 1) cr = na - 1;
    async16(sm + o, qg + (size_t)actb[cr] * 3072 + us * 8);
  }
  __syncthreads();
  bf16x8 qb[2][2];
#pragma unroll
  for (int mt = 0; mt < 2; ++mt)
#pragma unroll
    for (int ks = 0; ks < 2; ++ks) {
      int row = w * 32 + mt * 16 + c;
      int u = (ks * 4 + g) ^ (row & 7);
      qb[mt][ks] = *(const bf16x8*)(sm + row * 128 + u * 16);
    }
  // original positions for causal logic
  int qpos[2];
#pragma unroll
  for (int mt = 0; mt < 2; ++mt) {
    int rr = q0 + w * 32 + mt * 16 + c; if (rr > na - 1) rr = na - 1;
    qpos[mt] = actb[rr];
  }
  int rf = q0 + w * 32;       if (rf > na - 1) rf = na - 1;
  int rl = q0 + w * 32 + 31;  if (rl > na - 1) rl = na - 1;
  const int wmin = actb[rf], wmax = actb[rl];
  int bl = q0 + 127;          if (bl > na - 1) bl = na - 1;
  const int nkt = (actb[bl] >> 6) + 1;

  float m_run[2] = {-1e30f, -1e30f}, l_run[2] = {0.f, 0.f};
  f32x4 o_acc[2][4] = {};

  for (int kt = 0; kt < nkt; ++kt) {
    const int k0 = kt << 6;
#pragma unroll
    for (int rd = 0; rd < 2; ++rd) {
      int o = ((rd * 4 + w) << 10) + (lane << 4);
      int row = o >> 7;
      int us = ((o >> 4) & 7) ^ (row & 7);
      async16(Ks + o, kg + (size_t)(k0 + row) * 3072 + us * 8);
    }
    {
      float4 va = *(const float4*)(vg + (size_t)(k0 + lane) * 3072 + w * 8);
      float4 vb2 = *(const float4*)(vg + (size_t)(k0 + lane) * 3072 + w * 8 + 32);
      scatterV(Vs, w, lane, va, vb2);
    }
    __syncthreads();
    if (k0 <= wmax) {
      f32x4 st[4][2] = {};
      __builtin_amdgcn_s_setprio(1);
#pragma unroll
      for (int ks = 0; ks < 2; ++ks) {
        bf16x8 ka[4];
#pragma unroll
        for (int nt = 0; nt < 4; ++nt) {
          int row = nt * 16 + c;
          int u = (ks * 4 + g) ^ (row & 7);
          ka[nt] = *(const bf16x8*)(Ks + row * 128 + u * 16);
        }
#pragma unroll
        for (int nt = 0; nt < 4; ++nt)
#pragma unroll
          for (int mt = 0; mt < 2; ++mt)
            st[nt][mt] = __builtin_amdgcn_mfma_f32_16x16x32_bf16(
                ka[nt], qb[mt][ks], st[nt][mt], 0, 0, 0);
      }
      __builtin_amdgcn_s_setprio(0);
      const bool needmask = (k0 + 63) > wmin;
#pragma unroll
      for (int mt = 0; mt < 2; ++mt) {
        float mx = -1e30f;
        if (needmask) {
          int qglob = qpos[mt];
#pragma unroll
          for (int nt = 0; nt < 4; ++nt)
#pragma unroll
            for (int r = 0; r < 4; ++r) {
              float sv = st[nt][mt][r] * SCL;
              if (k0 + nt * 16 + g4 + r > qglob) sv = -1e30f;
              st[nt][mt][r] = sv;
              mx = fmaxf(mx, sv);
            }
        } else {
#pragma unroll
          for (int nt = 0; nt < 4; ++nt)
#pragma unroll
            for (int r = 0; r < 4; ++r) {
              float sv = st[nt][mt][r] * SCL;
              st[nt][mt][r] = sv;
              mx = fmaxf(mx, sv);
            }
        }
        mx = fmaxf(mx, __shfl_xor(mx, 16));
        mx = fmaxf(mx, __shfl_xor(mx, 32));
        const bool skip = __all(mx - m_run[mt] <= 8.f) != 0;
        float mnew = skip ? m_run[mt] : fmaxf(m_run[mt], mx);
        float rs = 0.f;
#pragma unroll
        for (int nt = 0; nt < 4; ++nt)
#pragma unroll
          for (int r = 0; r < 4; ++r) {
            float p = __builtin_amdgcn_exp2f(st[nt][mt][r] - mnew);
            st[nt][mt][r] = p;
            rs += p;
          }
        rs += __shfl_xor(rs, 16);
        rs += __shfl_xor(rs, 32);
        if (skip) {
          l_run[mt] += rs;
        } else {
          float fac = __builtin_amdgcn_exp2f(m_run[mt] - mnew);
          m_run[mt] = mnew;
          l_run[mt] = l_run[mt] * fac + rs;
#pragma unroll
          for (int r = 0; r < 4; ++r) {
            float fr = __shfl(fac, g * 20 + r);
#pragma unroll
            for (int dt = 0; dt < 4; ++dt) o_acc[mt][dt][r] *= fr;
          }
        }
        int rowq = mt * 16 + c;
        int rbase = rowq * 128 + 8 * (g & 1);
#pragma unroll
        for (int nt = 0; nt < 4; ++nt) {
          int us = (2 * nt + (g >> 1)) ^ (c & 7);
          union { uint2 v; __bf16 bb[4]; } pp;
          pp.bb[0] = (__bf16)st[nt][mt][0]; pp.bb[1] = (__bf16)st[nt][mt][1];
          pp.bb[2] = (__bf16)st[nt][mt][2]; pp.bb[3] = (__bf16)st[nt][mt][3];
          *(uint2*)(Ps + rbase + us * 16) = pp.v;
        }
      }
      __builtin_amdgcn_s_setprio(1);
#pragma unroll
      for (int ks = 0; ks < 2; ++ks) {
        bf16x8 pa[2], vb[4];
#pragma unroll
        for (int mt = 0; mt < 2; ++mt) {
          int row = mt * 16 + c;
          int u = (ks * 4 + g) ^ (row & 7);
          pa[mt] = *(const bf16x8*)(Ps + row * 128 + u * 16);
        }
#pragma unroll
        for (int dt = 0; dt < 4; ++dt) {
          int row = dt * 16 + c;
          int u = (ks * 4 + g) ^ (row & 7);
          vb[dt] = *(const bf16x8*)(Vs + row * 128 + u * 16);
        }
#pragma unroll
        for (int mt = 0; mt < 2; ++mt)
#pragma unroll
          for (int dt = 0; dt < 4; ++dt)
            o_acc[mt][dt] = __builtin_amdgcn_mfma_f32_16x16x32_bf16(
                pa[mt], vb[dt], o_acc[mt][dt], 0, 0, 0);
      }
      __builtin_amdgcn_s_setprio(0);
    }
    __syncthreads();
  }
  // store compacted ctx rows (rows >= na hold garbage; WO never reads them)
#pragma unroll
  for (int mt = 0; mt < 2; ++mt)
#pragma unroll
    for (int r = 0; r < 4; ++r) {
      float lr = __shfl(l_run[mt], g * 20 + r);
      float inv = 1.f / lr;
      int tokr = q0 + w * 32 + mt * 16 + g4 + r;
#pragma unroll
      for (int dt = 0; dt < 4; ++dt) {
        int d = dt * 16 + c;
        ctx[(tokbase + tokr) * DDIM + h * 64 + d] =
            (__bf16)(o_acc[mt][dt][r] * inv);
      }
    }
}

// ---------------------------------------------------------------------------
// aux loss: (mean(probs) - 0.2)^2
// ---------------------------------------------------------------------------
__global__ __launch_bounds__(256) void aux_kernel(const float* __restrict__ probsp,
                                                  float* __restrict__ outp) {
  const int t = threadIdx.x;
  float sum = 0.f;
  for (int i = t; i < NTOK; i += 256) sum += probsp[i];
#pragma unroll
  for (int d = 32; d; d >>= 1) sum += __shfl_down(sum, d);
  __shared__ float ws4[4];
  if ((t & 63) == 0) ws4[t >> 6] = sum;
  __syncthreads();
  if (t == 0) {
    float m = (ws4[0] + ws4[1] + ws4[2] + ws4[3]) * (1.f / NTOK) - 0.2f;
    outp[0] = m * m;
  }
}

// ---------------------------------------------------------------------------
extern "C" void kernel_launch(void* const* d_in, const int* in_sizes, int n_in,
                              void* d_out, int out_size, void* d_ws, size_t ws_size,
                              hipStream_t stream) {
  const float* x      = (const float*)d_in[0];
  const float* gate_w = (const float*)d_in[1];
  const float* gate_b = (const float*)d_in[2];
  const float* wq     = (const float*)d_in[3];
  const float* wk     = (const float*)d_in[4];
  const float* wv     = (const float*)d_in[5];
  const float* wo     = (const float*)d_in[6];
  const float* conv_w = (const float*)d_in[7];
  const float* conv_b = (const float*)d_in[8];
  const float* mlp_w1 = (const float*)d_in[9];
  const float* mlp_b1 = (const float*)d_in[10];
  const float* mlp_w2 = (const float*)d_in[11];
  const float* mlp_b2 = (const float*)d_in[12];
  float* out = (float*)d_out;

  char* ws = (char*)d_ws;
  const size_t MB = 1ull << 20;
  __bf16* xb     = (__bf16*)(ws + 0);
  __bf16* xcb    = (__bf16*)(ws + 16 * MB);
  __bf16* ctx    = (__bf16*)(ws + 16 * MB);    // overlays xcb (compacted rows)
  __bf16* wqkv_t = (__bf16*)(ws + 32 * MB);
  __bf16* wo_t   = (__bf16*)(ws + 38 * MB);
  __bf16* w1_t   = (__bf16*)(ws + 40 * MB);
  __bf16* w2_t   = (__bf16*)(ws + 48 * MB);
  float*  maskp  = (float*)(ws + 56 * MB);
  float*  probsp = (float*)(ws + 56 * MB + 65536);
  float2* ropetab= (float2*)(ws + 56 * MB + 131072);      // 512KB
  int*    act    = (int*)(ws + 56 * MB + 655360);         // 32KB
  int*    nactp  = (int*)(ws + 56 * MB + 688128);         // 16B
  __bf16* h1     = (__bf16*)(ws + 57 * MB);
  __bf16* qkv    = (__bf16*)(ws + 57 * MB);    // overlays h1

  prep_kernel<<<NTOK, 256, 0, stream>>>(x, gate_w, gate_b, conv_w, conv_b,
                                        xb, xcb, maskp, probsp);
  compact_kernel<<<4, 256, 0, stream>>>(maskp, act, nactp);
  tabgen_kernel<<<256, 256, 0, stream>>>(ropetab);
  tcast_kernel<<<dim3(16, 16), 256, 0, stream>>>(wq, wqkv_t, 1024, 1024);
  tcast_kernel<<<dim3(16, 16), 256, 0, stream>>>(wk, wqkv_t + 1024 * 1024, 1024, 1024);
  tcast_kernel<<<dim3(16, 16), 256, 0, stream>>>(wv, wqkv_t + 2048 * 1024, 1024, 1024);
  tcast_kernel<<<dim3(16, 16), 256, 0, stream>>>(wo, wo_t, 1024, 1024);
  tcast_kernel<<<dim3(64, 16), 256, 0, stream>>>(mlp_w1, w1_t, 1024, 4096);
  tcast_kernel<<<dim3(16, 64), 256, 0, stream>>>(mlp_w2, w2_t, 4096, 1024);

  // Reflexive (MLP) stream first so h1 region can be reused by qkv.
  gemm256p<1, false><<<dim3(16, 32), 512, 131072, stream>>>(
      xcb, w1_t, mlp_b1, nullptr, h1, NTOK, MLPD, DDIM);
  gemm_bt2<<<dim3(8, 64), 256, 0, stream>>>(h1, w2_t, mlp_b2, x, out,
                                            NTOK, DDIM, MLPD);
  // Contextual stream (RoPE fused into the QKV epilogue).
  gemm256p<0, true><<<dim3(12, 32), 512, 131072, stream>>>(
      xb, wqkv_t, nullptr, ropetab, qkv, NTOK, 3072, DDIM);
  attn_kernel<<<dim3(64, 16), 256, 0, stream>>>(qkv, ctx, act, nactp);
  gemm_wo<<<dim3(8, 64), 256, 0, stream>>>(ctx, wo_t, act, nactp, out,
                                           NTOK, DDIM, DDIM);
  aux_kernel<<<1, 256, 0, stream>>>(probsp, out + (size_t)(out_size - 1));
}

// Round 15
// 393.355 us; speedup vs baseline: 1.0493x; 1.0493x over previous
//
#include <hip/hip_runtime.h>
#include <hip/hip_bf16.h>

#define DDIM 1024
#define SLEN 2048
#define NTOK 8192
#define MLPD 4096

typedef float f32x4 __attribute__((ext_vector_type(4)));
typedef __bf16 bf16x8 __attribute__((ext_vector_type(8)));

__device__ __forceinline__ void async16(void* lds, const void* g) {
  __builtin_amdgcn_global_load_lds(
      (__attribute__((address_space(1))) void*)g,
      (__attribute__((address_space(3))) void*)lds, 16, 0, 0);
}

template <int N> struct VMC { static constexpr int v = N; };

// ---------------------------------------------------------------------------
// prep: router logits + mask + probs, causal depthwise conv (k=3), x -> bf16
// ---------------------------------------------------------------------------
__global__ __launch_bounds__(256) void prep_kernel(
    const float* __restrict__ x, const float* __restrict__ gate_w,
    const float* __restrict__ gate_b, const float* __restrict__ conv_w,
    const float* __restrict__ conv_b, __bf16* __restrict__ xb,
    __bf16* __restrict__ xcb, float* __restrict__ maskp,
    float* __restrict__ probsp) {
  const int tok = blockIdx.x, t = threadIdx.x;
  const int s = tok & (SLEN - 1);
  const float* xr = x + (size_t)tok * DDIM;
  float4 v = ((const float4*)xr)[t];
  float4 g = ((const float4*)gate_w)[t];
  float part = v.x * g.x + v.y * g.y + v.z * g.z + v.w * g.w;
#pragma unroll
  for (int d = 32; d; d >>= 1) part += __shfl_down(part, d);
  __shared__ float ws4[4];
  const int lane = t & 63, w = t >> 6;
  if (lane == 0) ws4[w] = part;
  __syncthreads();
  if (t == 0) {
    float logit = ws4[0] + ws4[1] + ws4[2] + ws4[3] + gate_b[0];
    float prob = 1.f / (1.f + __expf(-logit));
    probsp[tok] = prob;
    maskp[tok] = prob > 0.5f ? 1.f : 0.f;
  }
  union { ushort4 u; __bf16 b[4]; } xo;
  xo.b[0] = (__bf16)v.x; xo.b[1] = (__bf16)v.y;
  xo.b[2] = (__bf16)v.z; xo.b[3] = (__bf16)v.w;
  ((ushort4*)(xb + (size_t)tok * DDIM))[t] = xo.u;
  float4 zero4 = {0.f, 0.f, 0.f, 0.f};
  float4 m1 = (s >= 1) ? ((const float4*)(xr - DDIM))[t] : zero4;
  float4 m2 = (s >= 2) ? ((const float4*)(xr - 2 * DDIM))[t] : zero4;
  int d0 = t * 4;
  float vv[4] = {v.x, v.y, v.z, v.w};
  float a1[4] = {m1.x, m1.y, m1.z, m1.w};
  float a2[4] = {m2.x, m2.y, m2.z, m2.w};
  union { ushort4 u; __bf16 b[4]; } co;
#pragma unroll
  for (int i = 0; i < 4; ++i) {
    float c0 = conv_w[(d0 + i) * 3 + 0];
    float c1 = conv_w[(d0 + i) * 3 + 1];
    float c2 = conv_w[(d0 + i) * 3 + 2];
    float r = a2[i] * c0 + a1[i] * c1 + vv[i] * c2 + conv_b[d0 + i];
    co.b[i] = (__bf16)r;
  }
  ((ushort4*)(xcb + (size_t)tok * DDIM))[t] = co.u;
}

// ---------------------------------------------------------------------------
// RoPE trig table: tab[s][i] = (cos(s*invf(i)), sin(s*invf(i))), s<2048, i<32
// ---------------------------------------------------------------------------
__global__ __launch_bounds__(256) void tabgen_kernel(float2* __restrict__ tab) {
  const int idx = blockIdx.x * 256 + threadIdx.x;  // 65536 total
  const int s = idx >> 5, i = idx & 31;
  float invf = __builtin_amdgcn_exp2f(-(float)i * (13.28771238f / 32.f));
  float fr = (float)s * invf;
  tab[idx] = make_float2(cosf(fr), sinf(fr));
}

// ---------------------------------------------------------------------------
// transposed cast: src [K][N] f32 -> dst [N][K] bf16
// ---------------------------------------------------------------------------
__global__ __launch_bounds__(256) void tcast_kernel(const float* __restrict__ src,
                                                    __bf16* __restrict__ dst,
                                                    int K, int N) {
  __shared__ __bf16 tile[64][65];
  const int n0 = blockIdx.x * 64, k0 = blockIdx.y * 64;
  const int t = threadIdx.x;
  const int cr = (t & 15) * 4;
#pragma unroll
  for (int i = 0; i < 4; ++i) {
    int rr = (t >> 4) + i * 16;
    float4 v = *(const float4*)(src + (size_t)(k0 + rr) * N + n0 + cr);
    tile[rr][cr + 0] = (__bf16)v.x; tile[rr][cr + 1] = (__bf16)v.y;
    tile[rr][cr + 2] = (__bf16)v.z; tile[rr][cr + 3] = (__bf16)v.w;
  }
  __syncthreads();
#pragma unroll
  for (int i = 0; i < 2; ++i) {
    int c = t + i * 256;
    int nl = c >> 3, koff = (c & 7) * 8;
    union { uint4 u; __bf16 b[8]; } o;
#pragma unroll
    for (int j = 0; j < 8; ++j) o.b[j] = tile[koff + j][nl];
    *(uint4*)(dst + (size_t)(n0 + nl) * K + k0 + koff) = o.u;
  }
}

// ---------------------------------------------------------------------------
// 256x256 pipelined GEMM (ring-4, counted vmcnt), optional fused RoPE.
// ROPE: for output blocks with n0 < 2048 (q,k regions of the fused qkv),
// apply rotation in-register at the epilogue: pairs (i, i+32) of a head live
// in fragments (nt, nt+2) of the SAME thread (col = wn + nt*16 + c).
// EPI: 0 = bf16 store; 1 = bf16 relu(v+bias).
// ---------------------------------------------------------------------------
template <int EPI, bool ROPE>
__global__ __launch_bounds__(512, 2) void gemm256p(
    const __bf16* __restrict__ A, const __bf16* __restrict__ Bt,
    const float* __restrict__ bias, const float2* __restrict__ tab,
    __bf16* __restrict__ Cb, int M, int N, int K) {
  extern __shared__ char sm[];
  const int t = threadIdx.x, lane = t & 63, w = t >> 6;
  const int c = lane & 15, g = lane >> 4;
  const int nwg = gridDim.x * gridDim.y;
  const int wgid = blockIdx.y * gridDim.x + blockIdx.x;
  const int swz = (wgid & 7) * (nwg >> 3) + (wgid >> 3);
  const int m0 = (swz / gridDim.x) * 256, n0 = (swz % gridDim.x) * 256;
  const int wm = (w >> 2) * 128, wn = (w & 3) * 64;

  f32x4 acc[8][4] = {};
  const int nk = K >> 5;

  auto stage = [&](int buf, int kt) {
    const int k0 = kt << 5;
    char* base = sm + buf * 32768;
#pragma unroll
    for (int r = 0; r < 2; ++r) {
      int o = ((r * 8 + w) << 10) + (lane << 4);
      int rp = o >> 7;
      int u = (o >> 4) & 7;
      int l = u ^ (rp & 7);
      int mr = rp * 2 + (l >> 2);
      int kk = (l & 3) * 8;
      async16(base + o, A + (size_t)(m0 + mr) * K + k0 + kk);
      async16(base + 16384 + o, Bt + (size_t)(n0 + mr) * K + k0 + kk);
    }
  };

  auto body = [&](auto vmc, int tt, bool dostage) {
    if (dostage) stage((tt + 3) & 3, tt + 3);
    asm volatile("s_waitcnt vmcnt(%0)" ::"n"(decltype(vmc)::v) : "memory");
    __builtin_amdgcn_s_barrier();
    asm volatile("" ::: "memory");
    const char* Ab = sm + (tt & 3) * 32768;
    const char* Bb = Ab + 16384;
    bf16x8 aq[8], bq[4];
#pragma unroll
    for (int nt = 0; nt < 4; ++nt) {
      int row = wn + nt * 16 + c;
      int rp = row >> 1;
      int u = ((row & 1) * 4 + g) ^ (rp & 7);
      bq[nt] = *(const bf16x8*)(Bb + rp * 128 + u * 16);
    }
#pragma unroll
    for (int i = 0; i < 8; ++i) {
      int row = wm + i * 16 + c;
      int rp = row >> 1;
      int u = ((row & 1) * 4 + g) ^ (rp & 7);
      aq[i] = *(const bf16x8*)(Ab + rp * 128 + u * 16);
    }
    __builtin_amdgcn_s_setprio(1);
#pragma unroll
    for (int i = 0; i < 8; ++i)
#pragma unroll
      for (int nt = 0; nt < 4; ++nt)
        acc[i][nt] = __builtin_amdgcn_mfma_f32_16x16x32_bf16(
            aq[i], bq[nt], acc[i][nt], 0, 0, 0);
    __builtin_amdgcn_s_setprio(0);
    __builtin_amdgcn_s_barrier();
    asm volatile("" ::: "memory");
  };

  stage(0, 0);
  stage(1, 1);
  stage(2, 2);
  int tt = 0;
  for (; tt < nk - 3; ++tt) body(VMC<12>{}, tt, true);
  body(VMC<8>{}, tt, false); ++tt;
  body(VMC<4>{}, tt, false); ++tt;
  body(VMC<0>{}, tt, false);

  if (ROPE && n0 < 2048) {
#pragma unroll
    for (int i = 0; i < 8; ++i)
#pragma unroll
      for (int r = 0; r < 4; ++r) {
        int s = (m0 + wm + i * 16 + g * 4 + r) & (SLEN - 1);
        float2 t0 = tab[s * 32 + c];
        float2 t1 = tab[s * 32 + 16 + c];
        float q0 = acc[i][0][r], q2 = acc[i][2][r];
        acc[i][0][r] = q0 * t0.x - q2 * t0.y;
        acc[i][2][r] = q2 * t0.x + q0 * t0.y;
        float q1 = acc[i][1][r], q3 = acc[i][3][r];
        acc[i][1][r] = q1 * t1.x - q3 * t1.y;
        acc[i][3][r] = q3 * t1.x + q1 * t1.y;
      }
  }

#pragma unroll
  for (int i = 0; i < 8; ++i)
#pragma unroll
    for (int nt = 0; nt < 4; ++nt)
#pragma unroll
      for (int r = 0; r < 4; ++r) {
        int row = m0 + wm + i * 16 + g * 4 + r;
        int col = n0 + wn + nt * 16 + c;
        float v = acc[i][nt][r];
        size_t idx = (size_t)row * N + col;
        if constexpr (EPI == 0) {
          Cb[idx] = (__bf16)v;
        } else {
          v += bias[col];
          Cb[idx] = (__bf16)fmaxf(v, 0.f);
        }
      }
}

// ---------------------------------------------------------------------------
// GEMM 128x128 (MLP2/WO): EPI 2 = f32 out = xres+v+bias; 3 = out += mask*v
// ---------------------------------------------------------------------------
template <int EPI>
__global__ __launch_bounds__(256, 3) void gemm_bt(
    const __bf16* __restrict__ A, const __bf16* __restrict__ Bt,
    const float* __restrict__ bias, const float* __restrict__ xres,
    const float* __restrict__ maskp, __bf16* __restrict__ Cb,
    float* __restrict__ Cf, int M, int N, int K) {
  __shared__ char smem[32768];
  char* As = smem;
  char* Bs = smem + 16384;
  const int t = threadIdx.x, lane = t & 63, w = t >> 6;
  const int nwg = gridDim.x * gridDim.y;
  const int wgid = blockIdx.y * gridDim.x + blockIdx.x;
  const int swz = (wgid & 7) * (nwg >> 3) + (wgid >> 3);
  const int m0 = (swz / gridDim.x) * 128, n0 = (swz % gridDim.x) * 128;
  const int wm = (w >> 1) * 64, wn = (w & 1) * 64;
  f32x4 acc[4][4] = {};
  const int nk = K >> 6;
  for (int kt = 0; kt < nk; ++kt) {
    const int k0 = kt << 6;
#pragma unroll
    for (int rd = 0; rd < 4; ++rd) {
      int o = ((rd * 4 + w) << 10) + (lane << 4);
      int row = o >> 7;
      int us = ((o >> 4) & 7) ^ (row & 7);
      async16(As + o, A + (size_t)(m0 + row) * K + k0 + us * 8);
      async16(Bs + o, Bt + (size_t)(n0 + row) * K + k0 + us * 8);
    }
    __syncthreads();
#pragma unroll
    for (int ks = 0; ks < 2; ++ks) {
      bf16x8 af[4], bfr[4];
#pragma unroll
      for (int mt = 0; mt < 4; ++mt) {
        int row = wm + mt * 16 + (lane & 15);
        int u = (ks * 4 + (lane >> 4)) ^ (row & 7);
        af[mt] = *(const bf16x8*)(As + row * 128 + u * 16);
      }
#pragma unroll
      for (int nt = 0; nt < 4; ++nt) {
        int row = wn + nt * 16 + (lane & 15);
        int u = (ks * 4 + (lane >> 4)) ^ (row & 7);
        bfr[nt] = *(const bf16x8*)(Bs + row * 128 + u * 16);
      }
#pragma unroll
      for (int mt = 0; mt < 4; ++mt)
#pragma unroll
        for (int nt = 0; nt < 4; ++nt)
          acc[mt][nt] = __builtin_amdgcn_mfma_f32_16x16x32_bf16(
              af[mt], bfr[nt], acc[mt][nt], 0, 0, 0);
    }
    __syncthreads();
  }
#pragma unroll
  for (int mt = 0; mt < 4; ++mt)
#pragma unroll
    for (int nt = 0; nt < 4; ++nt)
#pragma unroll
      for (int r = 0; r < 4; ++r) {
        int row = m0 + wm + mt * 16 + ((lane >> 4) << 2) + r;
        int col = n0 + wn + nt * 16 + (lane & 15);
        float v = acc[mt][nt][r];
        size_t idx = (size_t)row * N + col;
        if constexpr (EPI == 2) {
          Cf[idx] = xres[idx] + v + bias[col];
        } else {
          Cf[idx] += maskp[row] * v;
        }
      }
}

// ---------------------------------------------------------------------------
// V scatter: regs -> swizzled Vt[d][kj] LDS
// ---------------------------------------------------------------------------
__device__ __forceinline__ void scatterV(char* Vdst, int w, int lane,
                                         float4 va, float4 vb) {
  union { float4 f; __bf16 bv[8]; } u0, u1;
  u0.f = va; u1.f = vb;
#pragma unroll
  for (int j = 0; j < 8; ++j) {
    int d = w * 8 + j;
    int by = d * 128 + (((lane >> 3) ^ (d & 7)) << 4) + ((lane & 7) << 1);
    *(__bf16*)(Vdst + by) = u0.bv[j];
    int d2 = d + 32;
    int by2 = d2 * 128 + (((lane >> 3) ^ (d2 & 7)) << 4) + ((lane & 7) << 1);
    *(__bf16*)(Vdst + by2) = u1.bv[j];
  }
}

// ---------------------------------------------------------------------------
// Flash attention, causal, swapped QK^T, in-lane softmax. Uniform q-tile
// pairs. XCD bh-grouping: the 8 same-bh blocks (sharing one 512KB K/V set)
// get the same blockIdx.x (= XCD under round-robin dispatch), so each XCD's
// L2 holds 8 bh x 512KB = 4MB of K/V (exactly fits) instead of 32MB thrash.
// bh = blockIdx.x*8 + (blockIdx.y&7), qtpair = blockIdx.y>>3 (bijective).
// ---------------------------------------------------------------------------
__global__ __launch_bounds__(256, 3) void attn_kernel(const __bf16* __restrict__ qkv,
                                                      __bf16* __restrict__ ctx) {
  __shared__ char sm[32768];
  const int t = threadIdx.x, lane = t & 63, w = t >> 6;
  const int c = lane & 15, g = lane >> 4, g4 = g * 4;
  const int bh = (int)blockIdx.x * 8 + ((int)blockIdx.y & 7);
  const int qp = (int)blockIdx.y >> 3;
  const int h = bh & 15, b = bh >> 4;
  const size_t tokbase = (size_t)b * SLEN;
  const __bf16* qg = qkv + tokbase * 3072 + h * 64;
  const __bf16* kg = qg + 1024;
  const __bf16* vg = qg + 2048;
  const float SCL = 0.125f * 1.44269504f;  // 1/sqrt(64) * log2(e)
  char* Ps = sm + (w << 12);
  char* Ks = sm + 16384;
  char* Vs = sm + 24576;

  for (int ph = 0; ph < 2; ++ph) {
    const int qt = ph == 0 ? qp : 15 - qp;
    const int q0 = qt * 128;
#pragma unroll
    for (int rd = 0; rd < 4; ++rd) {
      int o = ((rd * 4 + w) << 10) + (lane << 4);
      int row = o >> 7;
      int us = ((o >> 4) & 7) ^ (row & 7);
      async16(sm + o, qg + (size_t)(q0 + row) * 3072 + us * 8);
    }
    __syncthreads();
    bf16x8 qb[2][2];
#pragma unroll
    for (int mt = 0; mt < 2; ++mt)
#pragma unroll
      for (int ks = 0; ks < 2; ++ks) {
        int row = w * 32 + mt * 16 + c;
        int u = (ks * 4 + g) ^ (row & 7);
        qb[mt][ks] = *(const bf16x8*)(sm + row * 128 + u * 16);
      }

    float m_run[2] = {-1e30f, -1e30f}, l_run[2] = {0.f, 0.f};
    f32x4 o_acc[2][4] = {};
    const int nkt = (q0 + 128) >> 6;
    const int wrow0 = q0 + w * 32;

    for (int kt = 0; kt < nkt; ++kt) {
      const int k0 = kt << 6;
#pragma unroll
      for (int rd = 0; rd < 2; ++rd) {
        int o = ((rd * 4 + w) << 10) + (lane << 4);
        int row = o >> 7;
        int us = ((o >> 4) & 7) ^ (row & 7);
        async16(Ks + o, kg + (size_t)(k0 + row) * 3072 + us * 8);
      }
      {
        float4 va = *(const float4*)(vg + (size_t)(k0 + lane) * 3072 + w * 8);
        float4 vb2 = *(const float4*)(vg + (size_t)(k0 + lane) * 3072 + w * 8 + 32);
        scatterV(Vs, w, lane, va, vb2);
      }
      __syncthreads();
      if (k0 <= wrow0 + 31) {
        f32x4 st[4][2] = {};
        __builtin_amdgcn_s_setprio(1);
#pragma unroll
        for (int ks = 0; ks < 2; ++ks) {
          bf16x8 ka[4];
#pragma unroll
          for (int nt = 0; nt < 4; ++nt) {
            int row = nt * 16 + c;
            int u = (ks * 4 + g) ^ (row & 7);
            ka[nt] = *(const bf16x8*)(Ks + row * 128 + u * 16);
          }
#pragma unroll
          for (int nt = 0; nt < 4; ++nt)
#pragma unroll
            for (int mt = 0; mt < 2; ++mt)
              st[nt][mt] = __builtin_amdgcn_mfma_f32_16x16x32_bf16(
                  ka[nt], qb[mt][ks], st[nt][mt], 0, 0, 0);
        }
        __builtin_amdgcn_s_setprio(0);
        const bool needmask = (k0 + 63) > wrow0;
#pragma unroll
        for (int mt = 0; mt < 2; ++mt) {
          float mx = -1e30f;
          if (needmask) {
            int qglob = wrow0 + mt * 16 + c;
#pragma unroll
            for (int nt = 0; nt < 4; ++nt)
#pragma unroll
              for (int r = 0; r < 4; ++r) {
                float sv = st[nt][mt][r] * SCL;
                if (k0 + nt * 16 + g4 + r > qglob) sv = -1e30f;
                st[nt][mt][r] = sv;
                mx = fmaxf(mx, sv);
              }
          } else {
#pragma unroll
            for (int nt = 0; nt < 4; ++nt)
#pragma unroll
              for (int r = 0; r < 4; ++r) {
                float sv = st[nt][mt][r] * SCL;
                st[nt][mt][r] = sv;
                mx = fmaxf(mx, sv);
              }
          }
          mx = fmaxf(mx, __shfl_xor(mx, 16));
          mx = fmaxf(mx, __shfl_xor(mx, 32));
          const bool skip = __all(mx - m_run[mt] <= 8.f) != 0;
          float mnew = skip ? m_run[mt] : fmaxf(m_run[mt], mx);
          float rs = 0.f;
#pragma unroll
          for (int nt = 0; nt < 4; ++nt)
#pragma unroll
            for (int r = 0; r < 4; ++r) {
              float p = __builtin_amdgcn_exp2f(st[nt][mt][r] - mnew);
              st[nt][mt][r] = p;
              rs += p;
            }
          rs += __shfl_xor(rs, 16);
          rs += __shfl_xor(rs, 32);
          if (skip) {
            l_run[mt] += rs;
          } else {
            float fac = __builtin_amdgcn_exp2f(m_run[mt] - mnew);
            m_run[mt] = mnew;
            l_run[mt] = l_run[mt] * fac + rs;
#pragma unroll
            for (int r = 0; r < 4; ++r) {
              float fr = __shfl(fac, g * 20 + r);
#pragma unroll
              for (int dt = 0; dt < 4; ++dt) o_acc[mt][dt][r] *= fr;
            }
          }
          int rowq = mt * 16 + c;
          int rbase = rowq * 128 + 8 * (g & 1);
#pragma unroll
          for (int nt = 0; nt < 4; ++nt) {
            int us = (2 * nt + (g >> 1)) ^ (c & 7);
            union { uint2 v; __bf16 bb[4]; } pp;
            pp.bb[0] = (__bf16)st[nt][mt][0]; pp.bb[1] = (__bf16)st[nt][mt][1];
            pp.bb[2] = (__bf16)st[nt][mt][2]; pp.bb[3] = (__bf16)st[nt][mt][3];
            *(uint2*)(Ps + rbase + us * 16) = pp.v;
          }
        }
        __builtin_amdgcn_s_setprio(1);
#pragma unroll
        for (int ks = 0; ks < 2; ++ks) {
          bf16x8 pa[2], vb[4];
#pragma unroll
          for (int mt = 0; mt < 2; ++mt) {
            int row = mt * 16 + c;
            int u = (ks * 4 + g) ^ (row & 7);
            pa[mt] = *(const bf16x8*)(Ps + row * 128 + u * 16);
          }
#pragma unroll
          for (int dt = 0; dt < 4; ++dt) {
            int row = dt * 16 + c;
            int u = (ks * 4 + g) ^ (row & 7);
            vb[dt] = *(const bf16x8*)(Vs + row * 128 + u * 16);
          }
#pragma unroll
          for (int mt = 0; mt < 2; ++mt)
#pragma unroll
            for (int dt = 0; dt < 4; ++dt)
              o_acc[mt][dt] = __builtin_amdgcn_mfma_f32_16x16x32_bf16(
                  pa[mt], vb[dt], o_acc[mt][dt], 0, 0, 0);
        }
        __builtin_amdgcn_s_setprio(0);
      }
      __syncthreads();
    }
#pragma unroll
    for (int mt = 0; mt < 2; ++mt)
#pragma unroll
      for (int r = 0; r < 4; ++r) {
        float lr = __shfl(l_run[mt], g * 20 + r);
        float inv = 1.f / lr;
        int tokr = q0 + w * 32 + mt * 16 + g4 + r;
#pragma unroll
        for (int dt = 0; dt < 4; ++dt) {
          int d = dt * 16 + c;
          ctx[(tokbase + tokr) * DDIM + h * 64 + d] =
              (__bf16)(o_acc[mt][dt][r] * inv);
        }
      }
  }
}

// ---------------------------------------------------------------------------
// aux loss: (mean(probs) - 0.2)^2
// ---------------------------------------------------------------------------
__global__ __launch_bounds__(256) void aux_kernel(const float* __restrict__ probsp,
                                                  float* __restrict__ outp) {
  const int t = threadIdx.x;
  float sum = 0.f;
  for (int i = t; i < NTOK; i += 256) sum += probsp[i];
#pragma unroll
  for (int d = 32; d; d >>= 1) sum += __shfl_down(sum, d);
  __shared__ float ws4[4];
  if ((t & 63) == 0) ws4[t >> 6] = sum;
  __syncthreads();
  if (t == 0) {
    float m = (ws4[0] + ws4[1] + ws4[2] + ws4[3]) * (1.f / NTOK) - 0.2f;
    outp[0] = m * m;
  }
}

// ---------------------------------------------------------------------------
extern "C" void kernel_launch(void* const* d_in, const int* in_sizes, int n_in,
                              void* d_out, int out_size, void* d_ws, size_t ws_size,
                              hipStream_t stream) {
  const float* x      = (const float*)d_in[0];
  const float* gate_w = (const float*)d_in[1];
  const float* gate_b = (const float*)d_in[2];
  const float* wq     = (const float*)d_in[3];
  const float* wk     = (const float*)d_in[4];
  const float* wv     = (const float*)d_in[5];
  const float* wo     = (const float*)d_in[6];
  const float* conv_w = (const float*)d_in[7];
  const float* conv_b = (const float*)d_in[8];
  const float* mlp_w1 = (const float*)d_in[9];
  const float* mlp_b1 = (const float*)d_in[10];
  const float* mlp_w2 = (const float*)d_in[11];
  const float* mlp_b2 = (const float*)d_in[12];
  float* out = (float*)d_out;

  char* ws = (char*)d_ws;
  const size_t MB = 1ull << 20;
  __bf16* xb     = (__bf16*)(ws + 0);
  __bf16* xcb    = (__bf16*)(ws + 16 * MB);
  __bf16* ctx    = (__bf16*)(ws + 16 * MB);    // overlays xcb
  __bf16* wqkv_t = (__bf16*)(ws + 32 * MB);
  __bf16* wo_t   = (__bf16*)(ws + 38 * MB);
  __bf16* w1_t   = (__bf16*)(ws + 40 * MB);
  __bf16* w2_t   = (__bf16*)(ws + 48 * MB);
  float*  maskp  = (float*)(ws + 56 * MB);
  float*  probsp = (float*)(ws + 56 * MB + 65536);
  float2* ropetab= (float2*)(ws + 56 * MB + 131072);  // 512KB
  __bf16* h1     = (__bf16*)(ws + 57 * MB);
  __bf16* qkv    = (__bf16*)(ws + 57 * MB);    // overlays h1

  prep_kernel<<<NTOK, 256, 0, stream>>>(x, gate_w, gate_b, conv_w, conv_b,
                                        xb, xcb, maskp, probsp);
  tabgen_kernel<<<256, 256, 0, stream>>>(ropetab);
  tcast_kernel<<<dim3(16, 16), 256, 0, stream>>>(wq, wqkv_t, 1024, 1024);
  tcast_kernel<<<dim3(16, 16), 256, 0, stream>>>(wk, wqkv_t + 1024 * 1024, 1024, 1024);
  tcast_kernel<<<dim3(16, 16), 256, 0, stream>>>(wv, wqkv_t + 2048 * 1024, 1024, 1024);
  tcast_kernel<<<dim3(16, 16), 256, 0, stream>>>(wo, wo_t, 1024, 1024);
  tcast_kernel<<<dim3(64, 16), 256, 0, stream>>>(mlp_w1, w1_t, 1024, 4096);
  tcast_kernel<<<dim3(16, 64), 256, 0, stream>>>(mlp_w2, w2_t, 4096, 1024);

  // Reflexive (MLP) stream first so h1 region can be reused by qkv.
  gemm256p<1, false><<<dim3(16, 32), 512, 131072, stream>>>(
      xcb, w1_t, mlp_b1, nullptr, h1, NTOK, MLPD, DDIM);
  gemm_bt<2><<<dim3(8, 64), 256, 0, stream>>>(h1, w2_t, mlp_b2, x, nullptr,
                                              nullptr, out, NTOK, DDIM, MLPD);
  // Contextual stream (RoPE fused into the QKV epilogue).
  gemm256p<0, true><<<dim3(12, 32), 512, 131072, stream>>>(
      xb, wqkv_t, nullptr, ropetab, qkv, NTOK, 3072, DDIM);
  attn_kernel<<<dim3(8, 64), 256, 0, stream>>>(qkv, ctx);
  gemm_bt<3><<<dim3(8, 64), 256, 0, stream>>>(ctx, wo_t, nullptr, nullptr, maskp,
                                              nullptr, out, NTOK, DDIM, DDIM);
  aux_kernel<<<1, 256, 0, stream>>>(probsp, out + (size_t)(out_size - 1));
}

// Round 18
// 375.603 us; speedup vs baseline: 1.0989x; 1.0473x over previous
//
#include <hip/hip_runtime.h>
#include <hip/hip_bf16.h>

#define DDIM 1024
#define SLEN 2048
#define NTOK 8192
#define MLPD 4096

typedef float f32x4 __attribute__((ext_vector_type(4)));
typedef __bf16 bf16x8 __attribute__((ext_vector_type(8)));

__device__ __forceinline__ void async16(void* lds, const void* g) {
  __builtin_amdgcn_global_load_lds(
      (__attribute__((address_space(1))) void*)g,
      (__attribute__((address_space(3))) void*)lds, 16, 0, 0);
}

template <int N> struct VMC { static constexpr int v = N; };

// ---------------------------------------------------------------------------
// prep: router logits + mask + probs, causal depthwise conv (k=3), x -> bf16
// ---------------------------------------------------------------------------
__global__ __launch_bounds__(256) void prep_kernel(
    const float* __restrict__ x, const float* __restrict__ gate_w,
    const float* __restrict__ gate_b, const float* __restrict__ conv_w,
    const float* __restrict__ conv_b, __bf16* __restrict__ xb,
    __bf16* __restrict__ xcb, float* __restrict__ maskp,
    float* __restrict__ probsp) {
  const int tok = blockIdx.x, t = threadIdx.x;
  const int s = tok & (SLEN - 1);
  const float* xr = x + (size_t)tok * DDIM;
  float4 v = ((const float4*)xr)[t];
  float4 g = ((const float4*)gate_w)[t];
  float part = v.x * g.x + v.y * g.y + v.z * g.z + v.w * g.w;
#pragma unroll
  for (int d = 32; d; d >>= 1) part += __shfl_down(part, d);
  __shared__ float ws4[4];
  const int lane = t & 63, w = t >> 6;
  if (lane == 0) ws4[w] = part;
  __syncthreads();
  if (t == 0) {
    float logit = ws4[0] + ws4[1] + ws4[2] + ws4[3] + gate_b[0];
    float prob = 1.f / (1.f + __expf(-logit));
    probsp[tok] = prob;
    maskp[tok] = prob > 0.5f ? 1.f : 0.f;
  }
  union { ushort4 u; __bf16 b[4]; } xo;
  xo.b[0] = (__bf16)v.x; xo.b[1] = (__bf16)v.y;
  xo.b[2] = (__bf16)v.z; xo.b[3] = (__bf16)v.w;
  ((ushort4*)(xb + (size_t)tok * DDIM))[t] = xo.u;
  float4 zero4 = {0.f, 0.f, 0.f, 0.f};
  float4 m1 = (s >= 1) ? ((const float4*)(xr - DDIM))[t] : zero4;
  float4 m2 = (s >= 2) ? ((const float4*)(xr - 2 * DDIM))[t] : zero4;
  int d0 = t * 4;
  float vv[4] = {v.x, v.y, v.z, v.w};
  float a1[4] = {m1.x, m1.y, m1.z, m1.w};
  float a2[4] = {m2.x, m2.y, m2.z, m2.w};
  union { ushort4 u; __bf16 b[4]; } co;
#pragma unroll
  for (int i = 0; i < 4; ++i) {
    float c0 = conv_w[(d0 + i) * 3 + 0];
    float c1 = conv_w[(d0 + i) * 3 + 1];
    float c2 = conv_w[(d0 + i) * 3 + 2];
    float r = a2[i] * c0 + a1[i] * c1 + vv[i] * c2 + conv_b[d0 + i];
    co.b[i] = (__bf16)r;
  }
  ((ushort4*)(xcb + (size_t)tok * DDIM))[t] = co.u;
}

// ---------------------------------------------------------------------------
// RoPE trig table: tab[s][i] = (cos(s*invf(i)), sin(s*invf(i))), s<2048, i<32
// ---------------------------------------------------------------------------
__global__ __launch_bounds__(256) void tabgen_kernel(float2* __restrict__ tab) {
  const int idx = blockIdx.x * 256 + threadIdx.x;  // 65536 total
  const int s = idx >> 5, i = idx & 31;
  float invf = __builtin_amdgcn_exp2f(-(float)i * (13.28771238f / 32.f));
  float fr = (float)s * invf;
  tab[idx] = make_float2(cosf(fr), sinf(fr));
}

// ---------------------------------------------------------------------------
// transposed cast: src [K][N] f32 -> dst [N][K] bf16
// ---------------------------------------------------------------------------
__device__ __forceinline__ void tcast_body(const float* __restrict__ src,
                                           __bf16* __restrict__ dst,
                                           int K, int N, int n0, int k0) {
  __shared__ __bf16 tile[64][65];
  const int t = threadIdx.x;
  const int cr = (t & 15) * 4;
#pragma unroll
  for (int i = 0; i < 4; ++i) {
    int rr = (t >> 4) + i * 16;
    float4 v = *(const float4*)(src + (size_t)(k0 + rr) * N + n0 + cr);
    tile[rr][cr + 0] = (__bf16)v.x; tile[rr][cr + 1] = (__bf16)v.y;
    tile[rr][cr + 2] = (__bf16)v.z; tile[rr][cr + 3] = (__bf16)v.w;
  }
  __syncthreads();
#pragma unroll
  for (int i = 0; i < 2; ++i) {
    int c = t + i * 256;
    int nl = c >> 3, koff = (c & 7) * 8;
    union { uint4 u; __bf16 b[8]; } o;
#pragma unroll
    for (int j = 0; j < 8; ++j) o.b[j] = tile[koff + j][nl];
    *(uint4*)(dst + (size_t)(n0 + nl) * K + k0 + koff) = o.u;
  }
}

__global__ __launch_bounds__(256) void tcast_kernel(const float* __restrict__ src,
                                                    __bf16* __restrict__ dst,
                                                    int K, int N) {
  tcast_body(src, dst, K, N, blockIdx.x * 64, blockIdx.y * 64);
}

// merged 1024x1024 casts: z in 0..3 selects {wq,wk,wv -> wqkv_t} and {wo -> wo_t}
__global__ __launch_bounds__(256) void tcast4_kernel(
    const float* __restrict__ s0, const float* __restrict__ s1,
    const float* __restrict__ s2, const float* __restrict__ s3,
    __bf16* __restrict__ dqkv, __bf16* __restrict__ dwo) {
  const int z = blockIdx.z;
  const float* src = z == 0 ? s0 : z == 1 ? s1 : z == 2 ? s2 : s3;
  __bf16* dst = z < 3 ? dqkv + (size_t)z * 1024 * 1024 : dwo;
  tcast_body(src, dst, 1024, 1024, blockIdx.x * 64, blockIdx.y * 64);
}

// ---------------------------------------------------------------------------
// 256x256 pipelined GEMM (ring-4, counted vmcnt), optional fused RoPE.
// EPI: 0 = bf16 store; 1 = bf16 relu(v+bias).
// ---------------------------------------------------------------------------
template <int EPI, bool ROPE>
__global__ __launch_bounds__(512, 2) void gemm256p(
    const __bf16* __restrict__ A, const __bf16* __restrict__ Bt,
    const float* __restrict__ bias, const float2* __restrict__ tab,
    __bf16* __restrict__ Cb, int M, int N, int K) {
  extern __shared__ char sm[];
  const int t = threadIdx.x, lane = t & 63, w = t >> 6;
  const int c = lane & 15, g = lane >> 4;
  const int nwg = gridDim.x * gridDim.y;
  const int wgid = blockIdx.y * gridDim.x + blockIdx.x;
  const int swz = (wgid & 7) * (nwg >> 3) + (wgid >> 3);
  const int m0 = (swz / gridDim.x) * 256, n0 = (swz % gridDim.x) * 256;
  const int wm = (w >> 2) * 128, wn = (w & 3) * 64;

  f32x4 acc[8][4] = {};
  const int nk = K >> 5;

  auto stage = [&](int buf, int kt) {
    const int k0 = kt << 5;
    char* base = sm + buf * 32768;
#pragma unroll
    for (int r = 0; r < 2; ++r) {
      int o = ((r * 8 + w) << 10) + (lane << 4);
      int rp = o >> 7;
      int u = (o >> 4) & 7;
      int l = u ^ (rp & 7);
      int mr = rp * 2 + (l >> 2);
      int kk = (l & 3) * 8;
      async16(base + o, A + (size_t)(m0 + mr) * K + k0 + kk);
      async16(base + 16384 + o, Bt + (size_t)(n0 + mr) * K + k0 + kk);
    }
  };

  auto body = [&](auto vmc, int tt, bool dostage) {
    if (dostage) stage((tt + 3) & 3, tt + 3);
    asm volatile("s_waitcnt vmcnt(%0)" ::"n"(decltype(vmc)::v) : "memory");
    __builtin_amdgcn_s_barrier();
    asm volatile("" ::: "memory");
    const char* Ab = sm + (tt & 3) * 32768;
    const char* Bb = Ab + 16384;
    bf16x8 aq[8], bq[4];
#pragma unroll
    for (int nt = 0; nt < 4; ++nt) {
      int row = wn + nt * 16 + c;
      int rp = row >> 1;
      int u = ((row & 1) * 4 + g) ^ (rp & 7);
      bq[nt] = *(const bf16x8*)(Bb + rp * 128 + u * 16);
    }
#pragma unroll
    for (int i = 0; i < 8; ++i) {
      int row = wm + i * 16 + c;
      int rp = row >> 1;
      int u = ((row & 1) * 4 + g) ^ (rp & 7);
      aq[i] = *(const bf16x8*)(Ab + rp * 128 + u * 16);
    }
    __builtin_amdgcn_s_setprio(1);
#pragma unroll
    for (int i = 0; i < 8; ++i)
#pragma unroll
      for (int nt = 0; nt < 4; ++nt)
        acc[i][nt] = __builtin_amdgcn_mfma_f32_16x16x32_bf16(
            aq[i], bq[nt], acc[i][nt], 0, 0, 0);
    __builtin_amdgcn_s_setprio(0);
    __builtin_amdgcn_s_barrier();
    asm volatile("" ::: "memory");
  };

  stage(0, 0);
  stage(1, 1);
  stage(2, 2);
  int tt = 0;
  for (; tt < nk - 3; ++tt) body(VMC<12>{}, tt, true);
  body(VMC<8>{}, tt, false); ++tt;
  body(VMC<4>{}, tt, false); ++tt;
  body(VMC<0>{}, tt, false);

  if (ROPE && n0 < 2048) {
#pragma unroll
    for (int i = 0; i < 8; ++i)
#pragma unroll
      for (int r = 0; r < 4; ++r) {
        int s = (m0 + wm + i * 16 + g * 4 + r) & (SLEN - 1);
        float2 t0 = tab[s * 32 + c];
        float2 t1 = tab[s * 32 + 16 + c];
        float q0 = acc[i][0][r], q2 = acc[i][2][r];
        acc[i][0][r] = q0 * t0.x - q2 * t0.y;
        acc[i][2][r] = q2 * t0.x + q0 * t0.y;
        float q1 = acc[i][1][r], q3 = acc[i][3][r];
        acc[i][1][r] = q1 * t1.x - q3 * t1.y;
        acc[i][3][r] = q3 * t1.x + q1 * t1.y;
      }
  }

#pragma unroll
  for (int i = 0; i < 8; ++i)
#pragma unroll
    for (int nt = 0; nt < 4; ++nt)
#pragma unroll
      for (int r = 0; r < 4; ++r) {
        int row = m0 + wm + i * 16 + g * 4 + r;
        int col = n0 + wn + nt * 16 + c;
        float v = acc[i][nt][r];
        size_t idx = (size_t)row * N + col;
        if constexpr (EPI == 0) {
          Cb[idx] = (__bf16)v;
        } else {
          v += bias[col];
          Cb[idx] = (__bf16)fmaxf(v, 0.f);
        }
      }
}

// ---------------------------------------------------------------------------
// GEMM 128x128 (MLP2/WO): EPI 2 = f32 out = xres+v+bias; 3 = out += mask*v
// ---------------------------------------------------------------------------
template <int EPI>
__global__ __launch_bounds__(256, 3) void gemm_bt(
    const __bf16* __restrict__ A, const __bf16* __restrict__ Bt,
    const float* __restrict__ bias, const float* __restrict__ xres,
    const float* __restrict__ maskp, __bf16* __restrict__ Cb,
    float* __restrict__ Cf, int M, int N, int K) {
  __shared__ char smem[32768];
  char* As = smem;
  char* Bs = smem + 16384;
  const int t = threadIdx.x, lane = t & 63, w = t >> 6;
  const int nwg = gridDim.x * gridDim.y;
  const int wgid = blockIdx.y * gridDim.x + blockIdx.x;
  const int swz = (wgid & 7) * (nwg >> 3) + (wgid >> 3);
  const int m0 = (swz / gridDim.x) * 128, n0 = (swz % gridDim.x) * 128;
  const int wm = (w >> 1) * 64, wn = (w & 1) * 64;
  f32x4 acc[4][4] = {};
  const int nk = K >> 6;
  for (int kt = 0; kt < nk; ++kt) {
    const int k0 = kt << 6;
#pragma unroll
    for (int rd = 0; rd < 4; ++rd) {
      int o = ((rd * 4 + w) << 10) + (lane << 4);
      int row = o >> 7;
      int us = ((o >> 4) & 7) ^ (row & 7);
      async16(As + o, A + (size_t)(m0 + row) * K + k0 + us * 8);
      async16(Bs + o, Bt + (size_t)(n0 + row) * K + k0 + us * 8);
    }
    __syncthreads();
#pragma unroll
    for (int ks = 0; ks < 2; ++ks) {
      bf16x8 af[4], bfr[4];
#pragma unroll
      for (int mt = 0; mt < 4; ++mt) {
        int row = wm + mt * 16 + (lane & 15);
        int u = (ks * 4 + (lane >> 4)) ^ (row & 7);
        af[mt] = *(const bf16x8*)(As + row * 128 + u * 16);
      }
#pragma unroll
      for (int nt = 0; nt < 4; ++nt) {
        int row = wn + nt * 16 + (lane & 15);
        int u = (ks * 4 + (lane >> 4)) ^ (row & 7);
        bfr[nt] = *(const bf16x8*)(Bs + row * 128 + u * 16);
      }
#pragma unroll
      for (int mt = 0; mt < 4; ++mt)
#pragma unroll
        for (int nt = 0; nt < 4; ++nt)
          acc[mt][nt] = __builtin_amdgcn_mfma_f32_16x16x32_bf16(
              af[mt], bfr[nt], acc[mt][nt], 0, 0, 0);
    }
    __syncthreads();
  }
#pragma unroll
  for (int mt = 0; mt < 4; ++mt)
#pragma unroll
    for (int nt = 0; nt < 4; ++nt)
#pragma unroll
      for (int r = 0; r < 4; ++r) {
        int row = m0 + wm + mt * 16 + ((lane >> 4) << 2) + r;
        int col = n0 + wn + nt * 16 + (lane & 15);
        float v = acc[mt][nt][r];
        size_t idx = (size_t)row * N + col;
        if constexpr (EPI == 2) {
          Cf[idx] = xres[idx] + v + bias[col];
        } else {
          Cf[idx] += maskp[row] * v;
        }
      }
}

// ---------------------------------------------------------------------------
// V scatter (8-wave): wave w owns d = w*8..w*8+7, lane = k-token
// ---------------------------------------------------------------------------
__device__ __forceinline__ void scatterV8(char* Vdst, int w, int lane, float4 va) {
  union { float4 f; __bf16 bv[8]; } u0;
  u0.f = va;
#pragma unroll
  for (int j = 0; j < 8; ++j) {
    int d = w * 8 + j;
    int by = d * 128 + (((lane >> 3) ^ (d & 7)) << 4) + ((lane & 7) << 1);
    *(__bf16*)(Vdst + by) = u0.bv[j];
  }
}

// ---------------------------------------------------------------------------
// Flash attention, causal, swapped QK^T, in-lane softmax — 8-WAVE version.
// 512 threads (8 waves x 16 q-rows), launch_bounds(512,4): 2 blocks/CU =
// 16 waves/CU. Grid 512 uniform q-tile-pair blocks, all resident. Per-wave
// state ~70 VGPR < 128 budget. LDS 32KB; Q->P overlay wave-private (wave w
// qb rows w*16.. = its 2KB P region). XCD bh-grouping. Defer-max THR=8.
// ---------------------------------------------------------------------------
__global__ __launch_bounds__(512, 4) void attn_kernel(const __bf16* __restrict__ qkv,
                                                      __bf16* __restrict__ ctx) {
  __shared__ char sm[32768];
  const int t = threadIdx.x, lane = t & 63, w = t >> 6;  // w in 0..7
  const int c = lane & 15, g = lane >> 4, g4 = g * 4;
  const int bh = (int)blockIdx.x * 8 + ((int)blockIdx.y & 7);
  const int qp = (int)blockIdx.y >> 3;
  const int h = bh & 15, b = bh >> 4;
  const size_t tokbase = (size_t)b * SLEN;
  const __bf16* qg = qkv + tokbase * 3072 + h * 64;
  const __bf16* kg = qg + 1024;
  const __bf16* vg = qg + 2048;
  const float SCL = 0.125f * 1.44269504f;  // 1/sqrt(64) * log2(e)
  char* Ps = sm + (w << 11);   // 2KB per wave
  char* Ks = sm + 16384;
  char* Vs = sm + 24576;

  for (int ph = 0; ph < 2; ++ph) {
    const int qt = ph == 0 ? qp : 15 - qp;
    const int q0 = qt * 128;
    // stage Q (16KB, 2 rounds of 512x16B)
#pragma unroll
    for (int rd = 0; rd < 2; ++rd) {
      int o = ((rd * 8 + w) << 10) + (lane << 4);
      int row = o >> 7;
      int us = ((o >> 4) & 7) ^ (row & 7);
      async16(sm + o, qg + (size_t)(q0 + row) * 3072 + us * 8);
    }
    __syncthreads();
    bf16x8 qb[2];  // B-frag: Q[q][d]; wave w rows w*16..w*16+15 (own P region)
#pragma unroll
    for (int ks = 0; ks < 2; ++ks) {
      int row = w * 16 + c;
      int u = (ks * 4 + g) ^ (row & 7);
      qb[ks] = *(const bf16x8*)(sm + row * 128 + u * 16);
    }

    float m_run = -1e30f, l_run = 0.f;
    f32x4 o_acc[4] = {};
    const int nkt = (q0 + 128) >> 6;
    const int wrow0 = q0 + w * 16;

    for (int kt = 0; kt < nkt; ++kt) {
      const int k0 = kt << 6;
      {
        int o = (w << 10) + (lane << 4);  // 8KB K tile, 1 round
        int row = o >> 7;
        int us = ((o >> 4) & 7) ^ (row & 7);
        async16(Ks + o, kg + (size_t)(k0 + row) * 3072 + us * 8);
        float4 va = *(const float4*)(vg + (size_t)(k0 + lane) * 3072 + w * 8);
        scatterV8(Vs, w, lane, va);
      }
      __syncthreads();
      if (k0 <= wrow0 + 15) {
        f32x4 st[4] = {};
        __builtin_amdgcn_s_setprio(1);
#pragma unroll
        for (int ks = 0; ks < 2; ++ks) {
          bf16x8 ka[4];
#pragma unroll
          for (int nt = 0; nt < 4; ++nt) {
            int row = nt * 16 + c;
            int u = (ks * 4 + g) ^ (row & 7);
            ka[nt] = *(const bf16x8*)(Ks + row * 128 + u * 16);
          }
#pragma unroll
          for (int nt = 0; nt < 4; ++nt)
            st[nt] = __builtin_amdgcn_mfma_f32_16x16x32_bf16(
                ka[nt], qb[ks], st[nt], 0, 0, 0);
        }
        __builtin_amdgcn_s_setprio(0);
        const bool needmask = (k0 + 63) > wrow0;
        float mx = -1e30f;
        if (needmask) {
          int qglob = wrow0 + c;
#pragma unroll
          for (int nt = 0; nt < 4; ++nt)
#pragma unroll
            for (int r = 0; r < 4; ++r) {
              float sv = st[nt][r] * SCL;
              if (k0 + nt * 16 + g4 + r > qglob) sv = -1e30f;
              st[nt][r] = sv;
              mx = fmaxf(mx, sv);
            }
        } else {
#pragma unroll
          for (int nt = 0; nt < 4; ++nt)
#pragma unroll
            for (int r = 0; r < 4; ++r) {
              float sv = st[nt][r] * SCL;
              st[nt][r] = sv;
              mx = fmaxf(mx, sv);
            }
        }
        mx = fmaxf(mx, __shfl_xor(mx, 16));
        mx = fmaxf(mx, __shfl_xor(mx, 32));
        const bool skip = __all(mx - m_run <= 8.f) != 0;
        float mnew = skip ? m_run : fmaxf(m_run, mx);
        float rs = 0.f;
#pragma unroll
        for (int nt = 0; nt < 4; ++nt)
#pragma unroll
          for (int r = 0; r < 4; ++r) {
            float p = __builtin_amdgcn_exp2f(st[nt][r] - mnew);
            st[nt][r] = p;
            rs += p;
          }
        rs += __shfl_xor(rs, 16);
        rs += __shfl_xor(rs, 32);
        if (skip) {
          l_run += rs;
        } else {
          float fac = __builtin_amdgcn_exp2f(m_run - mnew);
          m_run = mnew;
          l_run = l_run * fac + rs;
#pragma unroll
          for (int r = 0; r < 4; ++r) {
            float fr = __shfl(fac, g * 20 + r);  // lane (g<<4)|(g*4+r)
#pragma unroll
            for (int dt = 0; dt < 4; ++dt) o_acc[dt][r] *= fr;
          }
        }
        // P row c -> per-wave LDS (swizzled uint2)
        {
          int rbase = c * 128 + 8 * (g & 1);
#pragma unroll
          for (int nt = 0; nt < 4; ++nt) {
            int us = (2 * nt + (g >> 1)) ^ (c & 7);
            union { uint2 v; __bf16 bb[4]; } pp;
            pp.bb[0] = (__bf16)st[nt][0]; pp.bb[1] = (__bf16)st[nt][1];
            pp.bb[2] = (__bf16)st[nt][2]; pp.bb[3] = (__bf16)st[nt][3];
            *(uint2*)(Ps + rbase + us * 16) = pp.v;
          }
        }
        // PV
        __builtin_amdgcn_s_setprio(1);
#pragma unroll
        for (int ks = 0; ks < 2; ++ks) {
          bf16x8 pa, vb[4];
          {
            int u = (ks * 4 + g) ^ (c & 7);
            pa = *(const bf16x8*)(Ps + c * 128 + u * 16);
          }
#pragma unroll
          for (int dt = 0; dt < 4; ++dt) {
            int row = dt * 16 + c;
            int u = (ks * 4 + g) ^ (row & 7);
            vb[dt] = *(const bf16x8*)(Vs + row * 128 + u * 16);
          }
#pragma unroll
          for (int dt = 0; dt < 4; ++dt)
            o_acc[dt] = __builtin_amdgcn_mfma_f32_16x16x32_bf16(
                pa, vb[dt], o_acc[dt], 0, 0, 0);
        }
        __builtin_amdgcn_s_setprio(0);
      }
      __syncthreads();
    }
    // epilogue
#pragma unroll
    for (int r = 0; r < 4; ++r) {
      float lr = __shfl(l_run, g * 20 + r);
      float inv = 1.f / lr;
      int tokr = q0 + w * 16 + g4 + r;
#pragma unroll
      for (int dt = 0; dt < 4; ++dt) {
        int d = dt * 16 + c;
        ctx[(tokbase + tokr) * DDIM + h * 64 + d] =
            (__bf16)(o_acc[dt][r] * inv);
      }
    }
  }
}

// ---------------------------------------------------------------------------
// aux loss: (mean(probs) - 0.2)^2
// ---------------------------------------------------------------------------
__global__ __launch_bounds__(256) void aux_kernel(const float* __restrict__ probsp,
                                                  float* __restrict__ outp) {
  const int t = threadIdx.x;
  float sum = 0.f;
  for (int i = t; i < NTOK; i += 256) sum += probsp[i];
#pragma unroll
  for (int d = 32; d; d >>= 1) sum += __shfl_down(sum, d);
  __shared__ float ws4[4];
  if ((t & 63) == 0) ws4[t >> 6] = sum;
  __syncthreads();
  if (t == 0) {
    float m = (ws4[0] + ws4[1] + ws4[2] + ws4[3]) * (1.f / NTOK) - 0.2f;
    outp[0] = m * m;
  }
}

// ---------------------------------------------------------------------------
extern "C" void kernel_launch(void* const* d_in, const int* in_sizes, int n_in,
                              void* d_out, int out_size, void* d_ws, size_t ws_size,
                              hipStream_t stream) {
  const float* x      = (const float*)d_in[0];
  const float* gate_w = (const float*)d_in[1];
  const float* gate_b = (const float*)d_in[2];
  const float* wq     = (const float*)d_in[3];
  const float* wk     = (const float*)d_in[4];
  const float* wv     = (const float*)d_in[5];
  const float* wo     = (const float*)d_in[6];
  const float* conv_w = (const float*)d_in[7];
  const float* conv_b = (const float*)d_in[8];
  const float* mlp_w1 = (const float*)d_in[9];
  const float* mlp_b1 = (const float*)d_in[10];
  const float* mlp_w2 = (const float*)d_in[11];
  const float* mlp_b2 = (const float*)d_in[12];
  float* out = (float*)d_out;

  char* ws = (char*)d_ws;
  const size_t MB = 1ull << 20;
  __bf16* xb     = (__bf16*)(ws + 0);
  __bf16* xcb    = (__bf16*)(ws + 16 * MB);
  __bf16* ctx    = (__bf16*)(ws + 16 * MB);    // overlays xcb
  __bf16* wqkv_t = (__bf16*)(ws + 32 * MB);
  __bf16* wo_t   = (__bf16*)(ws + 38 * MB);
  __bf16* w1_t   = (__bf16*)(ws + 40 * MB);
  __bf16* w2_t   = (__bf16*)(ws + 48 * MB);
  float*  maskp  = (float*)(ws + 56 * MB);
  float*  probsp = (float*)(ws + 56 * MB + 65536);
  float2* ropetab= (float2*)(ws + 56 * MB + 131072);  // 512KB
  __bf16* h1     = (__bf16*)(ws + 57 * MB);
  __bf16* qkv    = (__bf16*)(ws + 57 * MB);    // overlays h1

  prep_kernel<<<NTOK, 256, 0, stream>>>(x, gate_w, gate_b, conv_w, conv_b,
                                        xb, xcb, maskp, probsp);
  tabgen_kernel<<<256, 256, 0, stream>>>(ropetab);
  tcast4_kernel<<<dim3(16, 16, 4), 256, 0, stream>>>(wq, wk, wv, wo,
                                                     wqkv_t, wo_t);
  tcast_kernel<<<dim3(64, 16), 256, 0, stream>>>(mlp_w1, w1_t, 1024, 4096);
  tcast_kernel<<<dim3(16, 64), 256, 0, stream>>>(mlp_w2, w2_t, 4096, 1024);

  // Reflexive (MLP) stream first so h1 region can be reused by qkv.
  gemm256p<1, false><<<dim3(16, 32), 512, 131072, stream>>>(
      xcb, w1_t, mlp_b1, nullptr, h1, NTOK, MLPD, DDIM);
  gemm_bt<2><<<dim3(8, 64), 256, 0, stream>>>(h1, w2_t, mlp_b2, x, nullptr,
                                              nullptr, out, NTOK, DDIM, MLPD);
  // Contextual stream (RoPE fused into the QKV epilogue).
  gemm256p<0, true><<<dim3(12, 32), 512, 131072, stream>>>(
      xb, wqkv_t, nullptr, ropetab, qkv, NTOK, 3072, DDIM);
  attn_kernel<<<dim3(8, 64), 512, 0, stream>>>(qkv, ctx);
  gemm_bt<3><<<dim3(8, 64), 256, 0, stream>>>(ctx, wo_t, nullptr, nullptr, maskp,
                                              nullptr, out, NTOK, DDIM, DDIM);
  aux_kernel<<<1, 256, 0, stream>>>(probsp, out + (size_t)(out_size - 1));
}

// Round 21
// 370.185 us; speedup vs baseline: 1.1150x; 1.0146x over previous
//
#include <hip/hip_runtime.h>
#include <hip/hip_bf16.h>

#define DDIM 1024
#define SLEN 2048
#define NTOK 8192
#define MLPD 4096

typedef float f32x4 __attribute__((ext_vector_type(4)));
typedef __bf16 bf16x8 __attribute__((ext_vector_type(8)));

__device__ __forceinline__ void async16(void* lds, const void* g) {
  __builtin_amdgcn_global_load_lds(
      (__attribute__((address_space(1))) void*)g,
      (__attribute__((address_space(3))) void*)lds, 16, 0, 0);
}

template <int N> struct VMC { static constexpr int v = N; };

// ---------------------------------------------------------------------------
// prep: router logits + mask + probs, causal depthwise conv (k=3), x -> bf16
// ---------------------------------------------------------------------------
__global__ __launch_bounds__(256) void prep_kernel(
    const float* __restrict__ x, const float* __restrict__ gate_w,
    const float* __restrict__ gate_b, const float* __restrict__ conv_w,
    const float* __restrict__ conv_b, __bf16* __restrict__ xb,
    __bf16* __restrict__ xcb, float* __restrict__ maskp,
    float* __restrict__ probsp) {
  const int tok = blockIdx.x, t = threadIdx.x;
  const int s = tok & (SLEN - 1);
  const float* xr = x + (size_t)tok * DDIM;
  float4 v = ((const float4*)xr)[t];
  float4 g = ((const float4*)gate_w)[t];
  float part = v.x * g.x + v.y * g.y + v.z * g.z + v.w * g.w;
#pragma unroll
  for (int d = 32; d; d >>= 1) part += __shfl_down(part, d);
  __shared__ float ws4[4];
  const int lane = t & 63, w = t >> 6;
  if (lane == 0) ws4[w] = part;
  __syncthreads();
  if (t == 0) {
    float logit = ws4[0] + ws4[1] + ws4[2] + ws4[3] + gate_b[0];
    float prob = 1.f / (1.f + __expf(-logit));
    probsp[tok] = prob;
    maskp[tok] = prob > 0.5f ? 1.f : 0.f;
  }
  union { ushort4 u; __bf16 b[4]; } xo;
  xo.b[0] = (__bf16)v.x; xo.b[1] = (__bf16)v.y;
  xo.b[2] = (__bf16)v.z; xo.b[3] = (__bf16)v.w;
  ((ushort4*)(xb + (size_t)tok * DDIM))[t] = xo.u;
  float4 zero4 = {0.f, 0.f, 0.f, 0.f};
  float4 m1 = (s >= 1) ? ((const float4*)(xr - DDIM))[t] : zero4;
  float4 m2 = (s >= 2) ? ((const float4*)(xr - 2 * DDIM))[t] : zero4;
  int d0 = t * 4;
  float vv[4] = {v.x, v.y, v.z, v.w};
  float a1[4] = {m1.x, m1.y, m1.z, m1.w};
  float a2[4] = {m2.x, m2.y, m2.z, m2.w};
  union { ushort4 u; __bf16 b[4]; } co;
#pragma unroll
  for (int i = 0; i < 4; ++i) {
    float c0 = conv_w[(d0 + i) * 3 + 0];
    float c1 = conv_w[(d0 + i) * 3 + 1];
    float c2 = conv_w[(d0 + i) * 3 + 2];
    float r = a2[i] * c0 + a1[i] * c1 + vv[i] * c2 + conv_b[d0 + i];
    co.b[i] = (__bf16)r;
  }
  ((ushort4*)(xcb + (size_t)tok * DDIM))[t] = co.u;
}

// ---------------------------------------------------------------------------
// RoPE trig table: tab[s][i] = (cos(s*invf(i)), sin(s*invf(i))), s<2048, i<32
// ---------------------------------------------------------------------------
__global__ __launch_bounds__(256) void tabgen_kernel(float2* __restrict__ tab) {
  const int idx = blockIdx.x * 256 + threadIdx.x;  // 65536 total
  const int s = idx >> 5, i = idx & 31;
  float invf = __builtin_amdgcn_exp2f(-(float)i * (13.28771238f / 32.f));
  float fr = (float)s * invf;
  tab[idx] = make_float2(cosf(fr), sinf(fr));
}

// ---------------------------------------------------------------------------
// transposed cast: src [K][N] f32 -> dst [N][K] bf16
// ---------------------------------------------------------------------------
__device__ __forceinline__ void tcast_body(const float* __restrict__ src,
                                           __bf16* __restrict__ dst,
                                           int K, int N, int n0, int k0) {
  __shared__ __bf16 tile[64][65];
  const int t = threadIdx.x;
  const int cr = (t & 15) * 4;
#pragma unroll
  for (int i = 0; i < 4; ++i) {
    int rr = (t >> 4) + i * 16;
    float4 v = *(const float4*)(src + (size_t)(k0 + rr) * N + n0 + cr);
    tile[rr][cr + 0] = (__bf16)v.x; tile[rr][cr + 1] = (__bf16)v.y;
    tile[rr][cr + 2] = (__bf16)v.z; tile[rr][cr + 3] = (__bf16)v.w;
  }
  __syncthreads();
#pragma unroll
  for (int i = 0; i < 2; ++i) {
    int c = t + i * 256;
    int nl = c >> 3, koff = (c & 7) * 8;
    union { uint4 u; __bf16 b[8]; } o;
#pragma unroll
    for (int j = 0; j < 8; ++j) o.b[j] = tile[koff + j][nl];
    *(uint4*)(dst + (size_t)(n0 + nl) * K + k0 + koff) = o.u;
  }
}

__global__ __launch_bounds__(256) void tcast_kernel(const float* __restrict__ src,
                                                    __bf16* __restrict__ dst,
                                                    int K, int N) {
  tcast_body(src, dst, K, N, blockIdx.x * 64, blockIdx.y * 64);
}

// merged 1024x1024 casts: z in 0..3 selects {wq,wk,wv -> wqkv_t} and {wo -> wo_t}
__global__ __launch_bounds__(256) void tcast4_kernel(
    const float* __restrict__ s0, const float* __restrict__ s1,
    const float* __restrict__ s2, const float* __restrict__ s3,
    __bf16* __restrict__ dqkv, __bf16* __restrict__ dwo) {
  const int z = blockIdx.z;
  const float* src = z == 0 ? s0 : z == 1 ? s1 : z == 2 ? s2 : s3;
  __bf16* dst = z < 3 ? dqkv + (size_t)z * 1024 * 1024 : dwo;
  tcast_body(src, dst, 1024, 1024, blockIdx.x * 64, blockIdx.y * 64);
}

// ---------------------------------------------------------------------------
// 256x256 pipelined GEMM (ring-4, counted vmcnt). EPI: bf16 relu(v+bias).
// Used for MLP1 only (grid 512 = 2 exact occupancy rounds at 1 block/CU).
// ---------------------------------------------------------------------------
__global__ __launch_bounds__(512, 2) void gemm256p(
    const __bf16* __restrict__ A, const __bf16* __restrict__ Bt,
    const float* __restrict__ bias, __bf16* __restrict__ Cb,
    int M, int N, int K) {
  extern __shared__ char sm[];
  const int t = threadIdx.x, lane = t & 63, w = t >> 6;
  const int c = lane & 15, g = lane >> 4;
  const int nwg = gridDim.x * gridDim.y;
  const int wgid = blockIdx.y * gridDim.x + blockIdx.x;
  const int swz = (wgid & 7) * (nwg >> 3) + (wgid >> 3);
  const int m0 = (swz / gridDim.x) * 256, n0 = (swz % gridDim.x) * 256;
  const int wm = (w >> 2) * 128, wn = (w & 3) * 64;

  f32x4 acc[8][4] = {};
  const int nk = K >> 5;

  auto stage = [&](int buf, int kt) {
    const int k0 = kt << 5;
    char* base = sm + buf * 32768;
#pragma unroll
    for (int r = 0; r < 2; ++r) {
      int o = ((r * 8 + w) << 10) + (lane << 4);
      int rp = o >> 7;
      int u = (o >> 4) & 7;
      int l = u ^ (rp & 7);
      int mr = rp * 2 + (l >> 2);
      int kk = (l & 3) * 8;
      async16(base + o, A + (size_t)(m0 + mr) * K + k0 + kk);
      async16(base + 16384 + o, Bt + (size_t)(n0 + mr) * K + k0 + kk);
    }
  };

  auto body = [&](auto vmc, int tt, bool dostage) {
    if (dostage) stage((tt + 3) & 3, tt + 3);
    asm volatile("s_waitcnt vmcnt(%0)" ::"n"(decltype(vmc)::v) : "memory");
    __builtin_amdgcn_s_barrier();
    asm volatile("" ::: "memory");
    const char* Ab = sm + (tt & 3) * 32768;
    const char* Bb = Ab + 16384;
    bf16x8 aq[8], bq[4];
#pragma unroll
    for (int nt = 0; nt < 4; ++nt) {
      int row = wn + nt * 16 + c;
      int rp = row >> 1;
      int u = ((row & 1) * 4 + g) ^ (rp & 7);
      bq[nt] = *(const bf16x8*)(Bb + rp * 128 + u * 16);
    }
#pragma unroll
    for (int i = 0; i < 8; ++i) {
      int row = wm + i * 16 + c;
      int rp = row >> 1;
      int u = ((row & 1) * 4 + g) ^ (rp & 7);
      aq[i] = *(const bf16x8*)(Ab + rp * 128 + u * 16);
    }
    __builtin_amdgcn_s_setprio(1);
#pragma unroll
    for (int i = 0; i < 8; ++i)
#pragma unroll
      for (int nt = 0; nt < 4; ++nt)
        acc[i][nt] = __builtin_amdgcn_mfma_f32_16x16x32_bf16(
            aq[i], bq[nt], acc[i][nt], 0, 0, 0);
    __builtin_amdgcn_s_setprio(0);
    __builtin_amdgcn_s_barrier();
    asm volatile("" ::: "memory");
  };

  stage(0, 0);
  stage(1, 1);
  stage(2, 2);
  int tt = 0;
  for (; tt < nk - 3; ++tt) body(VMC<12>{}, tt, true);
  body(VMC<8>{}, tt, false); ++tt;
  body(VMC<4>{}, tt, false); ++tt;
  body(VMC<0>{}, tt, false);

#pragma unroll
  for (int i = 0; i < 8; ++i)
#pragma unroll
    for (int nt = 0; nt < 4; ++nt)
#pragma unroll
      for (int r = 0; r < 4; ++r) {
        int row = m0 + wm + i * 16 + g * 4 + r;
        int col = n0 + wn + nt * 16 + c;
        float v = acc[i][nt][r] + bias[col];
        Cb[(size_t)row * N + col] = (__bf16)fmaxf(v, 0.f);
      }
}

// ---------------------------------------------------------------------------
// GEMM 128x128 for QKV with fused RoPE: bf16 store; for n0 < 2048 (q,k
// regions) rotate pairs (i, i+32) which live in fragments (nt, nt+2) of the
// same thread (i = nt*16 + c for nt in {0,1}); s = row & 2047.
// Grid (24,64) = 1536 blocks at 3/CU = exactly 2 full occupancy rounds.
// ---------------------------------------------------------------------------
__global__ __launch_bounds__(256, 3) void gemm_btq(
    const __bf16* __restrict__ A, const __bf16* __restrict__ Bt,
    const float2* __restrict__ tab, __bf16* __restrict__ Cb,
    int M, int N, int K) {
  __shared__ char smem[32768];
  char* As = smem;
  char* Bs = smem + 16384;
  const int t = threadIdx.x, lane = t & 63, w = t >> 6;
  const int nwg = gridDim.x * gridDim.y;
  const int wgid = blockIdx.y * gridDim.x + blockIdx.x;
  const int swz = (wgid & 7) * (nwg >> 3) + (wgid >> 3);
  const int m0 = (swz / gridDim.x) * 128, n0 = (swz % gridDim.x) * 128;
  const int wm = (w >> 1) * 64, wn = (w & 1) * 64;
  const int c = lane & 15, g = lane >> 4;
  f32x4 acc[4][4] = {};
  const int nk = K >> 6;
  for (int kt = 0; kt < nk; ++kt) {
    const int k0 = kt << 6;
#pragma unroll
    for (int rd = 0; rd < 4; ++rd) {
      int o = ((rd * 4 + w) << 10) + (lane << 4);
      int row = o >> 7;
      int us = ((o >> 4) & 7) ^ (row & 7);
      async16(As + o, A + (size_t)(m0 + row) * K + k0 + us * 8);
      async16(Bs + o, Bt + (size_t)(n0 + row) * K + k0 + us * 8);
    }
    __syncthreads();
#pragma unroll
    for (int ks = 0; ks < 2; ++ks) {
      bf16x8 af[4], bfr[4];
#pragma unroll
      for (int mt = 0; mt < 4; ++mt) {
        int row = wm + mt * 16 + c;
        int u = (ks * 4 + g) ^ (row & 7);
        af[mt] = *(const bf16x8*)(As + row * 128 + u * 16);
      }
#pragma unroll
      for (int nt = 0; nt < 4; ++nt) {
        int row = wn + nt * 16 + c;
        int u = (ks * 4 + g) ^ (row & 7);
        bfr[nt] = *(const bf16x8*)(Bs + row * 128 + u * 16);
      }
#pragma unroll
      for (int mt = 0; mt < 4; ++mt)
#pragma unroll
        for (int nt = 0; nt < 4; ++nt)
          acc[mt][nt] = __builtin_amdgcn_mfma_f32_16x16x32_bf16(
              af[mt], bfr[nt], acc[mt][nt], 0, 0, 0);
    }
    __syncthreads();
  }
  // fused RoPE (q,k cols only)
  if (n0 < 2048) {
#pragma unroll
    for (int mt = 0; mt < 4; ++mt)
#pragma unroll
      for (int r = 0; r < 4; ++r) {
        int s = (m0 + wm + mt * 16 + g * 4 + r) & (SLEN - 1);
        float2 t0 = tab[s * 32 + c];
        float2 t1 = tab[s * 32 + 16 + c];
        float q0 = acc[mt][0][r], q2 = acc[mt][2][r];
        acc[mt][0][r] = q0 * t0.x - q2 * t0.y;
        acc[mt][2][r] = q2 * t0.x + q0 * t0.y;
        float q1 = acc[mt][1][r], q3 = acc[mt][3][r];
        acc[mt][1][r] = q1 * t1.x - q3 * t1.y;
        acc[mt][3][r] = q3 * t1.x + q1 * t1.y;
      }
  }
#pragma unroll
  for (int mt = 0; mt < 4; ++mt)
#pragma unroll
    for (int nt = 0; nt < 4; ++nt)
#pragma unroll
      for (int r = 0; r < 4; ++r) {
        int row = m0 + wm + mt * 16 + g * 4 + r;
        int col = n0 + wn + nt * 16 + c;
        Cb[(size_t)row * N + col] = (__bf16)acc[mt][nt][r];
      }
}

// ---------------------------------------------------------------------------
// GEMM 128x128 (MLP2/WO): EPI 2 = f32 out = xres+v+bias; 3 = out += mask*v
// ---------------------------------------------------------------------------
template <int EPI>
__global__ __launch_bounds__(256, 3) void gemm_bt(
    const __bf16* __restrict__ A, const __bf16* __restrict__ Bt,
    const float* __restrict__ bias, const float* __restrict__ xres,
    const float* __restrict__ maskp, __bf16* __restrict__ Cb,
    float* __restrict__ Cf, int M, int N, int K) {
  __shared__ char smem[32768];
  char* As = smem;
  char* Bs = smem + 16384;
  const int t = threadIdx.x, lane = t & 63, w = t >> 6;
  const int nwg = gridDim.x * gridDim.y;
  const int wgid = blockIdx.y * gridDim.x + blockIdx.x;
  const int swz = (wgid & 7) * (nwg >> 3) + (wgid >> 3);
  const int m0 = (swz / gridDim.x) * 128, n0 = (swz % gridDim.x) * 128;
  const int wm = (w >> 1) * 64, wn = (w & 1) * 64;
  f32x4 acc[4][4] = {};
  const int nk = K >> 6;
  for (int kt = 0; kt < nk; ++kt) {
    const int k0 = kt << 6;
#pragma unroll
    for (int rd = 0; rd < 4; ++rd) {
      int o = ((rd * 4 + w) << 10) + (lane << 4);
      int row = o >> 7;
      int us = ((o >> 4) & 7) ^ (row & 7);
      async16(As + o, A + (size_t)(m0 + row) * K + k0 + us * 8);
      async16(Bs + o, Bt + (size_t)(n0 + row) * K + k0 + us * 8);
    }
    __syncthreads();
#pragma unroll
    for (int ks = 0; ks < 2; ++ks) {
      bf16x8 af[4], bfr[4];
#pragma unroll
      for (int mt = 0; mt < 4; ++mt) {
        int row = wm + mt * 16 + (lane & 15);
        int u = (ks * 4 + (lane >> 4)) ^ (row & 7);
        af[mt] = *(const bf16x8*)(As + row * 128 + u * 16);
      }
#pragma unroll
      for (int nt = 0; nt < 4; ++nt) {
        int row = wn + nt * 16 + (lane & 15);
        int u = (ks * 4 + (lane >> 4)) ^ (row & 7);
        bfr[nt] = *(const bf16x8*)(Bs + row * 128 + u * 16);
      }
#pragma unroll
      for (int mt = 0; mt < 4; ++mt)
#pragma unroll
        for (int nt = 0; nt < 4; ++nt)
          acc[mt][nt] = __builtin_amdgcn_mfma_f32_16x16x32_bf16(
              af[mt], bfr[nt], acc[mt][nt], 0, 0, 0);
    }
    __syncthreads();
  }
#pragma unroll
  for (int mt = 0; mt < 4; ++mt)
#pragma unroll
    for (int nt = 0; nt < 4; ++nt)
#pragma unroll
      for (int r = 0; r < 4; ++r) {
        int row = m0 + wm + mt * 16 + ((lane >> 4) << 2) + r;
        int col = n0 + wn + nt * 16 + (lane & 15);
        float v = acc[mt][nt][r];
        size_t idx = (size_t)row * N + col;
        if constexpr (EPI == 2) {
          Cf[idx] = xres[idx] + v + bias[col];
        } else {
          Cf[idx] += maskp[row] * v;
        }
      }
}

// ---------------------------------------------------------------------------
// V scatter (8-wave): wave w owns d = w*8..w*8+7, lane = k-token
// ---------------------------------------------------------------------------
__device__ __forceinline__ void scatterV8(char* Vdst, int w, int lane, float4 va) {
  union { float4 f; __bf16 bv[8]; } u0;
  u0.f = va;
#pragma unroll
  for (int j = 0; j < 8; ++j) {
    int d = w * 8 + j;
    int by = d * 128 + (((lane >> 3) ^ (d & 7)) << 4) + ((lane & 7) << 1);
    *(__bf16*)(Vdst + by) = u0.bv[j];
  }
}

// ---------------------------------------------------------------------------
// Flash attention, causal, swapped QK^T, in-lane softmax — 8-wave version
// (verified R18: 16 waves/CU, no spill). XCD bh-grouping. Defer-max THR=8.
// ---------------------------------------------------------------------------
__global__ __launch_bounds__(512, 4) void attn_kernel(const __bf16* __restrict__ qkv,
                                                      __bf16* __restrict__ ctx) {
  __shared__ char sm[32768];
  const int t = threadIdx.x, lane = t & 63, w = t >> 6;  // w in 0..7
  const int c = lane & 15, g = lane >> 4, g4 = g * 4;
  const int bh = (int)blockIdx.x * 8 + ((int)blockIdx.y & 7);
  const int qp = (int)blockIdx.y >> 3;
  const int h = bh & 15, b = bh >> 4;
  const size_t tokbase = (size_t)b * SLEN;
  const __bf16* qg = qkv + tokbase * 3072 + h * 64;
  const __bf16* kg = qg + 1024;
  const __bf16* vg = qg + 2048;
  const float SCL = 0.125f * 1.44269504f;  // 1/sqrt(64) * log2(e)
  char* Ps = sm + (w << 11);   // 2KB per wave
  char* Ks = sm + 16384;
  char* Vs = sm + 24576;

  for (int ph = 0; ph < 2; ++ph) {
    const int qt = ph == 0 ? qp : 15 - qp;
    const int q0 = qt * 128;
#pragma unroll
    for (int rd = 0; rd < 2; ++rd) {
      int o = ((rd * 8 + w) << 10) + (lane << 4);
      int row = o >> 7;
      int us = ((o >> 4) & 7) ^ (row & 7);
      async16(sm + o, qg + (size_t)(q0 + row) * 3072 + us * 8);
    }
    __syncthreads();
    bf16x8 qb[2];
#pragma unroll
    for (int ks = 0; ks < 2; ++ks) {
      int row = w * 16 + c;
      int u = (ks * 4 + g) ^ (row & 7);
      qb[ks] = *(const bf16x8*)(sm + row * 128 + u * 16);
    }

    float m_run = -1e30f, l_run = 0.f;
    f32x4 o_acc[4] = {};
    const int nkt = (q0 + 128) >> 6;
    const int wrow0 = q0 + w * 16;

    for (int kt = 0; kt < nkt; ++kt) {
      const int k0 = kt << 6;
      {
        int o = (w << 10) + (lane << 4);
        int row = o >> 7;
        int us = ((o >> 4) & 7) ^ (row & 7);
        async16(Ks + o, kg + (size_t)(k0 + row) * 3072 + us * 8);
        float4 va = *(const float4*)(vg + (size_t)(k0 + lane) * 3072 + w * 8);
        scatterV8(Vs, w, lane, va);
      }
      __syncthreads();
      if (k0 <= wrow0 + 15) {
        f32x4 st[4] = {};
        __builtin_amdgcn_s_setprio(1);
#pragma unroll
        for (int ks = 0; ks < 2; ++ks) {
          bf16x8 ka[4];
#pragma unroll
          for (int nt = 0; nt < 4; ++nt) {
            int row = nt * 16 + c;
            int u = (ks * 4 + g) ^ (row & 7);
            ka[nt] = *(const bf16x8*)(Ks + row * 128 + u * 16);
          }
#pragma unroll
          for (int nt = 0; nt < 4; ++nt)
            st[nt] = __builtin_amdgcn_mfma_f32_16x16x32_bf16(
                ka[nt], qb[ks], st[nt], 0, 0, 0);
        }
        __builtin_amdgcn_s_setprio(0);
        const bool needmask = (k0 + 63) > wrow0;
        float mx = -1e30f;
        if (needmask) {
          int qglob = wrow0 + c;
#pragma unroll
          for (int nt = 0; nt < 4; ++nt)
#pragma unroll
            for (int r = 0; r < 4; ++r) {
              float sv = st[nt][r] * SCL;
              if (k0 + nt * 16 + g4 + r > qglob) sv = -1e30f;
              st[nt][r] = sv;
              mx = fmaxf(mx, sv);
            }
        } else {
#pragma unroll
          for (int nt = 0; nt < 4; ++nt)
#pragma unroll
            for (int r = 0; r < 4; ++r) {
              float sv = st[nt][r] * SCL;
              st[nt][r] = sv;
              mx = fmaxf(mx, sv);
            }
        }
        mx = fmaxf(mx, __shfl_xor(mx, 16));
        mx = fmaxf(mx, __shfl_xor(mx, 32));
        const bool skip = __all(mx - m_run <= 8.f) != 0;
        float mnew = skip ? m_run : fmaxf(m_run, mx);
        float rs = 0.f;
#pragma unroll
        for (int nt = 0; nt < 4; ++nt)
#pragma unroll
          for (int r = 0; r < 4; ++r) {
            float p = __builtin_amdgcn_exp2f(st[nt][r] - mnew);
            st[nt][r] = p;
            rs += p;
          }
        rs += __shfl_xor(rs, 16);
        rs += __shfl_xor(rs, 32);
        if (skip) {
          l_run += rs;
        } else {
          float fac = __builtin_amdgcn_exp2f(m_run - mnew);
          m_run = mnew;
          l_run = l_run * fac + rs;
#pragma unroll
          for (int r = 0; r < 4; ++r) {
            float fr = __shfl(fac, g * 20 + r);
#pragma unroll
            for (int dt = 0; dt < 4; ++dt) o_acc[dt][r] *= fr;
          }
        }
        {
          int rbase = c * 128 + 8 * (g & 1);
#pragma unroll
          for (int nt = 0; nt < 4; ++nt) {
            int us = (2 * nt + (g >> 1)) ^ (c & 7);
            union { uint2 v; __bf16 bb[4]; } pp;
            pp.bb[0] = (__bf16)st[nt][0]; pp.bb[1] = (__bf16)st[nt][1];
            pp.bb[2] = (__bf16)st[nt][2]; pp.bb[3] = (__bf16)st[nt][3];
            *(uint2*)(Ps + rbase + us * 16) = pp.v;
          }
        }
        __builtin_amdgcn_s_setprio(1);
#pragma unroll
        for (int ks = 0; ks < 2; ++ks) {
          bf16x8 pa, vb[4];
          {
            int u = (ks * 4 + g) ^ (c & 7);
            pa = *(const bf16x8*)(Ps + c * 128 + u * 16);
          }
#pragma unroll
          for (int dt = 0; dt < 4; ++dt) {
            int row = dt * 16 + c;
            int u = (ks * 4 + g) ^ (row & 7);
            vb[dt] = *(const bf16x8*)(Vs + row * 128 + u * 16);
          }
#pragma unroll
          for (int dt = 0; dt < 4; ++dt)
            o_acc[dt] = __builtin_amdgcn_mfma_f32_16x16x32_bf16(
                pa, vb[dt], o_acc[dt], 0, 0, 0);
        }
        __builtin_amdgcn_s_setprio(0);
      }
      __syncthreads();
    }
#pragma unroll
    for (int r = 0; r < 4; ++r) {
      float lr = __shfl(l_run, g * 20 + r);
      float inv = 1.f / lr;
      int tokr = q0 + w * 16 + g4 + r;
#pragma unroll
      for (int dt = 0; dt < 4; ++dt) {
        int d = dt * 16 + c;
        ctx[(tokbase + tokr) * DDIM + h * 64 + d] =
            (__bf16)(o_acc[dt][r] * inv);
      }
    }
  }
}

// ---------------------------------------------------------------------------
// aux loss: (mean(probs) - 0.2)^2
// ---------------------------------------------------------------------------
__global__ __launch_bounds__(256) void aux_kernel(const float* __restrict__ probsp,
                                                  float* __restrict__ outp) {
  const int t = threadIdx.x;
  float sum = 0.f;
  for (int i = t; i < NTOK; i += 256) sum += probsp[i];
#pragma unroll
  for (int d = 32; d; d >>= 1) sum += __shfl_down(sum, d);
  __shared__ float ws4[4];
  if ((t & 63) == 0) ws4[t >> 6] = sum;
  __syncthreads();
  if (t == 0) {
    float m = (ws4[0] + ws4[1] + ws4[2] + ws4[3]) * (1.f / NTOK) - 0.2f;
    outp[0] = m * m;
  }
}

// ---------------------------------------------------------------------------
extern "C" void kernel_launch(void* const* d_in, const int* in_sizes, int n_in,
                              void* d_out, int out_size, void* d_ws, size_t ws_size,
                              hipStream_t stream) {
  const float* x      = (const float*)d_in[0];
  const float* gate_w = (const float*)d_in[1];
  const float* gate_b = (const float*)d_in[2];
  const float* wq     = (const float*)d_in[3];
  const float* wk     = (const float*)d_in[4];
  const float* wv     = (const float*)d_in[5];
  const float* wo     = (const float*)d_in[6];
  const float* conv_w = (const float*)d_in[7];
  const float* conv_b = (const float*)d_in[8];
  const float* mlp_w1 = (const float*)d_in[9];
  const float* mlp_b1 = (const float*)d_in[10];
  const float* mlp_w2 = (const float*)d_in[11];
  const float* mlp_b2 = (const float*)d_in[12];
  float* out = (float*)d_out;

  char* ws = (char*)d_ws;
  const size_t MB = 1ull << 20;
  __bf16* xb     = (__bf16*)(ws + 0);
  __bf16* xcb    = (__bf16*)(ws + 16 * MB);
  __bf16* ctx    = (__bf16*)(ws + 16 * MB);    // overlays xcb
  __bf16* wqkv_t = (__bf16*)(ws + 32 * MB);
  __bf16* wo_t   = (__bf16*)(ws + 38 * MB);
  __bf16* w1_t   = (__bf16*)(ws + 40 * MB);
  __bf16* w2_t   = (__bf16*)(ws + 48 * MB);
  float*  maskp  = (float*)(ws + 56 * MB);
  float*  probsp = (float*)(ws + 56 * MB + 65536);
  float2* ropetab= (float2*)(ws + 56 * MB + 131072);  // 512KB
  __bf16* h1     = (__bf16*)(ws + 57 * MB);
  __bf16* qkv    = (__bf16*)(ws + 57 * MB);    // overlays h1

  prep_kernel<<<NTOK, 256, 0, stream>>>(x, gate_w, gate_b, conv_w, conv_b,
                                        xb, xcb, maskp, probsp);
  tabgen_kernel<<<256, 256, 0, stream>>>(ropetab);
  tcast4_kernel<<<dim3(16, 16, 4), 256, 0, stream>>>(wq, wk, wv, wo,
                                                     wqkv_t, wo_t);
  tcast_kernel<<<dim3(64, 16), 256, 0, stream>>>(mlp_w1, w1_t, 1024, 4096);
  tcast_kernel<<<dim3(16, 64), 256, 0, stream>>>(mlp_w2, w2_t, 4096, 1024);

  // Reflexive (MLP) stream first so h1 region can be reused by qkv.
  gemm256p<<<dim3(16, 32), 512, 131072, stream>>>(xcb, w1_t, mlp_b1, h1,
                                                  NTOK, MLPD, DDIM);
  gemm_bt<2><<<dim3(8, 64), 256, 0, stream>>>(h1, w2_t, mlp_b2, x, nullptr,
                                              nullptr, out, NTOK, DDIM, MLPD);
  // Contextual stream (RoPE fused into the QKV epilogue; 128^2 tile so the
  // grid is 1536 blocks = exactly 2 full occupancy rounds at 3 blocks/CU).
  gemm_btq<<<dim3(24, 64), 256, 0, stream>>>(xb, wqkv_t, ropetab, qkv,
                                             NTOK, 3072, DDIM);
  attn_kernel<<<dim3(8, 64), 512, 0, stream>>>(qkv, ctx);
  gemm_bt<3><<<dim3(8, 64), 256, 0, stream>>>(ctx, wo_t, nullptr, nullptr, maskp,
                                              nullptr, out, NTOK, DDIM, DDIM);
  aux_kernel<<<1, 256, 0, stream>>>(probsp, out + (size_t)(out_size - 1));
}

// Round 22
// 363.729 us; speedup vs baseline: 1.1347x; 1.0177x over previous
//
#include <hip/hip_runtime.h>
#include <hip/hip_bf16.h>

#define DDIM 1024
#define SLEN 2048
#define NTOK 8192
#define MLPD 4096

typedef float f32x4 __attribute__((ext_vector_type(4)));
typedef __bf16 bf16x8 __attribute__((ext_vector_type(8)));

__device__ __forceinline__ void async16(void* lds, const void* g) {
  __builtin_amdgcn_global_load_lds(
      (__attribute__((address_space(1))) void*)g,
      (__attribute__((address_space(3))) void*)lds, 16, 0, 0);
}

template <int N> struct VMC { static constexpr int v = N; };

// ---------------------------------------------------------------------------
// prep: router logits + mask + probs, causal depthwise conv (k=3), x -> bf16
// ---------------------------------------------------------------------------
__global__ __launch_bounds__(256) void prep_kernel(
    const float* __restrict__ x, const float* __restrict__ gate_w,
    const float* __restrict__ gate_b, const float* __restrict__ conv_w,
    const float* __restrict__ conv_b, __bf16* __restrict__ xb,
    __bf16* __restrict__ xcb, float* __restrict__ maskp,
    float* __restrict__ probsp) {
  const int tok = blockIdx.x, t = threadIdx.x;
  const int s = tok & (SLEN - 1);
  const float* xr = x + (size_t)tok * DDIM;
  float4 v = ((const float4*)xr)[t];
  float4 g = ((const float4*)gate_w)[t];
  float part = v.x * g.x + v.y * g.y + v.z * g.z + v.w * g.w;
#pragma unroll
  for (int d = 32; d; d >>= 1) part += __shfl_down(part, d);
  __shared__ float ws4[4];
  const int lane = t & 63, w = t >> 6;
  if (lane == 0) ws4[w] = part;
  __syncthreads();
  if (t == 0) {
    float logit = ws4[0] + ws4[1] + ws4[2] + ws4[3] + gate_b[0];
    float prob = 1.f / (1.f + __expf(-logit));
    probsp[tok] = prob;
    maskp[tok] = prob > 0.5f ? 1.f : 0.f;
  }
  union { ushort4 u; __bf16 b[4]; } xo;
  xo.b[0] = (__bf16)v.x; xo.b[1] = (__bf16)v.y;
  xo.b[2] = (__bf16)v.z; xo.b[3] = (__bf16)v.w;
  ((ushort4*)(xb + (size_t)tok * DDIM))[t] = xo.u;
  float4 zero4 = {0.f, 0.f, 0.f, 0.f};
  float4 m1 = (s >= 1) ? ((const float4*)(xr - DDIM))[t] : zero4;
  float4 m2 = (s >= 2) ? ((const float4*)(xr - 2 * DDIM))[t] : zero4;
  int d0 = t * 4;
  float vv[4] = {v.x, v.y, v.z, v.w};
  float a1[4] = {m1.x, m1.y, m1.z, m1.w};
  float a2[4] = {m2.x, m2.y, m2.z, m2.w};
  union { ushort4 u; __bf16 b[4]; } co;
#pragma unroll
  for (int i = 0; i < 4; ++i) {
    float c0 = conv_w[(d0 + i) * 3 + 0];
    float c1 = conv_w[(d0 + i) * 3 + 1];
    float c2 = conv_w[(d0 + i) * 3 + 2];
    float r = a2[i] * c0 + a1[i] * c1 + vv[i] * c2 + conv_b[d0 + i];
    co.b[i] = (__bf16)r;
  }
  ((ushort4*)(xcb + (size_t)tok * DDIM))[t] = co.u;
}

// ---------------------------------------------------------------------------
// transposed cast body: src [K][N] f32 -> dst [N][K] bf16 (one 64x64 tile)
// ---------------------------------------------------------------------------
__device__ __forceinline__ void tcast_body(const float* __restrict__ src,
                                           __bf16* __restrict__ dst,
                                           int K, int N, int n0, int k0) {
  __shared__ __bf16 tile[64][65];
  const int t = threadIdx.x;
  const int cr = (t & 15) * 4;
#pragma unroll
  for (int i = 0; i < 4; ++i) {
    int rr = (t >> 4) + i * 16;
    float4 v = *(const float4*)(src + (size_t)(k0 + rr) * N + n0 + cr);
    tile[rr][cr + 0] = (__bf16)v.x; tile[rr][cr + 1] = (__bf16)v.y;
    tile[rr][cr + 2] = (__bf16)v.z; tile[rr][cr + 3] = (__bf16)v.w;
  }
  __syncthreads();
#pragma unroll
  for (int i = 0; i < 2; ++i) {
    int c = t + i * 256;
    int nl = c >> 3, koff = (c & 7) * 8;
    union { uint4 u; __bf16 b[8]; } o;
#pragma unroll
    for (int j = 0; j < 8; ++j) o.b[j] = tile[koff + j][nl];
    *(uint4*)(dst + (size_t)(n0 + nl) * K + k0 + koff) = o.u;
  }
}

// ---------------------------------------------------------------------------
// weights_prep: ALL weight casts + RoPE trig table in ONE dispatch.
// Flat grid 3328 blocks:
//   [0,1024):   wq/wk/wv/wo (4 x 256 tiles of 1024x1024)
//   [1024,2048): mlp_w1 (K=1024, N=4096; 64 n-tiles x 16 k-tiles)
//   [2048,3072): mlp_w2 (K=4096, N=1024; 16 n-tiles x 64 k-tiles)
//   [3072,3328): tab[s][i] = (cos, sin), 256 entries/block
// Branches are block-uniform; single tcast_body call site (one LDS tile).
// ---------------------------------------------------------------------------
__global__ __launch_bounds__(256) void weights_prep_kernel(
    const float* __restrict__ wq, const float* __restrict__ wk,
    const float* __restrict__ wv, const float* __restrict__ wo,
    const float* __restrict__ w1, const float* __restrict__ w2,
    __bf16* __restrict__ dqkv, __bf16* __restrict__ dwo,
    __bf16* __restrict__ dw1, __bf16* __restrict__ dw2,
    float2* __restrict__ tab) {
  const int id = blockIdx.x;
  if (id >= 3072) {
    const int idx = (id - 3072) * 256 + threadIdx.x;
    const int s = idx >> 5, i = idx & 31;
    float invf = __builtin_amdgcn_exp2f(-(float)i * (13.28771238f / 32.f));
    float fr = (float)s * invf;
    tab[idx] = make_float2(cosf(fr), sinf(fr));
    return;
  }
  const float* src;
  __bf16* dst;
  int K, N, n0, k0;
  if (id < 1024) {
    const int z = id >> 8, tile = id & 255;
    src = z == 0 ? wq : z == 1 ? wk : z == 2 ? wv : wo;
    dst = z < 3 ? dqkv + (size_t)z * 1024 * 1024 : dwo;
    K = 1024; N = 1024; n0 = (tile & 15) * 64; k0 = (tile >> 4) * 64;
  } else if (id < 2048) {
    const int tile = id - 1024;
    src = w1; dst = dw1;
    K = 1024; N = 4096; n0 = (tile & 63) * 64; k0 = (tile >> 6) * 64;
  } else {
    const int tile = id - 2048;
    src = w2; dst = dw2;
    K = 4096; N = 1024; n0 = (tile & 15) * 64; k0 = (tile >> 4) * 64;
  }
  tcast_body(src, dst, K, N, n0, k0);
}

// ---------------------------------------------------------------------------
// 256x256 pipelined GEMM (ring-4, counted vmcnt). EPI: bf16 relu(v+bias).
// Used for MLP1 only (grid 512 = 2 exact occupancy rounds at 1 block/CU).
// ---------------------------------------------------------------------------
__global__ __launch_bounds__(512, 2) void gemm256p(
    const __bf16* __restrict__ A, const __bf16* __restrict__ Bt,
    const float* __restrict__ bias, __bf16* __restrict__ Cb,
    int M, int N, int K) {
  extern __shared__ char sm[];
  const int t = threadIdx.x, lane = t & 63, w = t >> 6;
  const int c = lane & 15, g = lane >> 4;
  const int nwg = gridDim.x * gridDim.y;
  const int wgid = blockIdx.y * gridDim.x + blockIdx.x;
  const int swz = (wgid & 7) * (nwg >> 3) + (wgid >> 3);
  const int m0 = (swz / gridDim.x) * 256, n0 = (swz % gridDim.x) * 256;
  const int wm = (w >> 2) * 128, wn = (w & 3) * 64;

  f32x4 acc[8][4] = {};
  const int nk = K >> 5;

  auto stage = [&](int buf, int kt) {
    const int k0 = kt << 5;
    char* base = sm + buf * 32768;
#pragma unroll
    for (int r = 0; r < 2; ++r) {
      int o = ((r * 8 + w) << 10) + (lane << 4);
      int rp = o >> 7;
      int u = (o >> 4) & 7;
      int l = u ^ (rp & 7);
      int mr = rp * 2 + (l >> 2);
      int kk = (l & 3) * 8;
      async16(base + o, A + (size_t)(m0 + mr) * K + k0 + kk);
      async16(base + 16384 + o, Bt + (size_t)(n0 + mr) * K + k0 + kk);
    }
  };

  auto body = [&](auto vmc, int tt, bool dostage) {
    if (dostage) stage((tt + 3) & 3, tt + 3);
    asm volatile("s_waitcnt vmcnt(%0)" ::"n"(decltype(vmc)::v) : "memory");
    __builtin_amdgcn_s_barrier();
    asm volatile("" ::: "memory");
    const char* Ab = sm + (tt & 3) * 32768;
    const char* Bb = Ab + 16384;
    bf16x8 aq[8], bq[4];
#pragma unroll
    for (int nt = 0; nt < 4; ++nt) {
      int row = wn + nt * 16 + c;
      int rp = row >> 1;
      int u = ((row & 1) * 4 + g) ^ (rp & 7);
      bq[nt] = *(const bf16x8*)(Bb + rp * 128 + u * 16);
    }
#pragma unroll
    for (int i = 0; i < 8; ++i) {
      int row = wm + i * 16 + c;
      int rp = row >> 1;
      int u = ((row & 1) * 4 + g) ^ (rp & 7);
      aq[i] = *(const bf16x8*)(Ab + rp * 128 + u * 16);
    }
    __builtin_amdgcn_s_setprio(1);
#pragma unroll
    for (int i = 0; i < 8; ++i)
#pragma unroll
      for (int nt = 0; nt < 4; ++nt)
        acc[i][nt] = __builtin_amdgcn_mfma_f32_16x16x32_bf16(
            aq[i], bq[nt], acc[i][nt], 0, 0, 0);
    __builtin_amdgcn_s_setprio(0);
    __builtin_amdgcn_s_barrier();
    asm volatile("" ::: "memory");
  };

  stage(0, 0);
  stage(1, 1);
  stage(2, 2);
  int tt = 0;
  for (; tt < nk - 3; ++tt) body(VMC<12>{}, tt, true);
  body(VMC<8>{}, tt, false); ++tt;
  body(VMC<4>{}, tt, false); ++tt;
  body(VMC<0>{}, tt, false);

#pragma unroll
  for (int i = 0; i < 8; ++i)
#pragma unroll
    for (int nt = 0; nt < 4; ++nt)
#pragma unroll
      for (int r = 0; r < 4; ++r) {
        int row = m0 + wm + i * 16 + g * 4 + r;
        int col = n0 + wn + nt * 16 + c;
        float v = acc[i][nt][r] + bias[col];
        Cb[(size_t)row * N + col] = (__bf16)fmaxf(v, 0.f);
      }
}

// ---------------------------------------------------------------------------
// GEMM 128x128 for QKV with fused RoPE: bf16 store; for n0 < 2048 (q,k
// regions) rotate pairs (i, i+32) which live in fragments (nt, nt+2) of the
// same thread (i = nt*16 + c for nt in {0,1}); s = row & 2047.
// Grid (24,64) = 1536 blocks at 3/CU = exactly 2 full occupancy rounds.
// ---------------------------------------------------------------------------
__global__ __launch_bounds__(256, 3) void gemm_btq(
    const __bf16* __restrict__ A, const __bf16* __restrict__ Bt,
    const float2* __restrict__ tab, __bf16* __restrict__ Cb,
    int M, int N, int K) {
  __shared__ char smem[32768];
  char* As = smem;
  char* Bs = smem + 16384;
  const int t = threadIdx.x, lane = t & 63, w = t >> 6;
  const int nwg = gridDim.x * gridDim.y;
  const int wgid = blockIdx.y * gridDim.x + blockIdx.x;
  const int swz = (wgid & 7) * (nwg >> 3) + (wgid >> 3);
  const int m0 = (swz / gridDim.x) * 128, n0 = (swz % gridDim.x) * 128;
  const int wm = (w >> 1) * 64, wn = (w & 1) * 64;
  const int c = lane & 15, g = lane >> 4;
  f32x4 acc[4][4] = {};
  const int nk = K >> 6;
  for (int kt = 0; kt < nk; ++kt) {
    const int k0 = kt << 6;
#pragma unroll
    for (int rd = 0; rd < 4; ++rd) {
      int o = ((rd * 4 + w) << 10) + (lane << 4);
      int row = o >> 7;
      int us = ((o >> 4) & 7) ^ (row & 7);
      async16(As + o, A + (size_t)(m0 + row) * K + k0 + us * 8);
      async16(Bs + o, Bt + (size_t)(n0 + row) * K + k0 + us * 8);
    }
    __syncthreads();
#pragma unroll
    for (int ks = 0; ks < 2; ++ks) {
      bf16x8 af[4], bfr[4];
#pragma unroll
      for (int mt = 0; mt < 4; ++mt) {
        int row = wm + mt * 16 + c;
        int u = (ks * 4 + g) ^ (row & 7);
        af[mt] = *(const bf16x8*)(As + row * 128 + u * 16);
      }
#pragma unroll
      for (int nt = 0; nt < 4; ++nt) {
        int row = wn + nt * 16 + c;
        int u = (ks * 4 + g) ^ (row & 7);
        bfr[nt] = *(const bf16x8*)(Bs + row * 128 + u * 16);
      }
#pragma unroll
      for (int mt = 0; mt < 4; ++mt)
#pragma unroll
        for (int nt = 0; nt < 4; ++nt)
          acc[mt][nt] = __builtin_amdgcn_mfma_f32_16x16x32_bf16(
              af[mt], bfr[nt], acc[mt][nt], 0, 0, 0);
    }
    __syncthreads();
  }
  // fused RoPE (q,k cols only)
  if (n0 < 2048) {
#pragma unroll
    for (int mt = 0; mt < 4; ++mt)
#pragma unroll
      for (int r = 0; r < 4; ++r) {
        int s = (m0 + wm + mt * 16 + g * 4 + r) & (SLEN - 1);
        float2 t0 = tab[s * 32 + c];
        float2 t1 = tab[s * 32 + 16 + c];
        float q0 = acc[mt][0][r], q2 = acc[mt][2][r];
        acc[mt][0][r] = q0 * t0.x - q2 * t0.y;
        acc[mt][2][r] = q2 * t0.x + q0 * t0.y;
        float q1 = acc[mt][1][r], q3 = acc[mt][3][r];
        acc[mt][1][r] = q1 * t1.x - q3 * t1.y;
        acc[mt][3][r] = q3 * t1.x + q1 * t1.y;
      }
  }
#pragma unroll
  for (int mt = 0; mt < 4; ++mt)
#pragma unroll
    for (int nt = 0; nt < 4; ++nt)
#pragma unroll
      for (int r = 0; r < 4; ++r) {
        int row = m0 + wm + mt * 16 + g * 4 + r;
        int col = n0 + wn + nt * 16 + c;
        Cb[(size_t)row * N + col] = (__bf16)acc[mt][nt][r];
      }
}

// ---------------------------------------------------------------------------
// GEMM 128x128 (MLP2/WO): EPI 2 = f32 out = xres+v+bias; 3 = out += mask*v
// ---------------------------------------------------------------------------
template <int EPI>
__global__ __launch_bounds__(256, 3) void gemm_bt(
    const __bf16* __restrict__ A, const __bf16* __restrict__ Bt,
    const float* __restrict__ bias, const float* __restrict__ xres,
    const float* __restrict__ maskp, __bf16* __restrict__ Cb,
    float* __restrict__ Cf, int M, int N, int K) {
  __shared__ char smem[32768];
  char* As = smem;
  char* Bs = smem + 16384;
  const int t = threadIdx.x, lane = t & 63, w = t >> 6;
  const int nwg = gridDim.x * gridDim.y;
  const int wgid = blockIdx.y * gridDim.x + blockIdx.x;
  const int swz = (wgid & 7) * (nwg >> 3) + (wgid >> 3);
  const int m0 = (swz / gridDim.x) * 128, n0 = (swz % gridDim.x) * 128;
  const int wm = (w >> 1) * 64, wn = (w & 1) * 64;
  f32x4 acc[4][4] = {};
  const int nk = K >> 6;
  for (int kt = 0; kt < nk; ++kt) {
    const int k0 = kt << 6;
#pragma unroll
    for (int rd = 0; rd < 4; ++rd) {
      int o = ((rd * 4 + w) << 10) + (lane << 4);
      int row = o >> 7;
      int us = ((o >> 4) & 7) ^ (row & 7);
      async16(As + o, A + (size_t)(m0 + row) * K + k0 + us * 8);
      async16(Bs + o, Bt + (size_t)(n0 + row) * K + k0 + us * 8);
    }
    __syncthreads();
#pragma unroll
    for (int ks = 0; ks < 2; ++ks) {
      bf16x8 af[4], bfr[4];
#pragma unroll
      for (int mt = 0; mt < 4; ++mt) {
        int row = wm + mt * 16 + (lane & 15);
        int u = (ks * 4 + (lane >> 4)) ^ (row & 7);
        af[mt] = *(const bf16x8*)(As + row * 128 + u * 16);
      }
#pragma unroll
      for (int nt = 0; nt < 4; ++nt) {
        int row = wn + nt * 16 + (lane & 15);
        int u = (ks * 4 + (lane >> 4)) ^ (row & 7);
        bfr[nt] = *(const bf16x8*)(Bs + row * 128 + u * 16);
      }
#pragma unroll
      for (int mt = 0; mt < 4; ++mt)
#pragma unroll
        for (int nt = 0; nt < 4; ++nt)
          acc[mt][nt] = __builtin_amdgcn_mfma_f32_16x16x32_bf16(
              af[mt], bfr[nt], acc[mt][nt], 0, 0, 0);
    }
    __syncthreads();
  }
#pragma unroll
  for (int mt = 0; mt < 4; ++mt)
#pragma unroll
    for (int nt = 0; nt < 4; ++nt)
#pragma unroll
      for (int r = 0; r < 4; ++r) {
        int row = m0 + wm + mt * 16 + ((lane >> 4) << 2) + r;
        int col = n0 + wn + nt * 16 + (lane & 15);
        float v = acc[mt][nt][r];
        size_t idx = (size_t)row * N + col;
        if constexpr (EPI == 2) {
          Cf[idx] = xres[idx] + v + bias[col];
        } else {
          Cf[idx] += maskp[row] * v;
        }
      }
}

// ---------------------------------------------------------------------------
// V scatter (8-wave): wave w owns d = w*8..w*8+7, lane = k-token
// ---------------------------------------------------------------------------
__device__ __forceinline__ void scatterV8(char* Vdst, int w, int lane, float4 va) {
  union { float4 f; __bf16 bv[8]; } u0;
  u0.f = va;
#pragma unroll
  for (int j = 0; j < 8; ++j) {
    int d = w * 8 + j;
    int by = d * 128 + (((lane >> 3) ^ (d & 7)) << 4) + ((lane & 7) << 1);
    *(__bf16*)(Vdst + by) = u0.bv[j];
  }
}

// ---------------------------------------------------------------------------
// Flash attention, causal, swapped QK^T, in-lane softmax — 8-wave version
// (verified R18/R21: 16 waves/CU, no spill). XCD bh-grouping. Defer-max.
// ---------------------------------------------------------------------------
__global__ __launch_bounds__(512, 4) void attn_kernel(const __bf16* __restrict__ qkv,
                                                      __bf16* __restrict__ ctx) {
  __shared__ char sm[32768];
  const int t = threadIdx.x, lane = t & 63, w = t >> 6;  // w in 0..7
  const int c = lane & 15, g = lane >> 4, g4 = g * 4;
  const int bh = (int)blockIdx.x * 8 + ((int)blockIdx.y & 7);
  const int qp = (int)blockIdx.y >> 3;
  const int h = bh & 15, b = bh >> 4;
  const size_t tokbase = (size_t)b * SLEN;
  const __bf16* qg = qkv + tokbase * 3072 + h * 64;
  const __bf16* kg = qg + 1024;
  const __bf16* vg = qg + 2048;
  const float SCL = 0.125f * 1.44269504f;  // 1/sqrt(64) * log2(e)
  char* Ps = sm + (w << 11);   // 2KB per wave
  char* Ks = sm + 16384;
  char* Vs = sm + 24576;

  for (int ph = 0; ph < 2; ++ph) {
    const int qt = ph == 0 ? qp : 15 - qp;
    const int q0 = qt * 128;
#pragma unroll
    for (int rd = 0; rd < 2; ++rd) {
      int o = ((rd * 8 + w) << 10) + (lane << 4);
      int row = o >> 7;
      int us = ((o >> 4) & 7) ^ (row & 7);
      async16(sm + o, qg + (size_t)(q0 + row) * 3072 + us * 8);
    }
    __syncthreads();
    bf16x8 qb[2];
#pragma unroll
    for (int ks = 0; ks < 2; ++ks) {
      int row = w * 16 + c;
      int u = (ks * 4 + g) ^ (row & 7);
      qb[ks] = *(const bf16x8*)(sm + row * 128 + u * 16);
    }

    float m_run = -1e30f, l_run = 0.f;
    f32x4 o_acc[4] = {};
    const int nkt = (q0 + 128) >> 6;
    const int wrow0 = q0 + w * 16;

    for (int kt = 0; kt < nkt; ++kt) {
      const int k0 = kt << 6;
      {
        int o = (w << 10) + (lane << 4);
        int row = o >> 7;
        int us = ((o >> 4) & 7) ^ (row & 7);
        async16(Ks + o, kg + (size_t)(k0 + row) * 3072 + us * 8);
        float4 va = *(const float4*)(vg + (size_t)(k0 + lane) * 3072 + w * 8);
        scatterV8(Vs, w, lane, va);
      }
      __syncthreads();
      if (k0 <= wrow0 + 15) {
        f32x4 st[4] = {};
        __builtin_amdgcn_s_setprio(1);
#pragma unroll
        for (int ks = 0; ks < 2; ++ks) {
          bf16x8 ka[4];
#pragma unroll
          for (int nt = 0; nt < 4; ++nt) {
            int row = nt * 16 + c;
            int u = (ks * 4 + g) ^ (row & 7);
            ka[nt] = *(const bf16x8*)(Ks + row * 128 + u * 16);
          }
#pragma unroll
          for (int nt = 0; nt < 4; ++nt)
            st[nt] = __builtin_amdgcn_mfma_f32_16x16x32_bf16(
                ka[nt], qb[ks], st[nt], 0, 0, 0);
        }
        __builtin_amdgcn_s_setprio(0);
        const bool needmask = (k0 + 63) > wrow0;
        float mx = -1e30f;
        if (needmask) {
          int qglob = wrow0 + c;
#pragma unroll
          for (int nt = 0; nt < 4; ++nt)
#pragma unroll
            for (int r = 0; r < 4; ++r) {
              float sv = st[nt][r] * SCL;
              if (k0 + nt * 16 + g4 + r > qglob) sv = -1e30f;
              st[nt][r] = sv;
              mx = fmaxf(mx, sv);
            }
        } else {
#pragma unroll
          for (int nt = 0; nt < 4; ++nt)
#pragma unroll
            for (int r = 0; r < 4; ++r) {
              float sv = st[nt][r] * SCL;
              st[nt][r] = sv;
              mx = fmaxf(mx, sv);
            }
        }
        mx = fmaxf(mx, __shfl_xor(mx, 16));
        mx = fmaxf(mx, __shfl_xor(mx, 32));
        const bool skip = __all(mx - m_run <= 8.f) != 0;
        float mnew = skip ? m_run : fmaxf(m_run, mx);
        float rs = 0.f;
#pragma unroll
        for (int nt = 0; nt < 4; ++nt)
#pragma unroll
          for (int r = 0; r < 4; ++r) {
            float p = __builtin_amdgcn_exp2f(st[nt][r] - mnew);
            st[nt][r] = p;
            rs += p;
          }
        rs += __shfl_xor(rs, 16);
        rs += __shfl_xor(rs, 32);
        if (skip) {
          l_run += rs;
        } else {
          float fac = __builtin_amdgcn_exp2f(m_run - mnew);
          m_run = mnew;
          l_run = l_run * fac + rs;
#pragma unroll
          for (int r = 0; r < 4; ++r) {
            float fr = __shfl(fac, g * 20 + r);
#pragma unroll
            for (int dt = 0; dt < 4; ++dt) o_acc[dt][r] *= fr;
          }
        }
        {
          int rbase = c * 128 + 8 * (g & 1);
#pragma unroll
          for (int nt = 0; nt < 4; ++nt) {
            int us = (2 * nt + (g >> 1)) ^ (c & 7);
            union { uint2 v; __bf16 bb[4]; } pp;
            pp.bb[0] = (__bf16)st[nt][0]; pp.bb[1] = (__bf16)st[nt][1];
            pp.bb[2] = (__bf16)st[nt][2]; pp.bb[3] = (__bf16)st[nt][3];
            *(uint2*)(Ps + rbase + us * 16) = pp.v;
          }
        }
        __builtin_amdgcn_s_setprio(1);
#pragma unroll
        for (int ks = 0; ks < 2; ++ks) {
          bf16x8 pa, vb[4];
          {
            int u = (ks * 4 + g) ^ (c & 7);
            pa = *(const bf16x8*)(Ps + c * 128 + u * 16);
          }
#pragma unroll
          for (int dt = 0; dt < 4; ++dt) {
            int row = dt * 16 + c;
            int u = (ks * 4 + g) ^ (row & 7);
            vb[dt] = *(const bf16x8*)(Vs + row * 128 + u * 16);
          }
#pragma unroll
          for (int dt = 0; dt < 4; ++dt)
            o_acc[dt] = __builtin_amdgcn_mfma_f32_16x16x32_bf16(
                pa, vb[dt], o_acc[dt], 0, 0, 0);
        }
        __builtin_amdgcn_s_setprio(0);
      }
      __syncthreads();
    }
#pragma unroll
    for (int r = 0; r < 4; ++r) {
      float lr = __shfl(l_run, g * 20 + r);
      float inv = 1.f / lr;
      int tokr = q0 + w * 16 + g4 + r;
#pragma unroll
      for (int dt = 0; dt < 4; ++dt) {
        int d = dt * 16 + c;
        ctx[(tokbase + tokr) * DDIM + h * 64 + d] =
            (__bf16)(o_acc[dt][r] * inv);
      }
    }
  }
}

// ---------------------------------------------------------------------------
// aux loss: (mean(probs) - 0.2)^2
// ---------------------------------------------------------------------------
__global__ __launch_bounds__(256) void aux_kernel(const float* __restrict__ probsp,
                                                  float* __restrict__ outp) {
  const int t = threadIdx.x;
  float sum = 0.f;
  for (int i = t; i < NTOK; i += 256) sum += probsp[i];
#pragma unroll
  for (int d = 32; d; d >>= 1) sum += __shfl_down(sum, d);
  __shared__ float ws4[4];
  if ((t & 63) == 0) ws4[t >> 6] = sum;
  __syncthreads();
  if (t == 0) {
    float m = (ws4[0] + ws4[1] + ws4[2] + ws4[3]) * (1.f / NTOK) - 0.2f;
    outp[0] = m * m;
  }
}

// ---------------------------------------------------------------------------
extern "C" void kernel_launch(void* const* d_in, const int* in_sizes, int n_in,
                              void* d_out, int out_size, void* d_ws, size_t ws_size,
                              hipStream_t stream) {
  const float* x      = (const float*)d_in[0];
  const float* gate_w = (const float*)d_in[1];
  const float* gate_b = (const float*)d_in[2];
  const float* wq     = (const float*)d_in[3];
  const float* wk     = (const float*)d_in[4];
  const float* wv     = (const float*)d_in[5];
  const float* wo     = (const float*)d_in[6];
  const float* conv_w = (const float*)d_in[7];
  const float* conv_b = (const float*)d_in[8];
  const float* mlp_w1 = (const float*)d_in[9];
  const float* mlp_b1 = (const float*)d_in[10];
  const float* mlp_w2 = (const float*)d_in[11];
  const float* mlp_b2 = (const float*)d_in[12];
  float* out = (float*)d_out;

  char* ws = (char*)d_ws;
  const size_t MB = 1ull << 20;
  __bf16* xb     = (__bf16*)(ws + 0);
  __bf16* xcb    = (__bf16*)(ws + 16 * MB);
  __bf16* ctx    = (__bf16*)(ws + 16 * MB);    // overlays xcb
  __bf16* wqkv_t = (__bf16*)(ws + 32 * MB);
  __bf16* wo_t   = (__bf16*)(ws + 38 * MB);
  __bf16* w1_t   = (__bf16*)(ws + 40 * MB);
  __bf16* w2_t   = (__bf16*)(ws + 48 * MB);
  float*  maskp  = (float*)(ws + 56 * MB);
  float*  probsp = (float*)(ws + 56 * MB + 65536);
  float2* ropetab= (float2*)(ws + 56 * MB + 131072);  // 512KB
  __bf16* h1     = (__bf16*)(ws + 57 * MB);
  __bf16* qkv    = (__bf16*)(ws + 57 * MB);    // overlays h1

  prep_kernel<<<NTOK, 256, 0, stream>>>(x, gate_w, gate_b, conv_w, conv_b,
                                        xb, xcb, maskp, probsp);
  weights_prep_kernel<<<3328, 256, 0, stream>>>(wq, wk, wv, wo, mlp_w1, mlp_w2,
                                                wqkv_t, wo_t, w1_t, w2_t,
                                                ropetab);

  // Reflexive (MLP) stream first so h1 region can be reused by qkv.
  gemm256p<<<dim3(16, 32), 512, 131072, stream>>>(xcb, w1_t, mlp_b1, h1,
                                                  NTOK, MLPD, DDIM);
  gemm_bt<2><<<dim3(8, 64), 256, 0, stream>>>(h1, w2_t, mlp_b2, x, nullptr,
                                              nullptr, out, NTOK, DDIM, MLPD);
  // Contextual stream (RoPE fused into the QKV epilogue; 128^2 tile so the
  // grid is 1536 blocks = exactly 2 full occupancy rounds at 3 blocks/CU).
  gemm_btq<<<dim3(24, 64), 256, 0, stream>>>(xb, wqkv_t, ropetab, qkv,
                                             NTOK, 3072, DDIM);
  attn_kernel<<<dim3(8, 64), 512, 0, stream>>>(qkv, ctx);
  gemm_bt<3><<<dim3(8, 64), 256, 0, stream>>>(ctx, wo_t, nullptr, nullptr, maskp,
                                              nullptr, out, NTOK, DDIM, DDIM);
  aux_kernel<<<1, 256, 0, stream>>>(probsp, out + (size_t)(out_size - 1));
}

// Round 23
// 357.732 us; speedup vs baseline: 1.1538x; 1.0168x over previous
//
#include <hip/hip_runtime.h>
#include <hip/hip_bf16.h>

#define DDIM 1024
#define SLEN 2048
#define NTOK 8192
#define MLPD 4096

typedef float f32x4 __attribute__((ext_vector_type(4)));
typedef __bf16 bf16x8 __attribute__((ext_vector_type(8)));

__device__ __forceinline__ void async16(void* lds, const void* g) {
  __builtin_amdgcn_global_load_lds(
      (__attribute__((address_space(1))) void*)g,
      (__attribute__((address_space(3))) void*)lds, 16, 0, 0);
}

template <int N> struct VMC { static constexpr int v = N; };

// ---------------------------------------------------------------------------
// transposed cast body: src [K][N] f32 -> dst [N][K] bf16 (one 64x64 tile)
// ---------------------------------------------------------------------------
__device__ __forceinline__ void tcast_body(const float* __restrict__ src,
                                           __bf16* __restrict__ dst,
                                           int K, int N, int n0, int k0) {
  __shared__ __bf16 tile[64][65];
  const int t = threadIdx.x;
  const int cr = (t & 15) * 4;
#pragma unroll
  for (int i = 0; i < 4; ++i) {
    int rr = (t >> 4) + i * 16;
    float4 v = *(const float4*)(src + (size_t)(k0 + rr) * N + n0 + cr);
    tile[rr][cr + 0] = (__bf16)v.x; tile[rr][cr + 1] = (__bf16)v.y;
    tile[rr][cr + 2] = (__bf16)v.z; tile[rr][cr + 3] = (__bf16)v.w;
  }
  __syncthreads();
#pragma unroll
  for (int i = 0; i < 2; ++i) {
    int c = t + i * 256;
    int nl = c >> 3, koff = (c & 7) * 8;
    union { uint4 u; __bf16 b[8]; } o;
#pragma unroll
    for (int j = 0; j < 8; ++j) o.b[j] = tile[koff + j][nl];
    *(uint4*)(dst + (size_t)(n0 + nl) * K + k0 + koff) = o.u;
  }
}

// ---------------------------------------------------------------------------
// prep_all: token prep (wave-per-token) + ALL weight casts + RoPE table,
// ONE dispatch, flat grid 5376 blocks (block-uniform branches):
//   [0,2048):    token prep, 4 tokens/block (one 64-lane wave per token):
//                router logits/mask/probs, causal conv k=3, x -> bf16
//   [2048,3072): wq/wk/wv/wo casts (4 x 256 tiles of 1024x1024)
//   [3072,4096): mlp_w1 cast (K=1024, N=4096)
//   [4096,5120): mlp_w2 cast (K=4096, N=1024)
//   [5120,5376): tab[s][i] = (cos(s*invf), sin(s*invf))
// ---------------------------------------------------------------------------
__global__ __launch_bounds__(256) void prep_all_kernel(
    const float* __restrict__ x, const float* __restrict__ gate_w,
    const float* __restrict__ gate_b, const float* __restrict__ conv_w,
    const float* __restrict__ conv_b, __bf16* __restrict__ xb,
    __bf16* __restrict__ xcb, float* __restrict__ maskp,
    float* __restrict__ probsp,
    const float* __restrict__ wq, const float* __restrict__ wk,
    const float* __restrict__ wv, const float* __restrict__ wo,
    const float* __restrict__ w1, const float* __restrict__ w2,
    __bf16* __restrict__ dqkv, __bf16* __restrict__ dwo,
    __bf16* __restrict__ dw1, __bf16* __restrict__ dw2,
    float2* __restrict__ tab) {
  const int id = blockIdx.x;
  if (id < 2048) {
    // ---- token prep: one wave per token, no LDS, no barriers ----
    const int wv0 = threadIdx.x >> 6, lane = threadIdx.x & 63;
    const int tok = id * 4 + wv0;
    const int s = tok & (SLEN - 1);
    const float* xr = x + (size_t)tok * DDIM;
    float4 v[4], g4v[4];
#pragma unroll
    for (int i = 0; i < 4; ++i) {
      v[i] = ((const float4*)xr)[lane + i * 64];
      g4v[i] = ((const float4*)gate_w)[lane + i * 64];
    }
    float part = 0.f;
#pragma unroll
    for (int i = 0; i < 4; ++i)
      part += v[i].x * g4v[i].x + v[i].y * g4v[i].y + v[i].z * g4v[i].z +
              v[i].w * g4v[i].w;
#pragma unroll
    for (int d = 32; d; d >>= 1) part += __shfl_down(part, d);
    if (lane == 0) {
      float logit = part + gate_b[0];
      float prob = 1.f / (1.f + __expf(-logit));
      probsp[tok] = prob;
      maskp[tok] = prob > 0.5f ? 1.f : 0.f;
    }
    // cast x -> bf16
#pragma unroll
    for (int i = 0; i < 4; ++i) {
      union { ushort4 u; __bf16 b[4]; } xo;
      xo.b[0] = (__bf16)v[i].x; xo.b[1] = (__bf16)v[i].y;
      xo.b[2] = (__bf16)v[i].z; xo.b[3] = (__bf16)v[i].w;
      ((ushort4*)(xb + (size_t)tok * DDIM))[lane + i * 64] = xo.u;
    }
    // causal conv (left pad 2 within batch)
    float4 zero4 = {0.f, 0.f, 0.f, 0.f};
#pragma unroll
    for (int i = 0; i < 4; ++i) {
      float4 m1 = (s >= 1) ? ((const float4*)(xr - DDIM))[lane + i * 64] : zero4;
      float4 m2 = (s >= 2) ? ((const float4*)(xr - 2 * DDIM))[lane + i * 64] : zero4;
      int d0 = (lane + i * 64) * 4;
      float vv[4] = {v[i].x, v[i].y, v[i].z, v[i].w};
      float a1[4] = {m1.x, m1.y, m1.z, m1.w};
      float a2[4] = {m2.x, m2.y, m2.z, m2.w};
      union { ushort4 u; __bf16 b[4]; } co;
#pragma unroll
      for (int j = 0; j < 4; ++j) {
        float c0 = conv_w[(d0 + j) * 3 + 0];
        float c1 = conv_w[(d0 + j) * 3 + 1];
        float c2 = conv_w[(d0 + j) * 3 + 2];
        float r = a2[j] * c0 + a1[j] * c1 + vv[j] * c2 + conv_b[d0 + j];
        co.b[j] = (__bf16)r;
      }
      ((ushort4*)(xcb + (size_t)tok * DDIM))[lane + i * 64] = co.u;
    }
    return;
  }
  if (id >= 5120) {
    const int idx = (id - 5120) * 256 + threadIdx.x;
    const int s = idx >> 5, i = idx & 31;
    float invf = __builtin_amdgcn_exp2f(-(float)i * (13.28771238f / 32.f));
    float fr = (float)s * invf;
    tab[idx] = make_float2(cosf(fr), sinf(fr));
    return;
  }
  const float* src;
  __bf16* dst;
  int K, N, n0, k0;
  if (id < 3072) {
    const int z = (id - 2048) >> 8, tile = id & 255;
    src = z == 0 ? wq : z == 1 ? wk : z == 2 ? wv : wo;
    dst = z < 3 ? dqkv + (size_t)z * 1024 * 1024 : dwo;
    K = 1024; N = 1024; n0 = (tile & 15) * 64; k0 = (tile >> 4) * 64;
  } else if (id < 4096) {
    const int tile = id - 3072;
    src = w1; dst = dw1;
    K = 1024; N = 4096; n0 = (tile & 63) * 64; k0 = (tile >> 6) * 64;
  } else {
    const int tile = id - 4096;
    src = w2; dst = dw2;
    K = 4096; N = 1024; n0 = (tile & 15) * 64; k0 = (tile >> 4) * 64;
  }
  tcast_body(src, dst, K, N, n0, k0);
}

// ---------------------------------------------------------------------------
// 256x256 pipelined GEMM (ring-4, counted vmcnt). EPI: bf16 relu(v+bias).
// Used for MLP1 only (grid 512 = 2 exact occupancy rounds at 1 block/CU).
// ---------------------------------------------------------------------------
__global__ __launch_bounds__(512, 2) void gemm256p(
    const __bf16* __restrict__ A, const __bf16* __restrict__ Bt,
    const float* __restrict__ bias, __bf16* __restrict__ Cb,
    int M, int N, int K) {
  extern __shared__ char sm[];
  const int t = threadIdx.x, lane = t & 63, w = t >> 6;
  const int c = lane & 15, g = lane >> 4;
  const int nwg = gridDim.x * gridDim.y;
  const int wgid = blockIdx.y * gridDim.x + blockIdx.x;
  const int swz = (wgid & 7) * (nwg >> 3) + (wgid >> 3);
  const int m0 = (swz / gridDim.x) * 256, n0 = (swz % gridDim.x) * 256;
  const int wm = (w >> 2) * 128, wn = (w & 3) * 64;

  f32x4 acc[8][4] = {};
  const int nk = K >> 5;

  auto stage = [&](int buf, int kt) {
    const int k0 = kt << 5;
    char* base = sm + buf * 32768;
#pragma unroll
    for (int r = 0; r < 2; ++r) {
      int o = ((r * 8 + w) << 10) + (lane << 4);
      int rp = o >> 7;
      int u = (o >> 4) & 7;
      int l = u ^ (rp & 7);
      int mr = rp * 2 + (l >> 2);
      int kk = (l & 3) * 8;
      async16(base + o, A + (size_t)(m0 + mr) * K + k0 + kk);
      async16(base + 16384 + o, Bt + (size_t)(n0 + mr) * K + k0 + kk);
    }
  };

  auto body = [&](auto vmc, int tt, bool dostage) {
    if (dostage) stage((tt + 3) & 3, tt + 3);
    asm volatile("s_waitcnt vmcnt(%0)" ::"n"(decltype(vmc)::v) : "memory");
    __builtin_amdgcn_s_barrier();
    asm volatile("" ::: "memory");
    const char* Ab = sm + (tt & 3) * 32768;
    const char* Bb = Ab + 16384;
    bf16x8 aq[8], bq[4];
#pragma unroll
    for (int nt = 0; nt < 4; ++nt) {
      int row = wn + nt * 16 + c;
      int rp = row >> 1;
      int u = ((row & 1) * 4 + g) ^ (rp & 7);
      bq[nt] = *(const bf16x8*)(Bb + rp * 128 + u * 16);
    }
#pragma unroll
    for (int i = 0; i < 8; ++i) {
      int row = wm + i * 16 + c;
      int rp = row >> 1;
      int u = ((row & 1) * 4 + g) ^ (rp & 7);
      aq[i] = *(const bf16x8*)(Ab + rp * 128 + u * 16);
    }
    __builtin_amdgcn_s_setprio(1);
#pragma unroll
    for (int i = 0; i < 8; ++i)
#pragma unroll
      for (int nt = 0; nt < 4; ++nt)
        acc[i][nt] = __builtin_amdgcn_mfma_f32_16x16x32_bf16(
            aq[i], bq[nt], acc[i][nt], 0, 0, 0);
    __builtin_amdgcn_s_setprio(0);
    __builtin_amdgcn_s_barrier();
    asm volatile("" ::: "memory");
  };

  stage(0, 0);
  stage(1, 1);
  stage(2, 2);
  int tt = 0;
  for (; tt < nk - 3; ++tt) body(VMC<12>{}, tt, true);
  body(VMC<8>{}, tt, false); ++tt;
  body(VMC<4>{}, tt, false); ++tt;
  body(VMC<0>{}, tt, false);

#pragma unroll
  for (int i = 0; i < 8; ++i)
#pragma unroll
    for (int nt = 0; nt < 4; ++nt)
#pragma unroll
      for (int r = 0; r < 4; ++r) {
        int row = m0 + wm + i * 16 + g * 4 + r;
        int col = n0 + wn + nt * 16 + c;
        float v = acc[i][nt][r] + bias[col];
        Cb[(size_t)row * N + col] = (__bf16)fmaxf(v, 0.f);
      }
}

// ---------------------------------------------------------------------------
// GEMM 128x128 for QKV with fused RoPE: bf16 store; for n0 < 2048 (q,k
// regions) rotate pairs (i, i+32) which live in fragments (nt, nt+2) of the
// same thread (i = nt*16 + c for nt in {0,1}); s = row & 2047.
// Grid (24,64) = 1536 blocks at 3/CU = exactly 2 full occupancy rounds.
// ---------------------------------------------------------------------------
__global__ __launch_bounds__(256, 3) void gemm_btq(
    const __bf16* __restrict__ A, const __bf16* __restrict__ Bt,
    const float2* __restrict__ tab, __bf16* __restrict__ Cb,
    int M, int N, int K) {
  __shared__ char smem[32768];
  char* As = smem;
  char* Bs = smem + 16384;
  const int t = threadIdx.x, lane = t & 63, w = t >> 6;
  const int nwg = gridDim.x * gridDim.y;
  const int wgid = blockIdx.y * gridDim.x + blockIdx.x;
  const int swz = (wgid & 7) * (nwg >> 3) + (wgid >> 3);
  const int m0 = (swz / gridDim.x) * 128, n0 = (swz % gridDim.x) * 128;
  const int wm = (w >> 1) * 64, wn = (w & 1) * 64;
  const int c = lane & 15, g = lane >> 4;
  f32x4 acc[4][4] = {};
  const int nk = K >> 6;
  for (int kt = 0; kt < nk; ++kt) {
    const int k0 = kt << 6;
#pragma unroll
    for (int rd = 0; rd < 4; ++rd) {
      int o = ((rd * 4 + w) << 10) + (lane << 4);
      int row = o >> 7;
      int us = ((o >> 4) & 7) ^ (row & 7);
      async16(As + o, A + (size_t)(m0 + row) * K + k0 + us * 8);
      async16(Bs + o, Bt + (size_t)(n0 + row) * K + k0 + us * 8);
    }
    __syncthreads();
#pragma unroll
    for (int ks = 0; ks < 2; ++ks) {
      bf16x8 af[4], bfr[4];
#pragma unroll
      for (int mt = 0; mt < 4; ++mt) {
        int row = wm + mt * 16 + c;
        int u = (ks * 4 + g) ^ (row & 7);
        af[mt] = *(const bf16x8*)(As + row * 128 + u * 16);
      }
#pragma unroll
      for (int nt = 0; nt < 4; ++nt) {
        int row = wn + nt * 16 + c;
        int u = (ks * 4 + g) ^ (row & 7);
        bfr[nt] = *(const bf16x8*)(Bs + row * 128 + u * 16);
      }
#pragma unroll
      for (int mt = 0; mt < 4; ++mt)
#pragma unroll
        for (int nt = 0; nt < 4; ++nt)
          acc[mt][nt] = __builtin_amdgcn_mfma_f32_16x16x32_bf16(
              af[mt], bfr[nt], acc[mt][nt], 0, 0, 0);
    }
    __syncthreads();
  }
  // fused RoPE (q,k cols only)
  if (n0 < 2048) {
#pragma unroll
    for (int mt = 0; mt < 4; ++mt)
#pragma unroll
      for (int r = 0; r < 4; ++r) {
        int s = (m0 + wm + mt * 16 + g * 4 + r) & (SLEN - 1);
        float2 t0 = tab[s * 32 + c];
        float2 t1 = tab[s * 32 + 16 + c];
        float q0 = acc[mt][0][r], q2 = acc[mt][2][r];
        acc[mt][0][r] = q0 * t0.x - q2 * t0.y;
        acc[mt][2][r] = q2 * t0.x + q0 * t0.y;
        float q1 = acc[mt][1][r], q3 = acc[mt][3][r];
        acc[mt][1][r] = q1 * t1.x - q3 * t1.y;
        acc[mt][3][r] = q3 * t1.x + q1 * t1.y;
      }
  }
#pragma unroll
  for (int mt = 0; mt < 4; ++mt)
#pragma unroll
    for (int nt = 0; nt < 4; ++nt)
#pragma unroll
      for (int r = 0; r < 4; ++r) {
        int row = m0 + wm + mt * 16 + g * 4 + r;
        int col = n0 + wn + nt * 16 + c;
        Cb[(size_t)row * N + col] = (__bf16)acc[mt][nt][r];
      }
}

// ---------------------------------------------------------------------------
// GEMM 128x128 (MLP2/WO): EPI 2 = f32 out = xres+v+bias; 3 = out += mask*v
// ---------------------------------------------------------------------------
template <int EPI>
__global__ __launch_bounds__(256, 3) void gemm_bt(
    const __bf16* __restrict__ A, const __bf16* __restrict__ Bt,
    const float* __restrict__ bias, const float* __restrict__ xres,
    const float* __restrict__ maskp, __bf16* __restrict__ Cb,
    float* __restrict__ Cf, int M, int N, int K) {
  __shared__ char smem[32768];
  char* As = smem;
  char* Bs = smem + 16384;
  const int t = threadIdx.x, lane = t & 63, w = t >> 6;
  const int nwg = gridDim.x * gridDim.y;
  const int wgid = blockIdx.y * gridDim.x + blockIdx.x;
  const int swz = (wgid & 7) * (nwg >> 3) + (wgid >> 3);
  const int m0 = (swz / gridDim.x) * 128, n0 = (swz % gridDim.x) * 128;
  const int wm = (w >> 1) * 64, wn = (w & 1) * 64;
  f32x4 acc[4][4] = {};
  const int nk = K >> 6;
  for (int kt = 0; kt < nk; ++kt) {
    const int k0 = kt << 6;
#pragma unroll
    for (int rd = 0; rd < 4; ++rd) {
      int o = ((rd * 4 + w) << 10) + (lane << 4);
      int row = o >> 7;
      int us = ((o >> 4) & 7) ^ (row & 7);
      async16(As + o, A + (size_t)(m0 + row) * K + k0 + us * 8);
      async16(Bs + o, Bt + (size_t)(n0 + row) * K + k0 + us * 8);
    }
    __syncthreads();
#pragma unroll
    for (int ks = 0; ks < 2; ++ks) {
      bf16x8 af[4], bfr[4];
#pragma unroll
      for (int mt = 0; mt < 4; ++mt) {
        int row = wm + mt * 16 + (lane & 15);
        int u = (ks * 4 + (lane >> 4)) ^ (row & 7);
        af[mt] = *(const bf16x8*)(As + row * 128 + u * 16);
      }
#pragma unroll
      for (int nt = 0; nt < 4; ++nt) {
        int row = wn + nt * 16 + (lane & 15);
        int u = (ks * 4 + (lane >> 4)) ^ (row & 7);
        bfr[nt] = *(const bf16x8*)(Bs + row * 128 + u * 16);
      }
#pragma unroll
      for (int mt = 0; mt < 4; ++mt)
#pragma unroll
        for (int nt = 0; nt < 4; ++nt)
          acc[mt][nt] = __builtin_amdgcn_mfma_f32_16x16x32_bf16(
              af[mt], bfr[nt], acc[mt][nt], 0, 0, 0);
    }
    __syncthreads();
  }
#pragma unroll
  for (int mt = 0; mt < 4; ++mt)
#pragma unroll
    for (int nt = 0; nt < 4; ++nt)
#pragma unroll
      for (int r = 0; r < 4; ++r) {
        int row = m0 + wm + mt * 16 + ((lane >> 4) << 2) + r;
        int col = n0 + wn + nt * 16 + (lane & 15);
        float v = acc[mt][nt][r];
        size_t idx = (size_t)row * N + col;
        if constexpr (EPI == 2) {
          Cf[idx] = xres[idx] + v + bias[col];
        } else {
          Cf[idx] += maskp[row] * v;
        }
      }
}

// ---------------------------------------------------------------------------
// V scatter (8-wave): wave w owns d = w*8..w*8+7, lane = k-token
// ---------------------------------------------------------------------------
__device__ __forceinline__ void scatterV8(char* Vdst, int w, int lane, float4 va) {
  union { float4 f; __bf16 bv[8]; } u0;
  u0.f = va;
#pragma unroll
  for (int j = 0; j < 8; ++j) {
    int d = w * 8 + j;
    int by = d * 128 + (((lane >> 3) ^ (d & 7)) << 4) + ((lane & 7) << 1);
    *(__bf16*)(Vdst + by) = u0.bv[j];
  }
}

// ---------------------------------------------------------------------------
// Flash attention, causal, swapped QK^T, in-lane softmax — 8-wave version
// (verified R18/R21/R22: 16 waves/CU, no spill). XCD bh-grouping. Defer-max.
// ---------------------------------------------------------------------------
__global__ __launch_bounds__(512, 4) void attn_kernel(const __bf16* __restrict__ qkv,
                                                      __bf16* __restrict__ ctx) {
  __shared__ char sm[32768];
  const int t = threadIdx.x, lane = t & 63, w = t >> 6;  // w in 0..7
  const int c = lane & 15, g = lane >> 4, g4 = g * 4;
  const int bh = (int)blockIdx.x * 8 + ((int)blockIdx.y & 7);
  const int qp = (int)blockIdx.y >> 3;
  const int h = bh & 15, b = bh >> 4;
  const size_t tokbase = (size_t)b * SLEN;
  const __bf16* qg = qkv + tokbase * 3072 + h * 64;
  const __bf16* kg = qg + 1024;
  const __bf16* vg = qg + 2048;
  const float SCL = 0.125f * 1.44269504f;  // 1/sqrt(64) * log2(e)
  char* Ps = sm + (w << 11);   // 2KB per wave
  char* Ks = sm + 16384;
  char* Vs = sm + 24576;

  for (int ph = 0; ph < 2; ++ph) {
    const int qt = ph == 0 ? qp : 15 - qp;
    const int q0 = qt * 128;
#pragma unroll
    for (int rd = 0; rd < 2; ++rd) {
      int o = ((rd * 8 + w) << 10) + (lane << 4);
      int row = o >> 7;
      int us = ((o >> 4) & 7) ^ (row & 7);
      async16(sm + o, qg + (size_t)(q0 + row) * 3072 + us * 8);
    }
    __syncthreads();
    bf16x8 qb[2];
#pragma unroll
    for (int ks = 0; ks < 2; ++ks) {
      int row = w * 16 + c;
      int u = (ks * 4 + g) ^ (row & 7);
      qb[ks] = *(const bf16x8*)(sm + row * 128 + u * 16);
    }

    float m_run = -1e30f, l_run = 0.f;
    f32x4 o_acc[4] = {};
    const int nkt = (q0 + 128) >> 6;
    const int wrow0 = q0 + w * 16;

    for (int kt = 0; kt < nkt; ++kt) {
      const int k0 = kt << 6;
      {
        int o = (w << 10) + (lane << 4);
        int row = o >> 7;
        int us = ((o >> 4) & 7) ^ (row & 7);
        async16(Ks + o, kg + (size_t)(k0 + row) * 3072 + us * 8);
        float4 va = *(const float4*)(vg + (size_t)(k0 + lane) * 3072 + w * 8);
        scatterV8(Vs, w, lane, va);
      }
      __syncthreads();
      if (k0 <= wrow0 + 15) {
        f32x4 st[4] = {};
        __builtin_amdgcn_s_setprio(1);
#pragma unroll
        for (int ks = 0; ks < 2; ++ks) {
          bf16x8 ka[4];
#pragma unroll
          for (int nt = 0; nt < 4; ++nt) {
            int row = nt * 16 + c;
            int u = (ks * 4 + g) ^ (row & 7);
            ka[nt] = *(const bf16x8*)(Ks + row * 128 + u * 16);
          }
#pragma unroll
          for (int nt = 0; nt < 4; ++nt)
            st[nt] = __builtin_amdgcn_mfma_f32_16x16x32_bf16(
                ka[nt], qb[ks], st[nt], 0, 0, 0);
        }
        __builtin_amdgcn_s_setprio(0);
        const bool needmask = (k0 + 63) > wrow0;
        float mx = -1e30f;
        if (needmask) {
          int qglob = wrow0 + c;
#pragma unroll
          for (int nt = 0; nt < 4; ++nt)
#pragma unroll
            for (int r = 0; r < 4; ++r) {
              float sv = st[nt][r] * SCL;
              if (k0 + nt * 16 + g4 + r > qglob) sv = -1e30f;
              st[nt][r] = sv;
              mx = fmaxf(mx, sv);
            }
        } else {
#pragma unroll
          for (int nt = 0; nt < 4; ++nt)
#pragma unroll
            for (int r = 0; r < 4; ++r) {
              float sv = st[nt][r] * SCL;
              st[nt][r] = sv;
              mx = fmaxf(mx, sv);
            }
        }
        mx = fmaxf(mx, __shfl_xor(mx, 16));
        mx = fmaxf(mx, __shfl_xor(mx, 32));
        const bool skip = __all(mx - m_run <= 8.f) != 0;
        float mnew = skip ? m_run : fmaxf(m_run, mx);
        float rs = 0.f;
#pragma unroll
        for (int nt = 0; nt < 4; ++nt)
#pragma unroll
          for (int r = 0; r < 4; ++r) {
            float p = __builtin_amdgcn_exp2f(st[nt][r] - mnew);
            st[nt][r] = p;
            rs += p;
          }
        rs += __shfl_xor(rs, 16);
        rs += __shfl_xor(rs, 32);
        if (skip) {
          l_run += rs;
        } else {
          float fac = __builtin_amdgcn_exp2f(m_run - mnew);
          m_run = mnew;
          l_run = l_run * fac + rs;
#pragma unroll
          for (int r = 0; r < 4; ++r) {
            float fr = __shfl(fac, g * 20 + r);
#pragma unroll
            for (int dt = 0; dt < 4; ++dt) o_acc[dt][r] *= fr;
          }
        }
        {
          int rbase = c * 128 + 8 * (g & 1);
#pragma unroll
          for (int nt = 0; nt < 4; ++nt) {
            int us = (2 * nt + (g >> 1)) ^ (c & 7);
            union { uint2 v; __bf16 bb[4]; } pp;
            pp.bb[0] = (__bf16)st[nt][0]; pp.bb[1] = (__bf16)st[nt][1];
            pp.bb[2] = (__bf16)st[nt][2]; pp.bb[3] = (__bf16)st[nt][3];
            *(uint2*)(Ps + rbase + us * 16) = pp.v;
          }
        }
        __builtin_amdgcn_s_setprio(1);
#pragma unroll
        for (int ks = 0; ks < 2; ++ks) {
          bf16x8 pa, vb[4];
          {
            int u = (ks * 4 + g) ^ (c & 7);
            pa = *(const bf16x8*)(Ps + c * 128 + u * 16);
          }
#pragma unroll
          for (int dt = 0; dt < 4; ++dt) {
            int row = dt * 16 + c;
            int u = (ks * 4 + g) ^ (row & 7);
            vb[dt] = *(const bf16x8*)(Vs + row * 128 + u * 16);
          }
#pragma unroll
          for (int dt = 0; dt < 4; ++dt)
            o_acc[dt] = __builtin_amdgcn_mfma_f32_16x16x32_bf16(
                pa, vb[dt], o_acc[dt], 0, 0, 0);
        }
        __builtin_amdgcn_s_setprio(0);
      }
      __syncthreads();
    }
#pragma unroll
    for (int r = 0; r < 4; ++r) {
      float lr = __shfl(l_run, g * 20 + r);
      float inv = 1.f / lr;
      int tokr = q0 + w * 16 + g4 + r;
#pragma unroll
      for (int dt = 0; dt < 4; ++dt) {
        int d = dt * 16 + c;
        ctx[(tokbase + tokr) * DDIM + h * 64 + d] =
            (__bf16)(o_acc[dt][r] * inv);
      }
    }
  }
}

// ---------------------------------------------------------------------------
// aux loss: (mean(probs) - 0.2)^2
// ---------------------------------------------------------------------------
__global__ __launch_bounds__(256) void aux_kernel(const float* __restrict__ probsp,
                                                  float* __restrict__ outp) {
  const int t = threadIdx.x;
  float sum = 0.f;
  for (int i = t; i < NTOK; i += 256) sum += probsp[i];
#pragma unroll
  for (int d = 32; d; d >>= 1) sum += __shfl_down(sum, d);
  __shared__ float ws4[4];
  if ((t & 63) == 0) ws4[t >> 6] = sum;
  __syncthreads();
  if (t == 0) {
    float m = (ws4[0] + ws4[1] + ws4[2] + ws4[3]) * (1.f / NTOK) - 0.2f;
    outp[0] = m * m;
  }
}

// ---------------------------------------------------------------------------
extern "C" void kernel_launch(void* const* d_in, const int* in_sizes, int n_in,
                              void* d_out, int out_size, void* d_ws, size_t ws_size,
                              hipStream_t stream) {
  const float* x      = (const float*)d_in[0];
  const float* gate_w = (const float*)d_in[1];
  const float* gate_b = (const float*)d_in[2];
  const float* wq     = (const float*)d_in[3];
  const float* wk     = (const float*)d_in[4];
  const float* wv     = (const float*)d_in[5];
  const float* wo     = (const float*)d_in[6];
  const float* conv_w = (const float*)d_in[7];
  const float* conv_b = (const float*)d_in[8];
  const float* mlp_w1 = (const float*)d_in[9];
  const float* mlp_b1 = (const float*)d_in[10];
  const float* mlp_w2 = (const float*)d_in[11];
  const float* mlp_b2 = (const float*)d_in[12];
  float* out = (float*)d_out;

  char* ws = (char*)d_ws;
  const size_t MB = 1ull << 20;
  __bf16* xb     = (__bf16*)(ws + 0);
  __bf16* xcb    = (__bf16*)(ws + 16 * MB);
  __bf16* ctx    = (__bf16*)(ws + 16 * MB);    // overlays xcb
  __bf16* wqkv_t = (__bf16*)(ws + 32 * MB);
  __bf16* wo_t   = (__bf16*)(ws + 38 * MB);
  __bf16* w1_t   = (__bf16*)(ws + 40 * MB);
  __bf16* w2_t   = (__bf16*)(ws + 48 * MB);
  float*  maskp  = (float*)(ws + 56 * MB);
  float*  probsp = (float*)(ws + 56 * MB + 65536);
  float2* ropetab= (float2*)(ws + 56 * MB + 131072);  // 512KB
  __bf16* h1     = (__bf16*)(ws + 57 * MB);
  __bf16* qkv    = (__bf16*)(ws + 57 * MB);    // overlays h1

  prep_all_kernel<<<5376, 256, 0, stream>>>(
      x, gate_w, gate_b, conv_w, conv_b, xb, xcb, maskp, probsp,
      wq, wk, wv, wo, mlp_w1, mlp_w2, wqkv_t, wo_t, w1_t, w2_t, ropetab);

  // Reflexive (MLP) stream first so h1 region can be reused by qkv.
  gemm256p<<<dim3(16, 32), 512, 131072, stream>>>(xcb, w1_t, mlp_b1, h1,
                                                  NTOK, MLPD, DDIM);
  gemm_bt<2><<<dim3(8, 64), 256, 0, stream>>>(h1, w2_t, mlp_b2, x, nullptr,
                                              nullptr, out, NTOK, DDIM, MLPD);
  // Contextual stream (RoPE fused into the QKV epilogue; 128^2 tile so the
  // grid is 1536 blocks = exactly 2 full occupancy rounds at 3 blocks/CU).
  gemm_btq<<<dim3(24, 64), 256, 0, stream>>>(xb, wqkv_t, ropetab, qkv,
                                             NTOK, 3072, DDIM);
  attn_kernel<<<dim3(8, 64), 512, 0, stream>>>(qkv, ctx);
  gemm_bt<3><<<dim3(8, 64), 256, 0, stream>>>(ctx, wo_t, nullptr, nullptr, maskp,
                                              nullptr, out, NTOK, DDIM, DDIM);
  aux_kernel<<<1, 256, 0, stream>>>(probsp, out + (size_t)(out_size - 1));
}

// Round 24
// 352.440 us; speedup vs baseline: 1.1711x; 1.0150x over previous
//
#include <hip/hip_runtime.h>
#include <hip/hip_bf16.h>

#define DDIM 1024
#define SLEN 2048
#define NTOK 8192
#define MLPD 4096

typedef float f32x4 __attribute__((ext_vector_type(4)));
typedef __bf16 bf16x8 __attribute__((ext_vector_type(8)));

__device__ __forceinline__ void async16(void* lds, const void* g) {
  __builtin_amdgcn_global_load_lds(
      (__attribute__((address_space(1))) void*)g,
      (__attribute__((address_space(3))) void*)lds, 16, 0, 0);
}

template <int N> struct VMC { static constexpr int v = N; };

// ---------------------------------------------------------------------------
// transposed cast body: src [K][N] f32 -> dst [N][K] bf16 (one 64x64 tile)
// ---------------------------------------------------------------------------
__device__ __forceinline__ void tcast_body(const float* __restrict__ src,
                                           __bf16* __restrict__ dst,
                                           int K, int N, int n0, int k0) {
  __shared__ __bf16 tile[64][65];
  const int t = threadIdx.x;
  const int cr = (t & 15) * 4;
#pragma unroll
  for (int i = 0; i < 4; ++i) {
    int rr = (t >> 4) + i * 16;
    float4 v = *(const float4*)(src + (size_t)(k0 + rr) * N + n0 + cr);
    tile[rr][cr + 0] = (__bf16)v.x; tile[rr][cr + 1] = (__bf16)v.y;
    tile[rr][cr + 2] = (__bf16)v.z; tile[rr][cr + 3] = (__bf16)v.w;
  }
  __syncthreads();
#pragma unroll
  for (int i = 0; i < 2; ++i) {
    int c = t + i * 256;
    int nl = c >> 3, koff = (c & 7) * 8;
    union { uint4 u; __bf16 b[8]; } o;
#pragma unroll
    for (int j = 0; j < 8; ++j) o.b[j] = tile[koff + j][nl];
    *(uint4*)(dst + (size_t)(n0 + nl) * K + k0 + koff) = o.u;
  }
}

// ---------------------------------------------------------------------------
// prep_all: token prep (wave-per-token) + ALL weight casts + RoPE table,
// ONE dispatch, flat grid 5376 blocks (block-uniform branches):
//   [0,2048):    token prep, 4 tokens/block (one 64-lane wave per token)
//   [2048,3072): wq/wk/wv/wo casts   [3072,4096): mlp_w1   [4096,5120): mlp_w2
//   [5120,5376): RoPE trig table
// ---------------------------------------------------------------------------
__global__ __launch_bounds__(256) void prep_all_kernel(
    const float* __restrict__ x, const float* __restrict__ gate_w,
    const float* __restrict__ gate_b, const float* __restrict__ conv_w,
    const float* __restrict__ conv_b, __bf16* __restrict__ xb,
    __bf16* __restrict__ xcb, float* __restrict__ maskp,
    float* __restrict__ probsp,
    const float* __restrict__ wq, const float* __restrict__ wk,
    const float* __restrict__ wv, const float* __restrict__ wo,
    const float* __restrict__ w1, const float* __restrict__ w2,
    __bf16* __restrict__ dqkv, __bf16* __restrict__ dwo,
    __bf16* __restrict__ dw1, __bf16* __restrict__ dw2,
    float2* __restrict__ tab) {
  const int id = blockIdx.x;
  if (id < 2048) {
    const int wv0 = threadIdx.x >> 6, lane = threadIdx.x & 63;
    const int tok = id * 4 + wv0;
    const int s = tok & (SLEN - 1);
    const float* xr = x + (size_t)tok * DDIM;
    float4 v[4], g4v[4];
#pragma unroll
    for (int i = 0; i < 4; ++i) {
      v[i] = ((const float4*)xr)[lane + i * 64];
      g4v[i] = ((const float4*)gate_w)[lane + i * 64];
    }
    float part = 0.f;
#pragma unroll
    for (int i = 0; i < 4; ++i)
      part += v[i].x * g4v[i].x + v[i].y * g4v[i].y + v[i].z * g4v[i].z +
              v[i].w * g4v[i].w;
#pragma unroll
    for (int d = 32; d; d >>= 1) part += __shfl_down(part, d);
    if (lane == 0) {
      float logit = part + gate_b[0];
      float prob = 1.f / (1.f + __expf(-logit));
      probsp[tok] = prob;
      maskp[tok] = prob > 0.5f ? 1.f : 0.f;
    }
#pragma unroll
    for (int i = 0; i < 4; ++i) {
      union { ushort4 u; __bf16 b[4]; } xo;
      xo.b[0] = (__bf16)v[i].x; xo.b[1] = (__bf16)v[i].y;
      xo.b[2] = (__bf16)v[i].z; xo.b[3] = (__bf16)v[i].w;
      ((ushort4*)(xb + (size_t)tok * DDIM))[lane + i * 64] = xo.u;
    }
    float4 zero4 = {0.f, 0.f, 0.f, 0.f};
#pragma unroll
    for (int i = 0; i < 4; ++i) {
      float4 m1 = (s >= 1) ? ((const float4*)(xr - DDIM))[lane + i * 64] : zero4;
      float4 m2 = (s >= 2) ? ((const float4*)(xr - 2 * DDIM))[lane + i * 64] : zero4;
      int d0 = (lane + i * 64) * 4;
      float vv[4] = {v[i].x, v[i].y, v[i].z, v[i].w};
      float a1[4] = {m1.x, m1.y, m1.z, m1.w};
      float a2[4] = {m2.x, m2.y, m2.z, m2.w};
      union { ushort4 u; __bf16 b[4]; } co;
#pragma unroll
      for (int j = 0; j < 4; ++j) {
        float c0 = conv_w[(d0 + j) * 3 + 0];
        float c1 = conv_w[(d0 + j) * 3 + 1];
        float c2 = conv_w[(d0 + j) * 3 + 2];
        float r = a2[j] * c0 + a1[j] * c1 + vv[j] * c2 + conv_b[d0 + j];
        co.b[j] = (__bf16)r;
      }
      ((ushort4*)(xcb + (size_t)tok * DDIM))[lane + i * 64] = co.u;
    }
    return;
  }
  if (id >= 5120) {
    const int idx = (id - 5120) * 256 + threadIdx.x;
    const int s = idx >> 5, i = idx & 31;
    float invf = __builtin_amdgcn_exp2f(-(float)i * (13.28771238f / 32.f));
    float fr = (float)s * invf;
    tab[idx] = make_float2(cosf(fr), sinf(fr));
    return;
  }
  const float* src;
  __bf16* dst;
  int K, N, n0, k0;
  if (id < 3072) {
    const int z = (id - 2048) >> 8, tile = id & 255;
    src = z == 0 ? wq : z == 1 ? wk : z == 2 ? wv : wo;
    dst = z < 3 ? dqkv + (size_t)z * 1024 * 1024 : dwo;
    K = 1024; N = 1024; n0 = (tile & 15) * 64; k0 = (tile >> 4) * 64;
  } else if (id < 4096) {
    const int tile = id - 3072;
    src = w1; dst = dw1;
    K = 1024; N = 4096; n0 = (tile & 63) * 64; k0 = (tile >> 6) * 64;
  } else {
    const int tile = id - 4096;
    src = w2; dst = dw2;
    K = 4096; N = 1024; n0 = (tile & 15) * 64; k0 = (tile >> 4) * 64;
  }
  tcast_body(src, dst, K, N, n0, k0);
}

// ---------------------------------------------------------------------------
// 256x256 pipelined GEMM (ring-4, counted vmcnt). EPI: bf16 relu(v+bias).
// Used for MLP1 only (grid 512 = 2 exact occupancy rounds at 1 block/CU).
// ---------------------------------------------------------------------------
__global__ __launch_bounds__(512, 2) void gemm256p(
    const __bf16* __restrict__ A, const __bf16* __restrict__ Bt,
    const float* __restrict__ bias, __bf16* __restrict__ Cb,
    int M, int N, int K) {
  extern __shared__ char sm[];
  const int t = threadIdx.x, lane = t & 63, w = t >> 6;
  const int c = lane & 15, g = lane >> 4;
  const int nwg = gridDim.x * gridDim.y;
  const int wgid = blockIdx.y * gridDim.x + blockIdx.x;
  const int swz = (wgid & 7) * (nwg >> 3) + (wgid >> 3);
  const int m0 = (swz / gridDim.x) * 256, n0 = (swz % gridDim.x) * 256;
  const int wm = (w >> 2) * 128, wn = (w & 3) * 64;

  f32x4 acc[8][4] = {};
  const int nk = K >> 5;

  auto stage = [&](int buf, int kt) {
    const int k0 = kt << 5;
    char* base = sm + buf * 32768;
#pragma unroll
    for (int r = 0; r < 2; ++r) {
      int o = ((r * 8 + w) << 10) + (lane << 4);
      int rp = o >> 7;
      int u = (o >> 4) & 7;
      int l = u ^ (rp & 7);
      int mr = rp * 2 + (l >> 2);
      int kk = (l & 3) * 8;
      async16(base + o, A + (size_t)(m0 + mr) * K + k0 + kk);
      async16(base + 16384 + o, Bt + (size_t)(n0 + mr) * K + k0 + kk);
    }
  };

  auto body = [&](auto vmc, int tt, bool dostage) {
    if (dostage) stage((tt + 3) & 3, tt + 3);
    asm volatile("s_waitcnt vmcnt(%0)" ::"n"(decltype(vmc)::v) : "memory");
    __builtin_amdgcn_s_barrier();
    asm volatile("" ::: "memory");
    const char* Ab = sm + (tt & 3) * 32768;
    const char* Bb = Ab + 16384;
    bf16x8 aq[8], bq[4];
#pragma unroll
    for (int nt = 0; nt < 4; ++nt) {
      int row = wn + nt * 16 + c;
      int rp = row >> 1;
      int u = ((row & 1) * 4 + g) ^ (rp & 7);
      bq[nt] = *(const bf16x8*)(Bb + rp * 128 + u * 16);
    }
#pragma unroll
    for (int i = 0; i < 8; ++i) {
      int row = wm + i * 16 + c;
      int rp = row >> 1;
      int u = ((row & 1) * 4 + g) ^ (rp & 7);
      aq[i] = *(const bf16x8*)(Ab + rp * 128 + u * 16);
    }
    __builtin_amdgcn_s_setprio(1);
#pragma unroll
    for (int i = 0; i < 8; ++i)
#pragma unroll
      for (int nt = 0; nt < 4; ++nt)
        acc[i][nt] = __builtin_amdgcn_mfma_f32_16x16x32_bf16(
            aq[i], bq[nt], acc[i][nt], 0, 0, 0);
    __builtin_amdgcn_s_setprio(0);
    __builtin_amdgcn_s_barrier();
    asm volatile("" ::: "memory");
  };

  stage(0, 0);
  stage(1, 1);
  stage(2, 2);
  int tt = 0;
  for (; tt < nk - 3; ++tt) body(VMC<12>{}, tt, true);
  body(VMC<8>{}, tt, false); ++tt;
  body(VMC<4>{}, tt, false); ++tt;
  body(VMC<0>{}, tt, false);

#pragma unroll
  for (int i = 0; i < 8; ++i)
#pragma unroll
    for (int nt = 0; nt < 4; ++nt)
#pragma unroll
      for (int r = 0; r < 4; ++r) {
        int row = m0 + wm + i * 16 + g * 4 + r;
        int col = n0 + wn + nt * 16 + c;
        float v = acc[i][nt][r] + bias[col];
        Cb[(size_t)row * N + col] = (__bf16)fmaxf(v, 0.f);
      }
}

// ---------------------------------------------------------------------------
// GEMM 128x128 for QKV with fused RoPE: bf16 store; for n0 < 2048 (q,k
// regions) rotate pairs (i, i+32) which live in fragments (nt, nt+2) of the
// same thread (i = nt*16 + c for nt in {0,1}); s = row & 2047.
// Grid (24,64) = 1536 blocks at 3/CU = exactly 2 full occupancy rounds.
// ---------------------------------------------------------------------------
__global__ __launch_bounds__(256, 3) void gemm_btq(
    const __bf16* __restrict__ A, const __bf16* __restrict__ Bt,
    const float2* __restrict__ tab, __bf16* __restrict__ Cb,
    int M, int N, int K) {
  __shared__ char smem[32768];
  char* As = smem;
  char* Bs = smem + 16384;
  const int t = threadIdx.x, lane = t & 63, w = t >> 6;
  const int nwg = gridDim.x * gridDim.y;
  const int wgid = blockIdx.y * gridDim.x + blockIdx.x;
  const int swz = (wgid & 7) * (nwg >> 3) + (wgid >> 3);
  const int m0 = (swz / gridDim.x) * 128, n0 = (swz % gridDim.x) * 128;
  const int wm = (w >> 1) * 64, wn = (w & 1) * 64;
  const int c = lane & 15, g = lane >> 4;
  f32x4 acc[4][4] = {};
  const int nk = K >> 6;
  for (int kt = 0; kt < nk; ++kt) {
    const int k0 = kt << 6;
#pragma unroll
    for (int rd = 0; rd < 4; ++rd) {
      int o = ((rd * 4 + w) << 10) + (lane << 4);
      int row = o >> 7;
      int us = ((o >> 4) & 7) ^ (row & 7);
      async16(As + o, A + (size_t)(m0 + row) * K + k0 + us * 8);
      async16(Bs + o, Bt + (size_t)(n0 + row) * K + k0 + us * 8);
    }
    __syncthreads();
#pragma unroll
    for (int ks = 0; ks < 2; ++ks) {
      bf16x8 af[4], bfr[4];
#pragma unroll
      for (int mt = 0; mt < 4; ++mt) {
        int row = wm + mt * 16 + c;
        int u = (ks * 4 + g) ^ (row & 7);
        af[mt] = *(const bf16x8*)(As + row * 128 + u * 16);
      }
#pragma unroll
      for (int nt = 0; nt < 4; ++nt) {
        int row = wn + nt * 16 + c;
        int u = (ks * 4 + g) ^ (row & 7);
        bfr[nt] = *(const bf16x8*)(Bs + row * 128 + u * 16);
      }
#pragma unroll
      for (int mt = 0; mt < 4; ++mt)
#pragma unroll
        for (int nt = 0; nt < 4; ++nt)
          acc[mt][nt] = __builtin_amdgcn_mfma_f32_16x16x32_bf16(
              af[mt], bfr[nt], acc[mt][nt], 0, 0, 0);
    }
    __syncthreads();
  }
  if (n0 < 2048) {
#pragma unroll
    for (int mt = 0; mt < 4; ++mt)
#pragma unroll
      for (int r = 0; r < 4; ++r) {
        int s = (m0 + wm + mt * 16 + g * 4 + r) & (SLEN - 1);
        float2 t0 = tab[s * 32 + c];
        float2 t1 = tab[s * 32 + 16 + c];
        float q0 = acc[mt][0][r], q2 = acc[mt][2][r];
        acc[mt][0][r] = q0 * t0.x - q2 * t0.y;
        acc[mt][2][r] = q2 * t0.x + q0 * t0.y;
        float q1 = acc[mt][1][r], q3 = acc[mt][3][r];
        acc[mt][1][r] = q1 * t1.x - q3 * t1.y;
        acc[mt][3][r] = q3 * t1.x + q1 * t1.y;
      }
  }
#pragma unroll
  for (int mt = 0; mt < 4; ++mt)
#pragma unroll
    for (int nt = 0; nt < 4; ++nt)
#pragma unroll
      for (int r = 0; r < 4; ++r) {
        int row = m0 + wm + mt * 16 + g * 4 + r;
        int col = n0 + wn + nt * 16 + c;
        Cb[(size_t)row * N + col] = (__bf16)acc[mt][nt][r];
      }
}

// ---------------------------------------------------------------------------
// GEMM 128x128 (MLP2/WO): EPI 2 = f32 out = xres+v+bias; 3 = out += mask*v.
// EPI 3 additionally computes the aux loss in block (0,0) after its tile
// (block-uniform branch; smem reuse is safe past the k-loop's final barrier).
// ---------------------------------------------------------------------------
template <int EPI>
__global__ __launch_bounds__(256, 3) void gemm_bt(
    const __bf16* __restrict__ A, const __bf16* __restrict__ Bt,
    const float* __restrict__ bias, const float* __restrict__ xres,
    const float* __restrict__ maskp, __bf16* __restrict__ Cb,
    float* __restrict__ Cf, int M, int N, int K,
    const float* __restrict__ probsp, float* __restrict__ auxout) {
  __shared__ char smem[32768];
  char* As = smem;
  char* Bs = smem + 16384;
  const int t = threadIdx.x, lane = t & 63, w = t >> 6;
  const int nwg = gridDim.x * gridDim.y;
  const int wgid = blockIdx.y * gridDim.x + blockIdx.x;
  const int swz = (wgid & 7) * (nwg >> 3) + (wgid >> 3);
  const int m0 = (swz / gridDim.x) * 128, n0 = (swz % gridDim.x) * 128;
  const int wm = (w >> 1) * 64, wn = (w & 1) * 64;
  f32x4 acc[4][4] = {};
  const int nk = K >> 6;
  for (int kt = 0; kt < nk; ++kt) {
    const int k0 = kt << 6;
#pragma unroll
    for (int rd = 0; rd < 4; ++rd) {
      int o = ((rd * 4 + w) << 10) + (lane << 4);
      int row = o >> 7;
      int us = ((o >> 4) & 7) ^ (row & 7);
      async16(As + o, A + (size_t)(m0 + row) * K + k0 + us * 8);
      async16(Bs + o, Bt + (size_t)(n0 + row) * K + k0 + us * 8);
    }
    __syncthreads();
#pragma unroll
    for (int ks = 0; ks < 2; ++ks) {
      bf16x8 af[4], bfr[4];
#pragma unroll
      for (int mt = 0; mt < 4; ++mt) {
        int row = wm + mt * 16 + (lane & 15);
        int u = (ks * 4 + (lane >> 4)) ^ (row & 7);
        af[mt] = *(const bf16x8*)(As + row * 128 + u * 16);
      }
#pragma unroll
      for (int nt = 0; nt < 4; ++nt) {
        int row = wn + nt * 16 + (lane & 15);
        int u = (ks * 4 + (lane >> 4)) ^ (row & 7);
        bfr[nt] = *(const bf16x8*)(Bs + row * 128 + u * 16);
      }
#pragma unroll
      for (int mt = 0; mt < 4; ++mt)
#pragma unroll
        for (int nt = 0; nt < 4; ++nt)
          acc[mt][nt] = __builtin_amdgcn_mfma_f32_16x16x32_bf16(
              af[mt], bfr[nt], acc[mt][nt], 0, 0, 0);
    }
    __syncthreads();
  }
#pragma unroll
  for (int mt = 0; mt < 4; ++mt)
#pragma unroll
    for (int nt = 0; nt < 4; ++nt)
#pragma unroll
      for (int r = 0; r < 4; ++r) {
        int row = m0 + wm + mt * 16 + ((lane >> 4) << 2) + r;
        int col = n0 + wn + nt * 16 + (lane & 15);
        float v = acc[mt][nt][r];
        size_t idx = (size_t)row * N + col;
        if constexpr (EPI == 2) {
          Cf[idx] = xres[idx] + v + bias[col];
        } else {
          Cf[idx] += maskp[row] * v;
        }
      }
  if constexpr (EPI == 3) {
    if (blockIdx.x == 0 && blockIdx.y == 0) {
      float* ws4 = (float*)smem;  // reuse: k-loop LDS retired at last barrier
      float sum = 0.f;
      for (int i = t; i < NTOK; i += 256) sum += probsp[i];
#pragma unroll
      for (int d = 32; d; d >>= 1) sum += __shfl_down(sum, d);
      if ((t & 63) == 0) ws4[t >> 6] = sum;
      __syncthreads();
      if (t == 0) {
        float m = (ws4[0] + ws4[1] + ws4[2] + ws4[3]) * (1.f / NTOK) - 0.2f;
        auxout[0] = m * m;
      }
    }
  }
}

// ---------------------------------------------------------------------------
// V scatter (8-wave): wave w owns d = w*8..w*8+7, lane = k-token
// ---------------------------------------------------------------------------
__device__ __forceinline__ void scatterV8(char* Vdst, int w, int lane, float4 va) {
  union { float4 f; __bf16 bv[8]; } u0;
  u0.f = va;
#pragma unroll
  for (int j = 0; j < 8; ++j) {
    int d = w * 8 + j;
    int by = d * 128 + (((lane >> 3) ^ (d & 7)) << 4) + ((lane & 7) << 1);
    *(__bf16*)(Vdst + by) = u0.bv[j];
  }
}

// ---------------------------------------------------------------------------
// Flash attention, causal, swapped QK^T, in-lane softmax — 8-wave version
// (verified R18/R21/R22/R23: 16 waves/CU, no spill). XCD bh-grouping.
// ---------------------------------------------------------------------------
__global__ __launch_bounds__(512, 4) void attn_kernel(const __bf16* __restrict__ qkv,
                                                      __bf16* __restrict__ ctx) {
  __shared__ char sm[32768];
  const int t = threadIdx.x, lane = t & 63, w = t >> 6;  // w in 0..7
  const int c = lane & 15, g = lane >> 4, g4 = g * 4;
  const int bh = (int)blockIdx.x * 8 + ((int)blockIdx.y & 7);
  const int qp = (int)blockIdx.y >> 3;
  const int h = bh & 15, b = bh >> 4;
  const size_t tokbase = (size_t)b * SLEN;
  const __bf16* qg = qkv + tokbase * 3072 + h * 64;
  const __bf16* kg = qg + 1024;
  const __bf16* vg = qg + 2048;
  const float SCL = 0.125f * 1.44269504f;  // 1/sqrt(64) * log2(e)
  char* Ps = sm + (w << 11);   // 2KB per wave
  char* Ks = sm + 16384;
  char* Vs = sm + 24576;

  for (int ph = 0; ph < 2; ++ph) {
    const int qt = ph == 0 ? qp : 15 - qp;
    const int q0 = qt * 128;
#pragma unroll
    for (int rd = 0; rd < 2; ++rd) {
      int o = ((rd * 8 + w) << 10) + (lane << 4);
      int row = o >> 7;
      int us = ((o >> 4) & 7) ^ (row & 7);
      async16(sm + o, qg + (size_t)(q0 + row) * 3072 + us * 8);
    }
    __syncthreads();
    bf16x8 qb[2];
#pragma unroll
    for (int ks = 0; ks < 2; ++ks) {
      int row = w * 16 + c;
      int u = (ks * 4 + g) ^ (row & 7);
      qb[ks] = *(const bf16x8*)(sm + row * 128 + u * 16);
    }

    float m_run = -1e30f, l_run = 0.f;
    f32x4 o_acc[4] = {};
    const int nkt = (q0 + 128) >> 6;
    const int wrow0 = q0 + w * 16;

    for (int kt = 0; kt < nkt; ++kt) {
      const int k0 = kt << 6;
      {
        int o = (w << 10) + (lane << 4);
        int row = o >> 7;
        int us = ((o >> 4) & 7) ^ (row & 7);
        async16(Ks + o, kg + (size_t)(k0 + row) * 3072 + us * 8);
        float4 va = *(const float4*)(vg + (size_t)(k0 + lane) * 3072 + w * 8);
        scatterV8(Vs, w, lane, va);
      }
      __syncthreads();
      if (k0 <= wrow0 + 15) {
        f32x4 st[4] = {};
        __builtin_amdgcn_s_setprio(1);
#pragma unroll
        for (int ks = 0; ks < 2; ++ks) {
          bf16x8 ka[4];
#pragma unroll
          for (int nt = 0; nt < 4; ++nt) {
            int row = nt * 16 + c;
            int u = (ks * 4 + g) ^ (row & 7);
            ka[nt] = *(const bf16x8*)(Ks + row * 128 + u * 16);
          }
#pragma unroll
          for (int nt = 0; nt < 4; ++nt)
            st[nt] = __builtin_amdgcn_mfma_f32_16x16x32_bf16(
                ka[nt], qb[ks], st[nt], 0, 0, 0);
        }
        __builtin_amdgcn_s_setprio(0);
        const bool needmask = (k0 + 63) > wrow0;
        float mx = -1e30f;
        if (needmask) {
          int qglob = wrow0 + c;
#pragma unroll
          for (int nt = 0; nt < 4; ++nt)
#pragma unroll
            for (int r = 0; r < 4; ++r) {
              float sv = st[nt][r] * SCL;
              if (k0 + nt * 16 + g4 + r > qglob) sv = -1e30f;
              st[nt][r] = sv;
              mx = fmaxf(mx, sv);
            }
        } else {
#pragma unroll
          for (int nt = 0; nt < 4; ++nt)
#pragma unroll
            for (int r = 0; r < 4; ++r) {
              float sv = st[nt][r] * SCL;
              st[nt][r] = sv;
              mx = fmaxf(mx, sv);
            }
        }
        mx = fmaxf(mx, __shfl_xor(mx, 16));
        mx = fmaxf(mx, __shfl_xor(mx, 32));
        const bool skip = __all(mx - m_run <= 8.f) != 0;
        float mnew = skip ? m_run : fmaxf(m_run, mx);
        float rs = 0.f;
#pragma unroll
        for (int nt = 0; nt < 4; ++nt)
#pragma unroll
          for (int r = 0; r < 4; ++r) {
            float p = __builtin_amdgcn_exp2f(st[nt][r] - mnew);
            st[nt][r] = p;
            rs += p;
          }
        rs += __shfl_xor(rs, 16);
        rs += __shfl_xor(rs, 32);
        if (skip) {
          l_run += rs;
        } else {
          float fac = __builtin_amdgcn_exp2f(m_run - mnew);
          m_run = mnew;
          l_run = l_run * fac + rs;
#pragma unroll
          for (int r = 0; r < 4; ++r) {
            float fr = __shfl(fac, g * 20 + r);
#pragma unroll
            for (int dt = 0; dt < 4; ++dt) o_acc[dt][r] *= fr;
          }
        }
        {
          int rbase = c * 128 + 8 * (g & 1);
#pragma unroll
          for (int nt = 0; nt < 4; ++nt) {
            int us = (2 * nt + (g >> 1)) ^ (c & 7);
            union { uint2 v; __bf16 bb[4]; } pp;
            pp.bb[0] = (__bf16)st[nt][0]; pp.bb[1] = (__bf16)st[nt][1];
            pp.bb[2] = (__bf16)st[nt][2]; pp.bb[3] = (__bf16)st[nt][3];
            *(uint2*)(Ps + rbase + us * 16) = pp.v;
          }
        }
        __builtin_amdgcn_s_setprio(1);
#pragma unroll
        for (int ks = 0; ks < 2; ++ks) {
          bf16x8 pa, vb[4];
          {
            int u = (ks * 4 + g) ^ (c & 7);
            pa = *(const bf16x8*)(Ps + c * 128 + u * 16);
          }
#pragma unroll
          for (int dt = 0; dt < 4; ++dt) {
            int row = dt * 16 + c;
            int u = (ks * 4 + g) ^ (row & 7);
            vb[dt] = *(const bf16x8*)(Vs + row * 128 + u * 16);
          }
#pragma unroll
          for (int dt = 0; dt < 4; ++dt)
            o_acc[dt] = __builtin_amdgcn_mfma_f32_16x16x32_bf16(
                pa, vb[dt], o_acc[dt], 0, 0, 0);
        }
        __builtin_amdgcn_s_setprio(0);
      }
      __syncthreads();
    }
#pragma unroll
    for (int r = 0; r < 4; ++r) {
      float lr = __shfl(l_run, g * 20 + r);
      float inv = 1.f / lr;
      int tokr = q0 + w * 16 + g4 + r;
#pragma unroll
      for (int dt = 0; dt < 4; ++dt) {
        int d = dt * 16 + c;
        ctx[(tokbase + tokr) * DDIM + h * 64 + d] =
            (__bf16)(o_acc[dt][r] * inv);
      }
    }
  }
}

// ---------------------------------------------------------------------------
extern "C" void kernel_launch(void* const* d_in, const int* in_sizes, int n_in,
                              void* d_out, int out_size, void* d_ws, size_t ws_size,
                              hipStream_t stream) {
  const float* x      = (const float*)d_in[0];
  const float* gate_w = (const float*)d_in[1];
  const float* gate_b = (const float*)d_in[2];
  const float* wq     = (const float*)d_in[3];
  const float* wk     = (const float*)d_in[4];
  const float* wv     = (const float*)d_in[5];
  const float* wo     = (const float*)d_in[6];
  const float* conv_w = (const float*)d_in[7];
  const float* conv_b = (const float*)d_in[8];
  const float* mlp_w1 = (const float*)d_in[9];
  const float* mlp_b1 = (const float*)d_in[10];
  const float* mlp_w2 = (const float*)d_in[11];
  const float* mlp_b2 = (const float*)d_in[12];
  float* out = (float*)d_out;

  char* ws = (char*)d_ws;
  const size_t MB = 1ull << 20;
  __bf16* xb     = (__bf16*)(ws + 0);
  __bf16* xcb    = (__bf16*)(ws + 16 * MB);
  __bf16* ctx    = (__bf16*)(ws + 16 * MB);    // overlays xcb
  __bf16* wqkv_t = (__bf16*)(ws + 32 * MB);
  __bf16* wo_t   = (__bf16*)(ws + 38 * MB);
  __bf16* w1_t   = (__bf16*)(ws + 40 * MB);
  __bf16* w2_t   = (__bf16*)(ws + 48 * MB);
  float*  maskp  = (float*)(ws + 56 * MB);
  float*  probsp = (float*)(ws + 56 * MB + 65536);
  float2* ropetab= (float2*)(ws + 56 * MB + 131072);  // 512KB
  __bf16* h1     = (__bf16*)(ws + 57 * MB);
  __bf16* qkv    = (__bf16*)(ws + 57 * MB);    // overlays h1

  prep_all_kernel<<<5376, 256, 0, stream>>>(
      x, gate_w, gate_b, conv_w, conv_b, xb, xcb, maskp, probsp,
      wq, wk, wv, wo, mlp_w1, mlp_w2, wqkv_t, wo_t, w1_t, w2_t, ropetab);

  // Reflexive (MLP) stream first so h1 region can be reused by qkv.
  gemm256p<<<dim3(16, 32), 512, 131072, stream>>>(xcb, w1_t, mlp_b1, h1,
                                                  NTOK, MLPD, DDIM);
  gemm_bt<2><<<dim3(8, 64), 256, 0, stream>>>(h1, w2_t, mlp_b2, x, nullptr,
                                              nullptr, out, NTOK, DDIM, MLPD,
                                              nullptr, nullptr);
  // Contextual stream (RoPE fused into the QKV epilogue).
  gemm_btq<<<dim3(24, 64), 256, 0, stream>>>(xb, wqkv_t, ropetab, qkv,
                                             NTOK, 3072, DDIM);
  attn_kernel<<<dim3(8, 64), 512, 0, stream>>>(qkv, ctx);
  // WO GEMM; block (0,0) also emits the aux loss (replaces aux_kernel).
  gemm_bt<3><<<dim3(8, 64), 256, 0, stream>>>(ctx, wo_t, nullptr, nullptr, maskp,
                                              nullptr, out, NTOK, DDIM, DDIM,
                                              probsp, out + (size_t)(out_size - 1));
}